// Round 4
// baseline (2757.441 us; speedup 1.0000x reference)
//
#include <hip/hip_runtime.h>

#define BS 16
#define SEQ 1024
#define EMB 128
#define NHEAD 4
#define LN_EPS 1e-5f

typedef __attribute__((ext_vector_type(8))) short bf16x8;
typedef __attribute__((ext_vector_type(4))) float f32x4;
typedef __attribute__((ext_vector_type(4))) unsigned short u16x4;

__device__ __forceinline__ unsigned short f2b(float f) {
  union { float f; unsigned u; } v; v.f = f;
  unsigned r = v.u + 0x7fff + ((v.u >> 16) & 1);
  return (unsigned short)(r >> 16);
}
// split x into hi+lo bf16 (3-term Markidis precision: rel err ~2^-17)
__device__ __forceinline__ void split2(float x, unsigned short& hi, unsigned short& lo) {
  unsigned short h = f2b(x);
  float hf = __uint_as_float((unsigned)h << 16);
  hi = h; lo = f2b(x - hf);
}
__device__ __forceinline__ float rsqrt_acc(float v) {
  float r = rsqrtf(v);
  return r * (1.5f - 0.5f * v * r * r);   // one Newton step -> ~f32-exact
}

// ---------------- weight prep ----------------
__global__ void k_transpose_pad(const float* __restrict__ in, unsigned short* __restrict__ out,
                                size_t PL, int L, int Kin, int Nin, int Kout, int Nout) {
  int idx = blockIdx.x * 256 + threadIdx.x;
  int total = L * Kout * Nout;
  if (idx >= total) return;
  int k = idx % Kout;
  int n = (idx / Kout) % Nout;
  int l = idx / (Kout * Nout);
  float v = (k < Kin && n < Nin) ? in[(size_t)l * Kin * Nin + (size_t)k * Nin + n] : 0.f;
  unsigned short hi, lo; split2(v, hi, lo);
  out[idx] = hi; out[PL + idx] = lo;
}

// qvWT[l][512][128]: n<256 -> q (qW rows -> H dims 64..126), n>=256 -> v (H dims 0..62)
__global__ void k_prep_qv(const float* __restrict__ qW, const float* __restrict__ vW,
                          unsigned short* __restrict__ out, size_t PL) {
  int idx = blockIdx.x * 256 + threadIdx.x;
  int total = 11 * 512 * 128;
  if (idx >= total) return;
  int k = idx & 127;
  int n = (idx >> 7) & 511;
  int l = idx >> 16;
  float v = 0.f;
  if (n < 256) {
    if (n < 252 && k >= 64 && k < 127) v = qW[(size_t)l * 63 * 252 + (size_t)(k - 64) * 252 + n];
  } else {
    int n2 = n - 256;
    if (n2 < 252 && k < 63) v = vW[(size_t)l * 63 * 252 + (size_t)k * 252 + n2];
  }
  unsigned short hi, lo; split2(v, hi, lo);
  out[idx] = hi; out[PL + idx] = lo;
}

// ---------------- combine + read_in ----------------
__global__ void k_combine_readin(const float* __restrict__ xs, const float* __restrict__ ys,
                                 const float* __restrict__ W, const float* __restrict__ bias,
                                 float* __restrict__ H, unsigned short* __restrict__ Hbf, size_t hbPl) {
  int blk = blockIdx.x;            // b*1024 + t
  int b = blk >> 10, t = blk & 1023, p = t >> 1;
  __shared__ float zs[64];
  int tid = threadIdx.x;           // 128
  if (tid < 64) {
    float v;
    if (tid < 63) v = xs[((size_t)b * 512 + p) * 63 + tid];
    else v = (t & 1) ? ys[(size_t)b * 512 + p] : 0.f;
    zs[tid] = v;
  }
  __syncthreads();
  float acc = bias[tid];
  #pragma unroll 8
  for (int d = 0; d < 64; ++d) acc += zs[d] * W[d * 128 + tid];
  size_t o = (size_t)blk * 128 + tid;
  H[o] = acc;
  unsigned short hi, lo; split2(acc, hi, lo);
  Hbf[o] = hi; Hbf[hbPl + o] = lo;
}

// ---------------- generic split-precision MFMA GEMM ----------------
// MODE 0: bf16-split out0[row*N+c]
// MODE 2: last qkv (N=1536): q,k normal [b][h][t][128]; v transposed [b][h][d][t]
// MODE 3: qv63 (N=512): c<256 q normal [b][h][t][64] (d63=0); else v transposed [b][h][d][t] (d63=0)
template<int MODE, bool RELU>
__global__ __launch_bounds__(256) void k_gemm(
    const unsigned short* __restrict__ A, int aStride, size_t aPl,
    const unsigned short* __restrict__ BT, size_t bPl, const float* __restrict__ bias,
    int N, int K,
    unsigned short* __restrict__ out0, size_t o0Pl,
    unsigned short* __restrict__ out1, size_t o1Pl,
    unsigned short* __restrict__ out2, size_t o2Pl) {
  int wid = threadIdx.x >> 6, lane = threadIdx.x & 63;
  int lr = lane & 15, lg = lane >> 4;
  int row0 = blockIdx.x * 64 + wid * 16;
  int n0 = blockIdx.y * 64;
  f32x4 acc[4] = {};
  const unsigned short* aP = A + (size_t)(row0 + lr) * aStride + lg * 8;
  const unsigned short* bP = BT + (size_t)n0 * K + lg * 8;
  for (int k0 = 0; k0 < K; k0 += 32) {
    bf16x8 ah = *reinterpret_cast<const bf16x8*>(aP + k0);
    bf16x8 al = *reinterpret_cast<const bf16x8*>(aP + aPl + k0);
    #pragma unroll
    for (int nf = 0; nf < 4; ++nf) {
      const unsigned short* bpp = bP + (size_t)(nf * 16 + lr) * K + k0;
      bf16x8 bh = *reinterpret_cast<const bf16x8*>(bpp);
      bf16x8 bl = *reinterpret_cast<const bf16x8*>(bpp + bPl);
      acc[nf] = __builtin_amdgcn_mfma_f32_16x16x32_bf16(ah, bh, acc[nf], 0, 0, 0);
      acc[nf] = __builtin_amdgcn_mfma_f32_16x16x32_bf16(al, bh, acc[nf], 0, 0, 0);
      acc[nf] = __builtin_amdgcn_mfma_f32_16x16x32_bf16(ah, bl, acc[nf], 0, 0, 0);
    }
  }
  int rowb = row0 + lg * 4;
  #pragma unroll
  for (int nf = 0; nf < 4; ++nf) {
    int c = n0 + nf * 16 + lr;
    float bv = bias ? bias[c] : 0.f;
    float vr[4];
    #pragma unroll
    for (int r = 0; r < 4; ++r) {
      float v = acc[nf][r] + bv;
      vr[r] = RELU ? fmaxf(v, 0.f) : v;
    }
    if (MODE == 0) {
      #pragma unroll
      for (int r = 0; r < 4; ++r) {
        unsigned short hi, lo; split2(vr[r], hi, lo);
        size_t o = (size_t)(rowb + r) * N + c;
        out0[o] = hi; out0[o0Pl + o] = lo;
      }
    } else if (MODE == 2) {
      int tsel = c >> 9, c2 = c & 511, hh = c2 >> 7, d = c2 & 127;
      int b = rowb >> 10, t = rowb & 1023;
      size_t bh = (size_t)b * NHEAD + hh;
      if (tsel < 2) {
        unsigned short* base = tsel ? out1 : out0;
        size_t pl = tsel ? o1Pl : o0Pl;
        #pragma unroll
        for (int r = 0; r < 4; ++r) {
          unsigned short hi, lo; split2(vr[r], hi, lo);
          size_t o = (bh * SEQ + (size_t)(t + r)) * 128 + d;
          base[o] = hi; base[pl + o] = lo;
        }
      } else {
        u16x4 hv, lv;
        #pragma unroll
        for (int r = 0; r < 4; ++r) { unsigned short hi, lo; split2(vr[r], hi, lo); hv[r] = hi; lv[r] = lo; }
        size_t addr = (bh * 128 + d) * SEQ + t;
        *reinterpret_cast<u16x4*>(out2 + addr) = hv;
        *reinterpret_cast<u16x4*>(out2 + o2Pl + addr) = lv;
      }
    } else {  // MODE 3
      int b = rowb >> 10, t = rowb & 1023;
      if (c < 256) {
        int hh, d; bool pad = (c >= 252);
        if (!pad) { hh = c / 63; d = c - hh * 63; } else { hh = c - 252; d = 63; }
        size_t bh = (size_t)b * NHEAD + hh;
        #pragma unroll
        for (int r = 0; r < 4; ++r) {
          float v = pad ? 0.f : vr[r];
          unsigned short hi, lo; split2(v, hi, lo);
          size_t o = (bh * SEQ + (size_t)(t + r)) * 64 + d;
          out0[o] = hi; out0[o0Pl + o] = lo;
        }
      } else {
        int cc = c - 256; int hh, d; bool pad = (cc >= 252);
        if (!pad) { hh = cc / 63; d = cc - hh * 63; } else { hh = cc - 252; d = 63; }
        size_t bh = (size_t)b * NHEAD + hh;
        u16x4 hv, lv;
        #pragma unroll
        for (int r = 0; r < 4; ++r) {
          float v = pad ? 0.f : vr[r];
          unsigned short hi, lo; split2(v, hi, lo); hv[r] = hi; lv[r] = lo;
        }
        size_t addr = (bh * 64 + d) * SEQ + t;
        *reinterpret_cast<u16x4*>(out1 + addr) = hv;
        *reinterpret_cast<u16x4*>(out1 + o1Pl + addr) = lv;
      }
    }
  }
}

// ---------------- attention pass 1: per-(b,h,pair) blocks, 4 j-group waves ----------------
// writes per-head attn-out (scaled by hm^3/(i+1)) as f32 to ao[b][h][t][DHEAD]
template<int DHEAD>
__global__ __launch_bounds__(256) void k_attn1(
    const unsigned short* __restrict__ q, size_t qPl,
    const unsigned short* __restrict__ kbase, size_t kPl, size_t kBStride, size_t kHStride,
    const unsigned short* __restrict__ vT, size_t vPl,
    const float* __restrict__ head_mask,
    float* __restrict__ ao) {
  constexpr int KF = DHEAD / 32, NFO = DHEAD / 16;
  constexpr int NT = SEQ / 32;
  // 1024 blocks; 128 per XCD = 2 batches (K/V/Q of 2 batches ~fit per-XCD L2)
  int bid = blockIdx.x;
  int xcd = bid & 7, u = bid >> 3;       // u in [0,128)
  int b = xcd * 2 + (u >> 6);
  int rem = u & 63;
  int h = rem >> 4, pidx = rem & 15;
  int grp = threadIdx.x >> 6, lane = threadIdx.x & 63;
  int lr = lane & 15, lg = lane >> 4;
  __shared__ __align__(16) char shraw[4 * 2 * 32 * 40 * 2];   // 20 KB
  typedef unsigned short SArr[2][32][40];
  SArr* sS = (SArr*)shraw;             // sS[grp][plane][r][c]
  typedef float FRow[DHEAD];
  FRow* facc = (FRow*)shraw;           // facc[r][c] (aliases sS)
  const unsigned short* qh = q + (size_t)(b * NHEAD + h) * SEQ * DHEAD;
  const unsigned short* kh = kbase + (size_t)b * kBStride + (size_t)h * kHStride;
  const unsigned short* vh = vT + (size_t)(b * NHEAD + h) * DHEAD * SEQ;
  float hm = head_mask[h];
  float hm3 = hm * hm * hm;

  for (int s = 0; s < 2; ++s) {
    int tile = (s == 0) ? pidx : (NT - 1 - pidx);
    int i0 = tile * 32;
    bf16x8 qfh[2][KF], qfl[2][KF];
    #pragma unroll
    for (int mf = 0; mf < 2; ++mf)
      #pragma unroll
      for (int kf = 0; kf < KF; ++kf) {
        const unsigned short* qp = qh + (size_t)(i0 + mf * 16 + lr) * DHEAD + kf * 32 + lg * 8;
        qfh[mf][kf] = *reinterpret_cast<const bf16x8*>(qp);
        qfl[mf][kf] = *reinterpret_cast<const bf16x8*>(qp + qPl);
      }
    f32x4 oacc[2][NFO] = {};
    int jend = i0 + 32;
    for (int j0 = grp * 32; j0 < jend; j0 += 128) {
      #pragma unroll
      for (int nf2 = 0; nf2 < 2; ++nf2) {
        int j16 = j0 + nf2 * 16;
        bf16x8 kfh[KF], kfl[KF];
        #pragma unroll
        for (int kf = 0; kf < KF; ++kf) {
          const unsigned short* kp = kh + (size_t)(j16 + lr) * EMB + kf * 32 + lg * 8;
          kfh[kf] = *reinterpret_cast<const bf16x8*>(kp);
          kfl[kf] = *reinterpret_cast<const bf16x8*>(kp + kPl);
        }
        #pragma unroll
        for (int mf = 0; mf < 2; ++mf) {
          f32x4 sacc = {};
          #pragma unroll
          for (int kf = 0; kf < KF; ++kf) {
            sacc = __builtin_amdgcn_mfma_f32_16x16x32_bf16(qfh[mf][kf], kfh[kf], sacc, 0, 0, 0);
            sacc = __builtin_amdgcn_mfma_f32_16x16x32_bf16(qfl[mf][kf], kfh[kf], sacc, 0, 0, 0);
            sacc = __builtin_amdgcn_mfma_f32_16x16x32_bf16(qfh[mf][kf], kfl[kf], sacc, 0, 0, 0);
          }
          #pragma unroll
          for (int r = 0; r < 4; ++r) {
            int i = i0 + mf * 16 + lg * 4 + r;
            int j = j16 + lr;
            float v = (j <= i) ? fmaxf(sacc[r], 0.f) : 0.f;
            unsigned short shi, slo; split2(v, shi, slo);
            sS[grp][0][mf * 16 + lg * 4 + r][nf2 * 16 + lr] = shi;
            sS[grp][1][mf * 16 + lg * 4 + r][nf2 * 16 + lr] = slo;
          }
        }
      }
      asm volatile("s_waitcnt lgkmcnt(0)" ::: "memory");
      __builtin_amdgcn_sched_barrier(0);
      #pragma unroll
      for (int mf = 0; mf < 2; ++mf) {
        bf16x8 sfh = *reinterpret_cast<const bf16x8*>(&sS[grp][0][mf * 16 + lr][lg * 8]);
        bf16x8 sfl = *reinterpret_cast<const bf16x8*>(&sS[grp][1][mf * 16 + lr][lg * 8]);
        #pragma unroll
        for (int nf = 0; nf < NFO; ++nf) {
          const unsigned short* vp = vh + (size_t)(nf * 16 + lr) * SEQ + j0 + lg * 8;
          bf16x8 vfh = *reinterpret_cast<const bf16x8*>(vp);
          bf16x8 vfl = *reinterpret_cast<const bf16x8*>(vp + vPl);
          oacc[mf][nf] = __builtin_amdgcn_mfma_f32_16x16x32_bf16(sfh, vfh, oacc[mf][nf], 0, 0, 0);
          oacc[mf][nf] = __builtin_amdgcn_mfma_f32_16x16x32_bf16(sfl, vfh, oacc[mf][nf], 0, 0, 0);
          oacc[mf][nf] = __builtin_amdgcn_mfma_f32_16x16x32_bf16(sfh, vfl, oacc[mf][nf], 0, 0, 0);
        }
      }
    }
    __syncthreads();  // all waves done with sS (facc aliases it)
    for (int x = threadIdx.x; x < 32 * DHEAD; x += 256) ((float*)shraw)[x] = 0.f;
    __syncthreads();
    for (int w = 0; w < 4; ++w) {   // deterministic j-group sum
      if (grp == w) {
        #pragma unroll
        for (int mf = 0; mf < 2; ++mf)
          #pragma unroll
          for (int nf = 0; nf < NFO; ++nf)
            #pragma unroll
            for (int r = 0; r < 4; ++r)
              facc[mf * 16 + lg * 4 + r][nf * 16 + lr] += oacc[mf][nf][r];
      }
      __syncthreads();
    }
    for (int idx = threadIdx.x; idx < 32 * DHEAD; idx += 256) {
      int rr = idx / DHEAD, d = idx - rr * DHEAD;
      ao[((size_t)(b * NHEAD + h) * SEQ + i0 + rr) * DHEAD + d] =
          facc[rr][d] * hm3 / (float)(i0 + rr + 1);
    }
    __syncthreads();
  }
}

// ---------------- attention pass 2: head-sum + residual + LN1 ----------------
template<int DHEAD>
__global__ __launch_bounds__(256) void k_sumln(
    const float* __restrict__ ao,
    float* __restrict__ Hst, unsigned short* __restrict__ HbfOut, size_t hbPl,
    const float* __restrict__ g, const float* __restrict__ bta) {
  int wid = threadIdx.x >> 6, lane = threadIdx.x & 63;
  int t = blockIdx.x * 4 + wid;
  int b = t >> 10, tt = t & 1023;
  float a0 = 0.f, a1 = 0.f;
  #pragma unroll
  for (int h = 0; h < NHEAD; ++h) {
    const float* ap = ao + ((size_t)(b * NHEAD + h) * SEQ + tt) * DHEAD;
    if (DHEAD == 64) a1 += ap[lane];
    else { a0 += ap[lane]; a1 += ap[lane + 64]; }
  }
  size_t row = (size_t)t * EMB;
  int c0 = lane, c1 = lane + 64;
  float x0 = Hst[row + c0] + a0;
  float x1 = Hst[row + c1] + a1;
  float s1 = x0 + x1, s2 = x0 * x0 + x1 * x1;
  #pragma unroll
  for (int off = 1; off < 64; off <<= 1) {
    s1 += __shfl_xor(s1, off);
    s2 += __shfl_xor(s2, off);
  }
  float mu = s1 * (1.f / 128.f);
  float var = s2 * (1.f / 128.f) - mu * mu;
  float rs = rsqrt_acc(var + LN_EPS);
  float y0 = (x0 - mu) * rs * g[c0] + bta[c0];
  float y1 = (x1 - mu) * rs * g[c1] + bta[c1];
  Hst[row + c0] = y0; Hst[row + c1] = y1;
  unsigned short h0, l0, h1, l1; split2(y0, h0, l0); split2(y1, h1, l1);
  HbfOut[row + c0] = h0; HbfOut[hbPl + row + c0] = l0;
  HbfOut[row + c1] = h1; HbfOut[hbPl + row + c1] = l1;
}

// ---------------- fused attention (+LN1), last layer (DHEAD=128), 8-wave ----------------
template<int DHEAD>
__global__ __launch_bounds__(512) void k_attn_fused(
    const unsigned short* __restrict__ q, size_t qPl,
    const unsigned short* __restrict__ kbase, size_t kPl, size_t kBStride, size_t kHStride,
    const unsigned short* __restrict__ vT, size_t vPl,
    const float* __restrict__ head_mask,
    float* __restrict__ Hst, unsigned short* __restrict__ HbfOut, size_t hbPl,
    const float* __restrict__ g, const float* __restrict__ bta) {
  constexpr int KF = DHEAD / 32, NFO = DHEAD / 16;
  constexpr int NT = SEQ / 32;
  constexpr int SSB = 8 * 2 * 32 * 40 * 2;   // 40 KB
  constexpr int SH_BYTES = (SSB > 32 * DHEAD * 4) ? SSB : 32 * DHEAD * 4;
  int bid = blockIdx.x;
  int xcd = bid & 7, u = bid >> 3;
  int b = xcd * 2 + (u >> 4);
  int pidx = u & 15;
  int wid = threadIdx.x >> 6, lane = threadIdx.x & 63;
  int h = wid & 3, grp = wid >> 2;
  int lr = lane & 15, lg = lane >> 4;
  __shared__ __align__(16) char shraw[SH_BYTES];
  typedef unsigned short SArr[2][32][40];
  SArr* sS = (SArr*)shraw;
  typedef float FRow[DHEAD];
  FRow* facc = (FRow*)shraw;
  const unsigned short* qh = q + (size_t)(b * NHEAD + h) * SEQ * DHEAD;
  const unsigned short* kh = kbase + (size_t)b * kBStride + (size_t)h * kHStride;
  const unsigned short* vh = vT + (size_t)(b * NHEAD + h) * DHEAD * SEQ;
  float hm = head_mask[h];
  float hm3 = hm * hm * hm;

  for (int s = 0; s < 2; ++s) {
    int tile = (s == 0) ? pidx : (NT - 1 - pidx);
    int i0 = tile * 32;
    bf16x8 qfh[2][KF], qfl[2][KF];
    #pragma unroll
    for (int mf = 0; mf < 2; ++mf)
      #pragma unroll
      for (int kf = 0; kf < KF; ++kf) {
        const unsigned short* qp = qh + (size_t)(i0 + mf * 16 + lr) * DHEAD + kf * 32 + lg * 8;
        qfh[mf][kf] = *reinterpret_cast<const bf16x8*>(qp);
        qfl[mf][kf] = *reinterpret_cast<const bf16x8*>(qp + qPl);
      }
    f32x4 oacc[2][NFO] = {};
    int jend = i0 + 32;
    for (int j0 = grp * 32; j0 < jend; j0 += 64) {
      #pragma unroll
      for (int nf2 = 0; nf2 < 2; ++nf2) {
        int j16 = j0 + nf2 * 16;
        bf16x8 kfh[KF], kfl[KF];
        #pragma unroll
        for (int kf = 0; kf < KF; ++kf) {
          const unsigned short* kp = kh + (size_t)(j16 + lr) * EMB + kf * 32 + lg * 8;
          kfh[kf] = *reinterpret_cast<const bf16x8*>(kp);
          kfl[kf] = *reinterpret_cast<const bf16x8*>(kp + kPl);
        }
        #pragma unroll
        for (int mf = 0; mf < 2; ++mf) {
          f32x4 sacc = {};
          #pragma unroll
          for (int kf = 0; kf < KF; ++kf) {
            sacc = __builtin_amdgcn_mfma_f32_16x16x32_bf16(qfh[mf][kf], kfh[kf], sacc, 0, 0, 0);
            sacc = __builtin_amdgcn_mfma_f32_16x16x32_bf16(qfl[mf][kf], kfh[kf], sacc, 0, 0, 0);
            sacc = __builtin_amdgcn_mfma_f32_16x16x32_bf16(qfh[mf][kf], kfl[kf], sacc, 0, 0, 0);
          }
          #pragma unroll
          for (int r = 0; r < 4; ++r) {
            int i = i0 + mf * 16 + lg * 4 + r;
            int j = j16 + lr;
            float v = (j <= i) ? fmaxf(sacc[r], 0.f) : 0.f;
            unsigned short shi, slo; split2(v, shi, slo);
            sS[wid][0][mf * 16 + lg * 4 + r][nf2 * 16 + lr] = shi;
            sS[wid][1][mf * 16 + lg * 4 + r][nf2 * 16 + lr] = slo;
          }
        }
      }
      asm volatile("s_waitcnt lgkmcnt(0)" ::: "memory");
      __builtin_amdgcn_sched_barrier(0);
      #pragma unroll
      for (int mf = 0; mf < 2; ++mf) {
        bf16x8 sfh = *reinterpret_cast<const bf16x8*>(&sS[wid][0][mf * 16 + lr][lg * 8]);
        bf16x8 sfl = *reinterpret_cast<const bf16x8*>(&sS[wid][1][mf * 16 + lr][lg * 8]);
        #pragma unroll
        for (int nf = 0; nf < NFO; ++nf) {
          const unsigned short* vp = vh + (size_t)(nf * 16 + lr) * SEQ + j0 + lg * 8;
          bf16x8 vfh = *reinterpret_cast<const bf16x8*>(vp);
          bf16x8 vfl = *reinterpret_cast<const bf16x8*>(vp + vPl);
          oacc[mf][nf] = __builtin_amdgcn_mfma_f32_16x16x32_bf16(sfh, vfh, oacc[mf][nf], 0, 0, 0);
          oacc[mf][nf] = __builtin_amdgcn_mfma_f32_16x16x32_bf16(sfl, vfh, oacc[mf][nf], 0, 0, 0);
          oacc[mf][nf] = __builtin_amdgcn_mfma_f32_16x16x32_bf16(sfh, vfl, oacc[mf][nf], 0, 0, 0);
        }
      }
    }
    __syncthreads();
    for (int x = threadIdx.x; x < 32 * DHEAD; x += 512) ((float*)shraw)[x] = 0.f;
    __syncthreads();
    for (int w = 0; w < 8; ++w) {
      if (wid == w) {
        #pragma unroll
        for (int mf = 0; mf < 2; ++mf)
          #pragma unroll
          for (int nf = 0; nf < NFO; ++nf)
            #pragma unroll
            for (int r = 0; r < 4; ++r) {
              int rr = mf * 16 + lg * 4 + r;
              facc[rr][nf * 16 + lr] += oacc[mf][nf][r] * hm3 / (float)(i0 + rr + 1);
            }
      }
      __syncthreads();
    }
    for (int rl = 0; rl < 4; ++rl) {
      int rr = wid * 4 + rl;
      size_t row = ((size_t)b * SEQ + i0 + rr) * EMB;
      int c0 = lane, c1 = lane + 64;
      float a0 = (DHEAD == 128) ? facc[rr][c0] : 0.f;
      float a1 = (DHEAD == 128) ? facc[rr][c1] : facc[rr][lane];
      float x0 = Hst[row + c0] + a0;
      float x1 = Hst[row + c1] + a1;
      float s1 = x0 + x1, s2 = x0 * x0 + x1 * x1;
      #pragma unroll
      for (int off = 1; off < 64; off <<= 1) {
        s1 += __shfl_xor(s1, off);
        s2 += __shfl_xor(s2, off);
      }
      float mu = s1 * (1.f / 128.f);
      float var = s2 * (1.f / 128.f) - mu * mu;
      float rs = rsqrt_acc(var + LN_EPS);
      float y0 = (x0 - mu) * rs * g[c0] + bta[c0];
      float y1 = (x1 - mu) * rs * g[c1] + bta[c1];
      Hst[row + c0] = y0; Hst[row + c1] = y1;
      unsigned short h0, l0, h1, l1; split2(y0, h0, l0); split2(y1, h1, l1);
      HbfOut[row + c0] = h0; HbfOut[hbPl + row + c0] = l0;
      HbfOut[row + c1] = h1; HbfOut[hbPl + row + c1] = l1;
    }
    __syncthreads();
  }
}

// ---------------- fused MLP2 + residual + LN2 ----------------
// y = LN(H + mid @ W2^T + b2); block = 64 rows x full 128 cols, 4 waves
__global__ __launch_bounds__(256) void k_mlp2ln(
    const unsigned short* __restrict__ A, size_t aPl,
    const unsigned short* __restrict__ BT, size_t bPl, const float* __restrict__ bias,
    float* __restrict__ Hst, unsigned short* __restrict__ HbfOut, size_t hbPl,
    const float* __restrict__ g, const float* __restrict__ bta) {
  int wid = threadIdx.x >> 6, lane = threadIdx.x & 63;
  int lr = lane & 15, lg = lane >> 4;
  int row0 = blockIdx.x * 64 + wid * 16;
  f32x4 acc[8] = {};
  const unsigned short* aP = A + (size_t)(row0 + lr) * 512 + lg * 8;
  const unsigned short* bP = BT + lg * 8;
  for (int k0 = 0; k0 < 512; k0 += 32) {
    bf16x8 ah = *reinterpret_cast<const bf16x8*>(aP + k0);
    bf16x8 al = *reinterpret_cast<const bf16x8*>(aP + aPl + k0);
    #pragma unroll
    for (int nf = 0; nf < 8; ++nf) {
      const unsigned short* bpp = bP + (size_t)(nf * 16 + lr) * 512 + k0;
      bf16x8 bh = *reinterpret_cast<const bf16x8*>(bpp);
      bf16x8 bl = *reinterpret_cast<const bf16x8*>(bpp + bPl);
      acc[nf] = __builtin_amdgcn_mfma_f32_16x16x32_bf16(ah, bh, acc[nf], 0, 0, 0);
      acc[nf] = __builtin_amdgcn_mfma_f32_16x16x32_bf16(al, bh, acc[nf], 0, 0, 0);
      acc[nf] = __builtin_amdgcn_mfma_f32_16x16x32_bf16(ah, bl, acc[nf], 0, 0, 0);
    }
  }
  int rowb = row0 + lg * 4;
  float xv[8][4];
  float s1[4] = {}, s2[4] = {};
  #pragma unroll
  for (int nf = 0; nf < 8; ++nf) {
    int c = nf * 16 + lr;
    float bv = bias[c];
    #pragma unroll
    for (int r = 0; r < 4; ++r) {
      float x = acc[nf][r] + bv + Hst[(size_t)(rowb + r) * EMB + c];
      xv[nf][r] = x; s1[r] += x; s2[r] += x * x;
    }
  }
  #pragma unroll
  for (int off = 1; off < 16; off <<= 1) {
    #pragma unroll
    for (int r = 0; r < 4; ++r) {
      s1[r] += __shfl_xor(s1[r], off);
      s2[r] += __shfl_xor(s2[r], off);
    }
  }
  #pragma unroll
  for (int r = 0; r < 4; ++r) {
    float mu = s1[r] * (1.f / 128.f);
    float var = s2[r] * (1.f / 128.f) - mu * mu;
    float rs = rsqrt_acc(var + LN_EPS);
    #pragma unroll
    for (int nf = 0; nf < 8; ++nf) {
      int c = nf * 16 + lr;
      float y = (xv[nf][r] - mu) * rs * g[c] + bta[c];
      size_t o = (size_t)(rowb + r) * EMB + c;
      Hst[o] = y;
      unsigned short hi, lo; split2(y, hi, lo);
      HbfOut[o] = hi; HbfOut[hbPl + o] = lo;
    }
  }
}

// ---------------- readout ----------------
__global__ __launch_bounds__(64) void k_readout(const float* __restrict__ H,
                                                const float* __restrict__ W, const float* __restrict__ b0,
                                                float* __restrict__ out) {
  int idx = blockIdx.x;           // b*512 + p
  int b = idx >> 9, p = idx & 511;
  size_t row = ((size_t)b * SEQ + 2 * p) * EMB;
  int lane = threadIdx.x;
  float acc = H[row + lane] * W[lane] + H[row + 64 + lane] * W[64 + lane];
  #pragma unroll
  for (int off = 1; off < 64; off <<= 1) acc += __shfl_xor(acc, off);
  if (lane == 0) out[idx] = acc + b0[0];
}

extern "C" void kernel_launch(void* const* d_in, const int* in_sizes, int n_in,
                              void* d_out, int out_size, void* d_ws, size_t ws_size,
                              hipStream_t stream) {
  (void)in_sizes; (void)n_in; (void)out_size; (void)ws_size;
  const float* xs        = (const float*)d_in[0];
  const float* ys        = (const float*)d_in[1];
  const float* head_mask = (const float*)d_in[2];
  const float* read_in_W = (const float*)d_in[3];
  const float* read_in_b = (const float*)d_in[4];
  const float* qW        = (const float*)d_in[5];
  const float* vW        = (const float*)d_in[6];
  const float* qW_last   = (const float*)d_in[7];
  const float* kW_last   = (const float*)d_in[8];
  const float* vW_last   = (const float*)d_in[9];
  const float* ln1_g     = (const float*)d_in[10];
  const float* ln1_b     = (const float*)d_in[11];
  const float* ln2_g     = (const float*)d_in[12];
  const float* ln2_b     = (const float*)d_in[13];
  const float* mlp_W1    = (const float*)d_in[14];
  const float* mlp_b1    = (const float*)d_in[15];
  const float* mlp_W2    = (const float*)d_in[16];
  const float* mlp_b2    = (const float*)d_in[17];
  const float* ro_W      = (const float*)d_in[18];
  const float* ro_b      = (const float*)d_in[19];

  const size_t HPL   = (size_t)BS * SEQ * EMB;          // 2M
  const size_t QPL   = (size_t)BS * NHEAD * SEQ * 128;  // 8M
  const size_t VT64PL= (size_t)BS * NHEAD * 64 * SEQ;   // 4M
  const size_t MIDPL = (size_t)BS * SEQ * 512;          // 8M
  const size_t KMPL  = QPL;
  const size_t VTLPL = QPL;
  const size_t QVWPL = (size_t)11 * 512 * 128;
  const size_t W1PL  = (size_t)12 * 128 * 512;
  const size_t W2PL  = (size_t)12 * 512 * 128;
  const size_t LASTPL= (size_t)3 * 512 * 128;

  char* ws = (char*)d_ws;
  size_t off = 0;
  auto alloc = [&](size_t bytes) -> void* {
    void* p = ws + off;
    off += (bytes + 255) & ~(size_t)255;
    return p;
  };
  float* H             = (float*)alloc(HPL * 4);                  // 8 MB (in-place state)
  unsigned short* Hbf  = (unsigned short*)alloc(2 * HPL * 2);     // 8 MB
  unsigned short* Hbf2 = (unsigned short*)alloc(2 * HPL * 2);     // 8 MB
  unsigned short* qbuf = (unsigned short*)alloc(2 * QPL * 2);     // 32 MB
  unsigned short* kmid = (unsigned short*)alloc(2 * KMPL * 2);    // 32 MB (vT64 / mid / K-last)
  unsigned short* vTl  = (unsigned short*)alloc(2 * VTLPL * 2);   // 32 MB (ao f32 layers 0-10; vT last)
  float* ao = (float*)vTl;   // alias: ao (16 MB) lives attn1->sumln; vTl lives only in last layer
  unsigned short* qvWT = (unsigned short*)alloc(2 * QVWPL * 2);
  unsigned short* W1T  = (unsigned short*)alloc(2 * W1PL * 2);
  unsigned short* W2T  = (unsigned short*)alloc(2 * W2PL * 2);
  unsigned short* lastT= (unsigned short*)alloc(2 * LASTPL * 2);

  { int tot = 11 * 512 * 128; k_prep_qv<<<dim3((tot + 255) / 256), 256, 0, stream>>>(qW, vW, qvWT, QVWPL); }
  { int tot = 12 * 512 * 128; k_transpose_pad<<<dim3((tot + 255) / 256), 256, 0, stream>>>(mlp_W1, W1T, W1PL, 12, 128, 512, 128, 512); }
  { int tot = 12 * 128 * 512; k_transpose_pad<<<dim3((tot + 255) / 256), 256, 0, stream>>>(mlp_W2, W2T, W2PL, 12, 512, 128, 512, 128); }
  { int tot = 512 * 128;
    k_transpose_pad<<<dim3((tot + 255) / 256), 256, 0, stream>>>(qW_last, lastT,          LASTPL, 1, 128, 512, 128, 512);
    k_transpose_pad<<<dim3((tot + 255) / 256), 256, 0, stream>>>(kW_last, lastT + 65536,  LASTPL, 1, 128, 512, 128, 512);
    k_transpose_pad<<<dim3((tot + 255) / 256), 256, 0, stream>>>(vW_last, lastT + 131072, LASTPL, 1, 128, 512, 128, 512); }

  k_combine_readin<<<dim3(BS * SEQ), 128, 0, stream>>>(xs, ys, read_in_W, read_in_b, H, Hbf, HPL);

  for (int l = 0; l < 11; ++l) {
    k_gemm<3, false><<<dim3(256, 8), 256, 0, stream>>>(
        Hbf, 128, HPL, qvWT + (size_t)l * 65536, QVWPL, nullptr, 512, 128,
        qbuf, QPL, kmid, VT64PL, nullptr, 0);
    k_attn1<64><<<dim3(1024), 256, 0, stream>>>(
        qbuf, QPL, Hbf, HPL, (size_t)SEQ * EMB, 0, kmid, VT64PL, head_mask, ao);
    k_sumln<64><<<dim3(4096), 256, 0, stream>>>(
        ao, H, Hbf2, HPL, ln1_g + l * 128, ln1_b + l * 128);
    k_gemm<0, true><<<dim3(256, 8), 256, 0, stream>>>(
        Hbf2, 128, HPL, W1T + (size_t)l * 65536, W1PL, mlp_b1 + l * 512, 512, 128,
        kmid, MIDPL, nullptr, 0, nullptr, 0);
    k_mlp2ln<<<dim3(256), 256, 0, stream>>>(
        kmid, MIDPL, W2T + (size_t)l * 65536, W2PL, mlp_b2 + l * 128,
        H, Hbf, HPL, ln2_g + l * 128, ln2_b + l * 128);
  }
  // last layer
  k_gemm<2, false><<<dim3(256, 24), 256, 0, stream>>>(
      Hbf, 128, HPL, lastT, LASTPL, nullptr, 1536, 128,
      qbuf, QPL, kmid, KMPL, vTl, VTLPL);
  k_attn_fused<128><<<dim3(256), 512, 0, stream>>>(
      qbuf, QPL, kmid, KMPL, (size_t)NHEAD * SEQ * 128, (size_t)SEQ * 128, vTl, VTLPL, head_mask,
      H, Hbf2, HPL, ln1_g + 11 * 128, ln1_b + 11 * 128);
  k_gemm<0, true><<<dim3(256, 8), 256, 0, stream>>>(
      Hbf2, 128, HPL, W1T + (size_t)11 * 65536, W1PL, mlp_b1 + 11 * 512, 512, 128,
      kmid, MIDPL, nullptr, 0, nullptr, 0);
  k_mlp2ln<<<dim3(256), 256, 0, stream>>>(
      kmid, MIDPL, W2T + (size_t)11 * 65536, W2PL, mlp_b2 + 11 * 128,
      H, Hbf, HPL, ln2_g + 11 * 128, ln2_b + 11 * 128);

  k_readout<<<dim3(8192), 64, 0, stream>>>(H, ro_W, ro_b, (float*)d_out);
}

// Round 5
// 2704.511 us; speedup vs baseline: 1.0196x; 1.0196x over previous
//
#include <hip/hip_runtime.h>

#define BS 16
#define SEQ 1024
#define EMB 128
#define NHEAD 4
#define LN_EPS 1e-5f

typedef __attribute__((ext_vector_type(8))) short bf16x8;
typedef __attribute__((ext_vector_type(4))) float f32x4;
typedef __attribute__((ext_vector_type(4))) unsigned short u16x4;

__device__ __forceinline__ unsigned short f2b(float f) {
  union { float f; unsigned u; } v; v.f = f;
  unsigned r = v.u + 0x7fff + ((v.u >> 16) & 1);
  return (unsigned short)(r >> 16);
}
// split x into hi+lo bf16 (3-term Markidis precision: rel err ~2^-17)
__device__ __forceinline__ void split2(float x, unsigned short& hi, unsigned short& lo) {
  unsigned short h = f2b(x);
  float hf = __uint_as_float((unsigned)h << 16);
  hi = h; lo = f2b(x - hf);
}
__device__ __forceinline__ float rsqrt_acc(float v) {
  float r = rsqrtf(v);
  return r * (1.5f - 0.5f * v * r * r);   // one Newton step -> ~f32-exact
}

// ---------------- weight prep ----------------
__global__ void k_transpose_pad(const float* __restrict__ in, unsigned short* __restrict__ out,
                                size_t PL, int L, int Kin, int Nin, int Kout, int Nout) {
  int idx = blockIdx.x * 256 + threadIdx.x;
  int total = L * Kout * Nout;
  if (idx >= total) return;
  int k = idx % Kout;
  int n = (idx / Kout) % Nout;
  int l = idx / (Kout * Nout);
  float v = (k < Kin && n < Nin) ? in[(size_t)l * Kin * Nin + (size_t)k * Nin + n] : 0.f;
  unsigned short hi, lo; split2(v, hi, lo);
  out[idx] = hi; out[PL + idx] = lo;
}

// qvWT[l][512][128]: n<256 -> q (qW rows -> H dims 64..126), n>=256 -> v (H dims 0..62)
__global__ void k_prep_qv(const float* __restrict__ qW, const float* __restrict__ vW,
                          unsigned short* __restrict__ out, size_t PL) {
  int idx = blockIdx.x * 256 + threadIdx.x;
  int total = 11 * 512 * 128;
  if (idx >= total) return;
  int k = idx & 127;
  int n = (idx >> 7) & 511;
  int l = idx >> 16;
  float v = 0.f;
  if (n < 256) {
    if (n < 252 && k >= 64 && k < 127) v = qW[(size_t)l * 63 * 252 + (size_t)(k - 64) * 252 + n];
  } else {
    int n2 = n - 256;
    if (n2 < 252 && k < 63) v = vW[(size_t)l * 63 * 252 + (size_t)k * 252 + n2];
  }
  unsigned short hi, lo; split2(v, hi, lo);
  out[idx] = hi; out[PL + idx] = lo;
}

// ---------------- combine + read_in ----------------
__global__ void k_combine_readin(const float* __restrict__ xs, const float* __restrict__ ys,
                                 const float* __restrict__ W, const float* __restrict__ bias,
                                 float* __restrict__ H, unsigned short* __restrict__ Hbf, size_t hbPl) {
  int blk = blockIdx.x;            // b*1024 + t
  int b = blk >> 10, t = blk & 1023, p = t >> 1;
  __shared__ float zs[64];
  int tid = threadIdx.x;           // 128
  if (tid < 64) {
    float v;
    if (tid < 63) v = xs[((size_t)b * 512 + p) * 63 + tid];
    else v = (t & 1) ? ys[(size_t)b * 512 + p] : 0.f;
    zs[tid] = v;
  }
  __syncthreads();
  float acc = bias[tid];
  #pragma unroll 8
  for (int d = 0; d < 64; ++d) acc += zs[d] * W[d * 128 + tid];
  size_t o = (size_t)blk * 128 + tid;
  H[o] = acc;
  unsigned short hi, lo; split2(acc, hi, lo);
  Hbf[o] = hi; Hbf[hbPl + o] = lo;
}

// ---------------- generic split-precision MFMA GEMM (K compile-time: full unroll) ----------------
// MODE 0: bf16-split out0[row*N+c]
// MODE 2: last qkv (N=1536): q,k normal [b][h][t][128]; v transposed [b][h][d][t]
// MODE 3: qv63 (N=512): c<256 q normal [b][h][t][64] (d63=0); else v transposed [b][h][d][t] (d63=0)
template<int MODE, bool RELU, int K>
__global__ __launch_bounds__(256) void k_gemm(
    const unsigned short* __restrict__ A, int aStride, size_t aPl,
    const unsigned short* __restrict__ BT, size_t bPl, const float* __restrict__ bias,
    int N,
    unsigned short* __restrict__ out0, size_t o0Pl,
    unsigned short* __restrict__ out1, size_t o1Pl,
    unsigned short* __restrict__ out2, size_t o2Pl) {
  int wid = threadIdx.x >> 6, lane = threadIdx.x & 63;
  int lr = lane & 15, lg = lane >> 4;
  int row0 = blockIdx.x * 64 + wid * 16;
  int n0 = blockIdx.y * 64;
  f32x4 acc[4] = {};
  const unsigned short* aP = A + (size_t)(row0 + lr) * aStride + lg * 8;
  const unsigned short* bP = BT + (size_t)n0 * K + lg * 8;
  #pragma unroll
  for (int k0 = 0; k0 < K; k0 += 32) {
    bf16x8 ah = *reinterpret_cast<const bf16x8*>(aP + k0);
    bf16x8 al = *reinterpret_cast<const bf16x8*>(aP + aPl + k0);
    #pragma unroll
    for (int nf = 0; nf < 4; ++nf) {
      const unsigned short* bpp = bP + (size_t)(nf * 16 + lr) * K + k0;
      bf16x8 bh = *reinterpret_cast<const bf16x8*>(bpp);
      bf16x8 bl = *reinterpret_cast<const bf16x8*>(bpp + bPl);
      acc[nf] = __builtin_amdgcn_mfma_f32_16x16x32_bf16(ah, bh, acc[nf], 0, 0, 0);
      acc[nf] = __builtin_amdgcn_mfma_f32_16x16x32_bf16(al, bh, acc[nf], 0, 0, 0);
      acc[nf] = __builtin_amdgcn_mfma_f32_16x16x32_bf16(ah, bl, acc[nf], 0, 0, 0);
    }
  }
  int rowb = row0 + lg * 4;
  #pragma unroll
  for (int nf = 0; nf < 4; ++nf) {
    int c = n0 + nf * 16 + lr;
    float bv = bias ? bias[c] : 0.f;
    float vr[4];
    #pragma unroll
    for (int r = 0; r < 4; ++r) {
      float v = acc[nf][r] + bv;
      vr[r] = RELU ? fmaxf(v, 0.f) : v;
    }
    if (MODE == 0) {
      #pragma unroll
      for (int r = 0; r < 4; ++r) {
        unsigned short hi, lo; split2(vr[r], hi, lo);
        size_t o = (size_t)(rowb + r) * N + c;
        out0[o] = hi; out0[o0Pl + o] = lo;
      }
    } else if (MODE == 2) {
      int tsel = c >> 9, c2 = c & 511, hh = c2 >> 7, d = c2 & 127;
      int b = rowb >> 10, t = rowb & 1023;
      size_t bh = (size_t)b * NHEAD + hh;
      if (tsel < 2) {
        unsigned short* base = tsel ? out1 : out0;
        size_t pl = tsel ? o1Pl : o0Pl;
        #pragma unroll
        for (int r = 0; r < 4; ++r) {
          unsigned short hi, lo; split2(vr[r], hi, lo);
          size_t o = (bh * SEQ + (size_t)(t + r)) * 128 + d;
          base[o] = hi; base[pl + o] = lo;
        }
      } else {
        u16x4 hv, lv;
        #pragma unroll
        for (int r = 0; r < 4; ++r) { unsigned short hi, lo; split2(vr[r], hi, lo); hv[r] = hi; lv[r] = lo; }
        size_t addr = (bh * 128 + d) * SEQ + t;
        *reinterpret_cast<u16x4*>(out2 + addr) = hv;
        *reinterpret_cast<u16x4*>(out2 + o2Pl + addr) = lv;
      }
    } else {  // MODE 3
      int b = rowb >> 10, t = rowb & 1023;
      if (c < 256) {
        int hh, d; bool pad = (c >= 252);
        if (!pad) { hh = c / 63; d = c - hh * 63; } else { hh = c - 252; d = 63; }
        size_t bh = (size_t)b * NHEAD + hh;
        #pragma unroll
        for (int r = 0; r < 4; ++r) {
          float v = pad ? 0.f : vr[r];
          unsigned short hi, lo; split2(v, hi, lo);
          size_t o = (bh * SEQ + (size_t)(t + r)) * 64 + d;
          out0[o] = hi; out0[o0Pl + o] = lo;
        }
      } else {
        int cc = c - 256; int hh, d; bool pad = (cc >= 252);
        if (!pad) { hh = cc / 63; d = cc - hh * 63; } else { hh = cc - 252; d = 63; }
        size_t bh = (size_t)b * NHEAD + hh;
        u16x4 hv, lv;
        #pragma unroll
        for (int r = 0; r < 4; ++r) {
          float v = pad ? 0.f : vr[r];
          unsigned short hi, lo; split2(v, hi, lo); hv[r] = hi; lv[r] = lo;
        }
        size_t addr = (bh * 64 + d) * SEQ + t;
        *reinterpret_cast<u16x4*>(out1 + addr) = hv;
        *reinterpret_cast<u16x4*>(out1 + o1Pl + addr) = lv;
      }
    }
  }
}

// ---------------- attention pass 1: pipelined j-loop ----------------
// Block = (b,h,pair), 4 j-split waves. K double-buffered in regs (issued one step
// ahead); V issued at step top before QK compute. Parallel LDS tree head-sum.
// Writes per-head scaled attn-out f32 to ao[b][h][t][DHEAD].
template<int DHEAD>
__global__ __launch_bounds__(256) void k_attn1(
    const unsigned short* __restrict__ q, size_t qPl,
    const unsigned short* __restrict__ kbase, size_t kPl, size_t kBStride, size_t kHStride,
    const unsigned short* __restrict__ vT, size_t vPl,
    const float* __restrict__ head_mask,
    float* __restrict__ ao) {
  constexpr int KF = DHEAD / 32, NFO = DHEAD / 16;
  constexpr int NT = SEQ / 32;
  constexpr int SSB = 4 * 2 * 32 * 40 * 2;          // 20 KB (S tiles)
  constexpr int FAB = 4 * 32 * DHEAD * 4;           // 32 KB @ D64 (per-grp f32 partials)
  constexpr int SH_BYTES = (SSB > FAB) ? SSB : FAB;
  int bid = blockIdx.x;
  int xcd = bid & 7, u = bid >> 3;       // u in [0,128)
  int b = xcd * 2 + (u >> 6);
  int rem = u & 63;
  int h = rem >> 4, pidx = rem & 15;
  int grp = threadIdx.x >> 6, lane = threadIdx.x & 63;
  int lr = lane & 15, lg = lane >> 4;
  __shared__ __align__(16) char shraw[SH_BYTES];
  typedef unsigned short SArr[2][32][40];
  SArr* sS = (SArr*)shraw;             // sS[grp][plane][r][c]
  const unsigned short* qh = q + (size_t)(b * NHEAD + h) * SEQ * DHEAD;
  const unsigned short* kh = kbase + (size_t)b * kBStride + (size_t)h * kHStride;
  const unsigned short* vh = vT + (size_t)(b * NHEAD + h) * DHEAD * SEQ;
  float hm = head_mask[h];
  float hm3 = hm * hm * hm;

  for (int s = 0; s < 2; ++s) {
    int tile = (s == 0) ? pidx : (NT - 1 - pidx);
    int i0 = tile * 32;
    bf16x8 qfh[2][KF], qfl[2][KF];
    #pragma unroll
    for (int mf = 0; mf < 2; ++mf)
      #pragma unroll
      for (int kf = 0; kf < KF; ++kf) {
        const unsigned short* qp = qh + (size_t)(i0 + mf * 16 + lr) * DHEAD + kf * 32 + lg * 8;
        qfh[mf][kf] = *reinterpret_cast<const bf16x8*>(qp);
        qfl[mf][kf] = *reinterpret_cast<const bf16x8*>(qp + qPl);
      }
    f32x4 oacc[2][NFO] = {};
    int jend = i0 + 32;
    int j0 = grp * 32;
    bf16x8 kch[2][KF], kcl[2][KF];
    if (j0 < jend) {   // wave-uniform
      #pragma unroll
      for (int nf2 = 0; nf2 < 2; ++nf2)
        #pragma unroll
        for (int kf = 0; kf < KF; ++kf) {
          const unsigned short* kp = kh + (size_t)(j0 + nf2 * 16 + lr) * EMB + kf * 32 + lg * 8;
          kch[nf2][kf] = *reinterpret_cast<const bf16x8*>(kp);
          kcl[nf2][kf] = *reinterpret_cast<const bf16x8*>(kp + kPl);
        }
    }
    for (; j0 < jend; j0 += 128) {
      // V for current step: issue before QK compute (hidden under it)
      bf16x8 vch[NFO], vcl[NFO];
      #pragma unroll
      for (int nf = 0; nf < NFO; ++nf) {
        const unsigned short* vp = vh + (size_t)(nf * 16 + lr) * SEQ + j0 + lg * 8;
        vch[nf] = *reinterpret_cast<const bf16x8*>(vp);
        vcl[nf] = *reinterpret_cast<const bf16x8*>(vp + vPl);
      }
      // K for next step: issue now, consume next iteration
      int jn = j0 + 128;
      bf16x8 knh[2][KF], knl[2][KF];
      if (jn < jend) {   // wave-uniform
        #pragma unroll
        for (int nf2 = 0; nf2 < 2; ++nf2)
          #pragma unroll
          for (int kf = 0; kf < KF; ++kf) {
            const unsigned short* kp = kh + (size_t)(jn + nf2 * 16 + lr) * EMB + kf * 32 + lg * 8;
            knh[nf2][kf] = *reinterpret_cast<const bf16x8*>(kp);
            knl[nf2][kf] = *reinterpret_cast<const bf16x8*>(kp + kPl);
          }
      }
      // QK^T -> relu -> causal mask -> split -> LDS
      #pragma unroll
      for (int nf2 = 0; nf2 < 2; ++nf2) {
        #pragma unroll
        for (int mf = 0; mf < 2; ++mf) {
          f32x4 sacc = {};
          #pragma unroll
          for (int kf = 0; kf < KF; ++kf) {
            sacc = __builtin_amdgcn_mfma_f32_16x16x32_bf16(qfh[mf][kf], kch[nf2][kf], sacc, 0, 0, 0);
            sacc = __builtin_amdgcn_mfma_f32_16x16x32_bf16(qfl[mf][kf], kch[nf2][kf], sacc, 0, 0, 0);
            sacc = __builtin_amdgcn_mfma_f32_16x16x32_bf16(qfh[mf][kf], kcl[nf2][kf], sacc, 0, 0, 0);
          }
          #pragma unroll
          for (int r = 0; r < 4; ++r) {
            int i = i0 + mf * 16 + lg * 4 + r;
            int j = j0 + nf2 * 16 + lr;
            float v = (j <= i) ? fmaxf(sacc[r], 0.f) : 0.f;
            unsigned short shi, slo; split2(v, shi, slo);
            sS[grp][0][mf * 16 + lg * 4 + r][nf2 * 16 + lr] = shi;
            sS[grp][1][mf * 16 + lg * 4 + r][nf2 * 16 + lr] = slo;
          }
        }
      }
      asm volatile("s_waitcnt lgkmcnt(0)" ::: "memory");
      __builtin_amdgcn_sched_barrier(0);
      // PV
      #pragma unroll
      for (int mf = 0; mf < 2; ++mf) {
        bf16x8 sfh = *reinterpret_cast<const bf16x8*>(&sS[grp][0][mf * 16 + lr][lg * 8]);
        bf16x8 sfl = *reinterpret_cast<const bf16x8*>(&sS[grp][1][mf * 16 + lr][lg * 8]);
        #pragma unroll
        for (int nf = 0; nf < NFO; ++nf) {
          oacc[mf][nf] = __builtin_amdgcn_mfma_f32_16x16x32_bf16(sfh, vch[nf], oacc[mf][nf], 0, 0, 0);
          oacc[mf][nf] = __builtin_amdgcn_mfma_f32_16x16x32_bf16(sfl, vch[nf], oacc[mf][nf], 0, 0, 0);
          oacc[mf][nf] = __builtin_amdgcn_mfma_f32_16x16x32_bf16(sfh, vcl[nf], oacc[mf][nf], 0, 0, 0);
        }
      }
      // rotate K buffers
      if (jn < jend) {
        #pragma unroll
        for (int nf2 = 0; nf2 < 2; ++nf2)
          #pragma unroll
          for (int kf = 0; kf < KF; ++kf) {
            kch[nf2][kf] = knh[nf2][kf];
            kcl[nf2][kf] = knl[nf2][kf];
          }
      }
    }
    // ---- parallel head(j-group)-sum via LDS tree ----
    __syncthreads();   // all grps done reading their sS (f0 aliases it)
    float* f0 = (float*)shraw;     // [4][32][DHEAD] per-grp partials
    #pragma unroll
    for (int mf = 0; mf < 2; ++mf)
      #pragma unroll
      for (int nf = 0; nf < NFO; ++nf)
        #pragma unroll
        for (int r = 0; r < 4; ++r)
          f0[(grp * 32 + mf * 16 + lg * 4 + r) * DHEAD + nf * 16 + lr] = oacc[mf][nf][r];
    __syncthreads();
    for (int idx = threadIdx.x; idx < 2 * 32 * DHEAD; idx += 256)
      f0[idx] += f0[idx + 2 * 32 * DHEAD];
    __syncthreads();
    for (int idx = threadIdx.x; idx < 32 * DHEAD; idx += 256) {
      int rr = idx / DHEAD;
      float val = (f0[idx] + f0[idx + 32 * DHEAD]) * hm3 / (float)(i0 + rr + 1);
      ao[((size_t)(b * NHEAD + h) * SEQ + i0) * DHEAD + idx] = val;
    }
    __syncthreads();   // before next s reuses sS
  }
}

// ---------------- attention pass 2: head-sum + residual + LN1 ----------------
template<int DHEAD>
__global__ __launch_bounds__(256) void k_sumln(
    const float* __restrict__ ao,
    float* __restrict__ Hst, unsigned short* __restrict__ HbfOut, size_t hbPl,
    const float* __restrict__ g, const float* __restrict__ bta) {
  int wid = threadIdx.x >> 6, lane = threadIdx.x & 63;
  int t = blockIdx.x * 4 + wid;
  int b = t >> 10, tt = t & 1023;
  float a0 = 0.f, a1 = 0.f;
  #pragma unroll
  for (int h = 0; h < NHEAD; ++h) {
    const float* ap = ao + ((size_t)(b * NHEAD + h) * SEQ + tt) * DHEAD;
    if (DHEAD == 64) a1 += ap[lane];
    else { a0 += ap[lane]; a1 += ap[lane + 64]; }
  }
  size_t row = (size_t)t * EMB;
  int c0 = lane, c1 = lane + 64;
  float x0 = Hst[row + c0] + a0;
  float x1 = Hst[row + c1] + a1;
  float s1 = x0 + x1, s2 = x0 * x0 + x1 * x1;
  #pragma unroll
  for (int off = 1; off < 64; off <<= 1) {
    s1 += __shfl_xor(s1, off);
    s2 += __shfl_xor(s2, off);
  }
  float mu = s1 * (1.f / 128.f);
  float var = s2 * (1.f / 128.f) - mu * mu;
  float rs = rsqrt_acc(var + LN_EPS);
  float y0 = (x0 - mu) * rs * g[c0] + bta[c0];
  float y1 = (x1 - mu) * rs * g[c1] + bta[c1];
  Hst[row + c0] = y0; Hst[row + c1] = y1;
  unsigned short h0, l0, h1, l1; split2(y0, h0, l0); split2(y1, h1, l1);
  HbfOut[row + c0] = h0; HbfOut[hbPl + row + c0] = l0;
  HbfOut[row + c1] = h1; HbfOut[hbPl + row + c1] = l1;
}

// ---------------- fused attention (+LN1), last layer (DHEAD=128), 8-wave ----------------
template<int DHEAD>
__global__ __launch_bounds__(512) void k_attn_fused(
    const unsigned short* __restrict__ q, size_t qPl,
    const unsigned short* __restrict__ kbase, size_t kPl, size_t kBStride, size_t kHStride,
    const unsigned short* __restrict__ vT, size_t vPl,
    const float* __restrict__ head_mask,
    float* __restrict__ Hst, unsigned short* __restrict__ HbfOut, size_t hbPl,
    const float* __restrict__ g, const float* __restrict__ bta) {
  constexpr int KF = DHEAD / 32, NFO = DHEAD / 16;
  constexpr int NT = SEQ / 32;
  constexpr int SSB = 8 * 2 * 32 * 40 * 2;   // 40 KB
  constexpr int SH_BYTES = (SSB > 32 * DHEAD * 4) ? SSB : 32 * DHEAD * 4;
  int bid = blockIdx.x;
  int xcd = bid & 7, u = bid >> 3;
  int b = xcd * 2 + (u >> 4);
  int pidx = u & 15;
  int wid = threadIdx.x >> 6, lane = threadIdx.x & 63;
  int h = wid & 3, grp = wid >> 2;
  int lr = lane & 15, lg = lane >> 4;
  __shared__ __align__(16) char shraw[SH_BYTES];
  typedef unsigned short SArr[2][32][40];
  SArr* sS = (SArr*)shraw;
  typedef float FRow[DHEAD];
  FRow* facc = (FRow*)shraw;
  const unsigned short* qh = q + (size_t)(b * NHEAD + h) * SEQ * DHEAD;
  const unsigned short* kh = kbase + (size_t)b * kBStride + (size_t)h * kHStride;
  const unsigned short* vh = vT + (size_t)(b * NHEAD + h) * DHEAD * SEQ;
  float hm = head_mask[h];
  float hm3 = hm * hm * hm;

  for (int s = 0; s < 2; ++s) {
    int tile = (s == 0) ? pidx : (NT - 1 - pidx);
    int i0 = tile * 32;
    bf16x8 qfh[2][KF], qfl[2][KF];
    #pragma unroll
    for (int mf = 0; mf < 2; ++mf)
      #pragma unroll
      for (int kf = 0; kf < KF; ++kf) {
        const unsigned short* qp = qh + (size_t)(i0 + mf * 16 + lr) * DHEAD + kf * 32 + lg * 8;
        qfh[mf][kf] = *reinterpret_cast<const bf16x8*>(qp);
        qfl[mf][kf] = *reinterpret_cast<const bf16x8*>(qp + qPl);
      }
    f32x4 oacc[2][NFO] = {};
    int jend = i0 + 32;
    for (int j0 = grp * 32; j0 < jend; j0 += 64) {
      #pragma unroll
      for (int nf2 = 0; nf2 < 2; ++nf2) {
        int j16 = j0 + nf2 * 16;
        bf16x8 kfh[KF], kfl[KF];
        #pragma unroll
        for (int kf = 0; kf < KF; ++kf) {
          const unsigned short* kp = kh + (size_t)(j16 + lr) * EMB + kf * 32 + lg * 8;
          kfh[kf] = *reinterpret_cast<const bf16x8*>(kp);
          kfl[kf] = *reinterpret_cast<const bf16x8*>(kp + kPl);
        }
        #pragma unroll
        for (int mf = 0; mf < 2; ++mf) {
          f32x4 sacc = {};
          #pragma unroll
          for (int kf = 0; kf < KF; ++kf) {
            sacc = __builtin_amdgcn_mfma_f32_16x16x32_bf16(qfh[mf][kf], kfh[kf], sacc, 0, 0, 0);
            sacc = __builtin_amdgcn_mfma_f32_16x16x32_bf16(qfl[mf][kf], kfh[kf], sacc, 0, 0, 0);
            sacc = __builtin_amdgcn_mfma_f32_16x16x32_bf16(qfh[mf][kf], kfl[kf], sacc, 0, 0, 0);
          }
          #pragma unroll
          for (int r = 0; r < 4; ++r) {
            int i = i0 + mf * 16 + lg * 4 + r;
            int j = j16 + lr;
            float v = (j <= i) ? fmaxf(sacc[r], 0.f) : 0.f;
            unsigned short shi, slo; split2(v, shi, slo);
            sS[wid][0][mf * 16 + lg * 4 + r][nf2 * 16 + lr] = shi;
            sS[wid][1][mf * 16 + lg * 4 + r][nf2 * 16 + lr] = slo;
          }
        }
      }
      asm volatile("s_waitcnt lgkmcnt(0)" ::: "memory");
      __builtin_amdgcn_sched_barrier(0);
      #pragma unroll
      for (int mf = 0; mf < 2; ++mf) {
        bf16x8 sfh = *reinterpret_cast<const bf16x8*>(&sS[wid][0][mf * 16 + lr][lg * 8]);
        bf16x8 sfl = *reinterpret_cast<const bf16x8*>(&sS[wid][1][mf * 16 + lr][lg * 8]);
        #pragma unroll
        for (int nf = 0; nf < NFO; ++nf) {
          const unsigned short* vp = vh + (size_t)(nf * 16 + lr) * SEQ + j0 + lg * 8;
          bf16x8 vfh = *reinterpret_cast<const bf16x8*>(vp);
          bf16x8 vfl = *reinterpret_cast<const bf16x8*>(vp + vPl);
          oacc[mf][nf] = __builtin_amdgcn_mfma_f32_16x16x32_bf16(sfh, vfh, oacc[mf][nf], 0, 0, 0);
          oacc[mf][nf] = __builtin_amdgcn_mfma_f32_16x16x32_bf16(sfl, vfh, oacc[mf][nf], 0, 0, 0);
          oacc[mf][nf] = __builtin_amdgcn_mfma_f32_16x16x32_bf16(sfh, vfl, oacc[mf][nf], 0, 0, 0);
        }
      }
    }
    __syncthreads();
    for (int x = threadIdx.x; x < 32 * DHEAD; x += 512) ((float*)shraw)[x] = 0.f;
    __syncthreads();
    for (int w = 0; w < 8; ++w) {
      if (wid == w) {
        #pragma unroll
        for (int mf = 0; mf < 2; ++mf)
          #pragma unroll
          for (int nf = 0; nf < NFO; ++nf)
            #pragma unroll
            for (int r = 0; r < 4; ++r) {
              int rr = mf * 16 + lg * 4 + r;
              facc[rr][nf * 16 + lr] += oacc[mf][nf][r] * hm3 / (float)(i0 + rr + 1);
            }
      }
      __syncthreads();
    }
    for (int rl = 0; rl < 4; ++rl) {
      int rr = wid * 4 + rl;
      size_t row = ((size_t)b * SEQ + i0 + rr) * EMB;
      int c0 = lane, c1 = lane + 64;
      float a0 = (DHEAD == 128) ? facc[rr][c0] : 0.f;
      float a1 = (DHEAD == 128) ? facc[rr][c1] : facc[rr][lane];
      float x0 = Hst[row + c0] + a0;
      float x1 = Hst[row + c1] + a1;
      float s1 = x0 + x1, s2 = x0 * x0 + x1 * x1;
      #pragma unroll
      for (int off = 1; off < 64; off <<= 1) {
        s1 += __shfl_xor(s1, off);
        s2 += __shfl_xor(s2, off);
      }
      float mu = s1 * (1.f / 128.f);
      float var = s2 * (1.f / 128.f) - mu * mu;
      float rs = rsqrt_acc(var + LN_EPS);
      float y0 = (x0 - mu) * rs * g[c0] + bta[c0];
      float y1 = (x1 - mu) * rs * g[c1] + bta[c1];
      Hst[row + c0] = y0; Hst[row + c1] = y1;
      unsigned short h0, l0, h1, l1; split2(y0, h0, l0); split2(y1, h1, l1);
      HbfOut[row + c0] = h0; HbfOut[hbPl + row + c0] = l0;
      HbfOut[row + c1] = h1; HbfOut[hbPl + row + c1] = l1;
    }
    __syncthreads();
  }
}

// ---------------- fused MLP2 + residual + LN2 ----------------
__global__ __launch_bounds__(256) void k_mlp2ln(
    const unsigned short* __restrict__ A, size_t aPl,
    const unsigned short* __restrict__ BT, size_t bPl, const float* __restrict__ bias,
    float* __restrict__ Hst, unsigned short* __restrict__ HbfOut, size_t hbPl,
    const float* __restrict__ g, const float* __restrict__ bta) {
  int wid = threadIdx.x >> 6, lane = threadIdx.x & 63;
  int lr = lane & 15, lg = lane >> 4;
  int row0 = blockIdx.x * 64 + wid * 16;
  f32x4 acc[8] = {};
  const unsigned short* aP = A + (size_t)(row0 + lr) * 512 + lg * 8;
  const unsigned short* bP = BT + lg * 8;
  for (int k0 = 0; k0 < 512; k0 += 32) {
    bf16x8 ah = *reinterpret_cast<const bf16x8*>(aP + k0);
    bf16x8 al = *reinterpret_cast<const bf16x8*>(aP + aPl + k0);
    #pragma unroll
    for (int nf = 0; nf < 8; ++nf) {
      const unsigned short* bpp = bP + (size_t)(nf * 16 + lr) * 512 + k0;
      bf16x8 bh = *reinterpret_cast<const bf16x8*>(bpp);
      bf16x8 bl = *reinterpret_cast<const bf16x8*>(bpp + bPl);
      acc[nf] = __builtin_amdgcn_mfma_f32_16x16x32_bf16(ah, bh, acc[nf], 0, 0, 0);
      acc[nf] = __builtin_amdgcn_mfma_f32_16x16x32_bf16(al, bh, acc[nf], 0, 0, 0);
      acc[nf] = __builtin_amdgcn_mfma_f32_16x16x32_bf16(ah, bl, acc[nf], 0, 0, 0);
    }
  }
  int rowb = row0 + lg * 4;
  float xv[8][4];
  float s1[4] = {}, s2[4] = {};
  #pragma unroll
  for (int nf = 0; nf < 8; ++nf) {
    int c = nf * 16 + lr;
    float bv = bias[c];
    #pragma unroll
    for (int r = 0; r < 4; ++r) {
      float x = acc[nf][r] + bv + Hst[(size_t)(rowb + r) * EMB + c];
      xv[nf][r] = x; s1[r] += x; s2[r] += x * x;
    }
  }
  #pragma unroll
  for (int off = 1; off < 16; off <<= 1) {
    #pragma unroll
    for (int r = 0; r < 4; ++r) {
      s1[r] += __shfl_xor(s1[r], off);
      s2[r] += __shfl_xor(s2[r], off);
    }
  }
  #pragma unroll
  for (int r = 0; r < 4; ++r) {
    float mu = s1[r] * (1.f / 128.f);
    float var = s2[r] * (1.f / 128.f) - mu * mu;
    float rs = rsqrt_acc(var + LN_EPS);
    #pragma unroll
    for (int nf = 0; nf < 8; ++nf) {
      int c = nf * 16 + lr;
      float y = (xv[nf][r] - mu) * rs * g[c] + bta[c];
      size_t o = (size_t)(rowb + r) * EMB + c;
      Hst[o] = y;
      unsigned short hi, lo; split2(y, hi, lo);
      HbfOut[o] = hi; HbfOut[hbPl + o] = lo;
    }
  }
}

// ---------------- readout ----------------
__global__ __launch_bounds__(64) void k_readout(const float* __restrict__ H,
                                                const float* __restrict__ W, const float* __restrict__ b0,
                                                float* __restrict__ out) {
  int idx = blockIdx.x;           // b*512 + p
  int b = idx >> 9, p = idx & 511;
  size_t row = ((size_t)b * SEQ + 2 * p) * EMB;
  int lane = threadIdx.x;
  float acc = H[row + lane] * W[lane] + H[row + 64 + lane] * W[64 + lane];
  #pragma unroll
  for (int off = 1; off < 64; off <<= 1) acc += __shfl_xor(acc, off);
  if (lane == 0) out[idx] = acc + b0[0];
}

extern "C" void kernel_launch(void* const* d_in, const int* in_sizes, int n_in,
                              void* d_out, int out_size, void* d_ws, size_t ws_size,
                              hipStream_t stream) {
  (void)in_sizes; (void)n_in; (void)out_size; (void)ws_size;
  const float* xs        = (const float*)d_in[0];
  const float* ys        = (const float*)d_in[1];
  const float* head_mask = (const float*)d_in[2];
  const float* read_in_W = (const float*)d_in[3];
  const float* read_in_b = (const float*)d_in[4];
  const float* qW        = (const float*)d_in[5];
  const float* vW        = (const float*)d_in[6];
  const float* qW_last   = (const float*)d_in[7];
  const float* kW_last   = (const float*)d_in[8];
  const float* vW_last   = (const float*)d_in[9];
  const float* ln1_g     = (const float*)d_in[10];
  const float* ln1_b     = (const float*)d_in[11];
  const float* ln2_g     = (const float*)d_in[12];
  const float* ln2_b     = (const float*)d_in[13];
  const float* mlp_W1    = (const float*)d_in[14];
  const float* mlp_b1    = (const float*)d_in[15];
  const float* mlp_W2    = (const float*)d_in[16];
  const float* mlp_b2    = (const float*)d_in[17];
  const float* ro_W      = (const float*)d_in[18];
  const float* ro_b      = (const float*)d_in[19];

  const size_t HPL   = (size_t)BS * SEQ * EMB;          // 2M
  const size_t QPL   = (size_t)BS * NHEAD * SEQ * 128;  // 8M
  const size_t VT64PL= (size_t)BS * NHEAD * 64 * SEQ;   // 4M
  const size_t MIDPL = (size_t)BS * SEQ * 512;          // 8M
  const size_t KMPL  = QPL;
  const size_t VTLPL = QPL;
  const size_t QVWPL = (size_t)11 * 512 * 128;
  const size_t W1PL  = (size_t)12 * 128 * 512;
  const size_t W2PL  = (size_t)12 * 512 * 128;
  const size_t LASTPL= (size_t)3 * 512 * 128;

  char* ws = (char*)d_ws;
  size_t off = 0;
  auto alloc = [&](size_t bytes) -> void* {
    void* p = ws + off;
    off += (bytes + 255) & ~(size_t)255;
    return p;
  };
  float* H             = (float*)alloc(HPL * 4);                  // 8 MB (in-place state)
  unsigned short* Hbf  = (unsigned short*)alloc(2 * HPL * 2);     // 8 MB
  unsigned short* Hbf2 = (unsigned short*)alloc(2 * HPL * 2);     // 8 MB
  unsigned short* qbuf = (unsigned short*)alloc(2 * QPL * 2);     // 32 MB
  unsigned short* kmid = (unsigned short*)alloc(2 * KMPL * 2);    // 32 MB (vT64 / mid / K-last)
  unsigned short* vTl  = (unsigned short*)alloc(2 * VTLPL * 2);   // 32 MB (ao f32 layers 0-10; vT last)
  float* ao = (float*)vTl;   // alias: ao (16 MB) lives attn1->sumln; vTl lives only in last layer
  unsigned short* qvWT = (unsigned short*)alloc(2 * QVWPL * 2);
  unsigned short* W1T  = (unsigned short*)alloc(2 * W1PL * 2);
  unsigned short* W2T  = (unsigned short*)alloc(2 * W2PL * 2);
  unsigned short* lastT= (unsigned short*)alloc(2 * LASTPL * 2);

  { int tot = 11 * 512 * 128; k_prep_qv<<<dim3((tot + 255) / 256), 256, 0, stream>>>(qW, vW, qvWT, QVWPL); }
  { int tot = 12 * 512 * 128; k_transpose_pad<<<dim3((tot + 255) / 256), 256, 0, stream>>>(mlp_W1, W1T, W1PL, 12, 128, 512, 128, 512); }
  { int tot = 12 * 128 * 512; k_transpose_pad<<<dim3((tot + 255) / 256), 256, 0, stream>>>(mlp_W2, W2T, W2PL, 12, 512, 128, 512, 128); }
  { int tot = 512 * 128;
    k_transpose_pad<<<dim3((tot + 255) / 256), 256, 0, stream>>>(qW_last, lastT,          LASTPL, 1, 128, 512, 128, 512);
    k_transpose_pad<<<dim3((tot + 255) / 256), 256, 0, stream>>>(kW_last, lastT + 65536,  LASTPL, 1, 128, 512, 128, 512);
    k_transpose_pad<<<dim3((tot + 255) / 256), 256, 0, stream>>>(vW_last, lastT + 131072, LASTPL, 1, 128, 512, 128, 512); }

  k_combine_readin<<<dim3(BS * SEQ), 128, 0, stream>>>(xs, ys, read_in_W, read_in_b, H, Hbf, HPL);

  for (int l = 0; l < 11; ++l) {
    k_gemm<3, false, 128><<<dim3(256, 8), 256, 0, stream>>>(
        Hbf, 128, HPL, qvWT + (size_t)l * 65536, QVWPL, nullptr, 512,
        qbuf, QPL, kmid, VT64PL, nullptr, 0);
    k_attn1<64><<<dim3(1024), 256, 0, stream>>>(
        qbuf, QPL, Hbf, HPL, (size_t)SEQ * EMB, 0, kmid, VT64PL, head_mask, ao);
    k_sumln<64><<<dim3(4096), 256, 0, stream>>>(
        ao, H, Hbf2, HPL, ln1_g + l * 128, ln1_b + l * 128);
    k_gemm<0, true, 128><<<dim3(256, 8), 256, 0, stream>>>(
        Hbf2, 128, HPL, W1T + (size_t)l * 65536, W1PL, mlp_b1 + l * 512, 512,
        kmid, MIDPL, nullptr, 0, nullptr, 0);
    k_mlp2ln<<<dim3(256), 256, 0, stream>>>(
        kmid, MIDPL, W2T + (size_t)l * 65536, W2PL, mlp_b2 + l * 128,
        H, Hbf, HPL, ln2_g + l * 128, ln2_b + l * 128);
  }
  // last layer
  k_gemm<2, false, 128><<<dim3(256, 24), 256, 0, stream>>>(
      Hbf, 128, HPL, lastT, LASTPL, nullptr, 1536,
      qbuf, QPL, kmid, KMPL, vTl, VTLPL);
  k_attn_fused<128><<<dim3(256), 512, 0, stream>>>(
      qbuf, QPL, kmid, KMPL, (size_t)NHEAD * SEQ * 128, (size_t)SEQ * 128, vTl, VTLPL, head_mask,
      H, Hbf2, HPL, ln1_g + 11 * 128, ln1_b + 11 * 128);
  k_gemm<0, true, 128><<<dim3(256, 8), 256, 0, stream>>>(
      Hbf2, 128, HPL, W1T + (size_t)11 * 65536, W1PL, mlp_b1 + 11 * 512, 512,
      kmid, MIDPL, nullptr, 0, nullptr, 0);
  k_mlp2ln<<<dim3(256), 256, 0, stream>>>(
      kmid, MIDPL, W2T + (size_t)11 * 65536, W2PL, mlp_b2 + 11 * 128,
      H, Hbf, HPL, ln2_g + 11 * 128, ln2_b + 11 * 128);

  k_readout<<<dim3(8192), 64, 0, stream>>>(H, ro_W, ro_b, (float*)d_out);
}

// Round 6
// 2424.874 us; speedup vs baseline: 1.1371x; 1.1153x over previous
//
#include <hip/hip_runtime.h>

#define BS 16
#define SEQ 1024
#define EMB 128
#define NHEAD 4
#define LN_EPS 1e-5f

typedef __attribute__((ext_vector_type(8))) short bf16x8;
typedef __attribute__((ext_vector_type(4))) float f32x4;
typedef __attribute__((ext_vector_type(4))) unsigned short u16x4;
typedef __attribute__((ext_vector_type(4))) unsigned int u32x4;

__device__ __forceinline__ unsigned short f2b(float f) {
  union { float f; unsigned u; } v; v.f = f;
  unsigned r = v.u + 0x7fff + ((v.u >> 16) & 1);
  return (unsigned short)(r >> 16);
}
// split x into hi+lo bf16 (3-term Markidis precision: rel err ~2^-17)
__device__ __forceinline__ void split2(float x, unsigned short& hi, unsigned short& lo) {
  unsigned short h = f2b(x);
  float hf = __uint_as_float((unsigned)h << 16);
  hi = h; lo = f2b(x - hf);
}
__device__ __forceinline__ float rsqrt_acc(float v) {
  float r = rsqrtf(v);
  return r * (1.5f - 0.5f * v * r * r);   // one Newton step -> ~f32-exact
}

// ---------------- weight prep ----------------
__global__ void k_transpose_pad(const float* __restrict__ in, unsigned short* __restrict__ out,
                                size_t PL, int L, int Kin, int Nin, int Kout, int Nout) {
  int idx = blockIdx.x * 256 + threadIdx.x;
  int total = L * Kout * Nout;
  if (idx >= total) return;
  int k = idx % Kout;
  int n = (idx / Kout) % Nout;
  int l = idx / (Kout * Nout);
  float v = (k < Kin && n < Nin) ? in[(size_t)l * Kin * Nin + (size_t)k * Nin + n] : 0.f;
  unsigned short hi, lo; split2(v, hi, lo);
  out[idx] = hi; out[PL + idx] = lo;
}

// qvWT[l][512][128]: n<256 -> q (qW rows -> H dims 64..126), n>=256 -> v (H dims 0..62)
__global__ void k_prep_qv(const float* __restrict__ qW, const float* __restrict__ vW,
                          unsigned short* __restrict__ out, size_t PL) {
  int idx = blockIdx.x * 256 + threadIdx.x;
  int total = 11 * 512 * 128;
  if (idx >= total) return;
  int k = idx & 127;
  int n = (idx >> 7) & 511;
  int l = idx >> 16;
  float v = 0.f;
  if (n < 256) {
    if (n < 252 && k >= 64 && k < 127) v = qW[(size_t)l * 63 * 252 + (size_t)(k - 64) * 252 + n];
  } else {
    int n2 = n - 256;
    if (n2 < 252 && k < 63) v = vW[(size_t)l * 63 * 252 + (size_t)k * 252 + n2];
  }
  unsigned short hi, lo; split2(v, hi, lo);
  out[idx] = hi; out[PL + idx] = lo;
}

// ---------------- combine + read_in ----------------
__global__ void k_combine_readin(const float* __restrict__ xs, const float* __restrict__ ys,
                                 const float* __restrict__ W, const float* __restrict__ bias,
                                 float* __restrict__ H, unsigned short* __restrict__ Hbf, size_t hbPl) {
  int blk = blockIdx.x;            // b*1024 + t
  int b = blk >> 10, t = blk & 1023, p = t >> 1;
  __shared__ float zs[64];
  int tid = threadIdx.x;           // 128
  if (tid < 64) {
    float v;
    if (tid < 63) v = xs[((size_t)b * 512 + p) * 63 + tid];
    else v = (t & 1) ? ys[(size_t)b * 512 + p] : 0.f;
    zs[tid] = v;
  }
  __syncthreads();
  float acc = bias[tid];
  #pragma unroll 8
  for (int d = 0; d < 64; ++d) acc += zs[d] * W[d * 128 + tid];
  size_t o = (size_t)blk * 128 + tid;
  H[o] = acc;
  unsigned short hi, lo; split2(acc, hi, lo);
  Hbf[o] = hi; Hbf[hbPl + o] = lo;
}

// ---------------- generic split-precision MFMA GEMM (K compile-time) ----------------
template<int MODE, bool RELU, int K>
__global__ __launch_bounds__(256) void k_gemm(
    const unsigned short* __restrict__ A, int aStride, size_t aPl,
    const unsigned short* __restrict__ BT, size_t bPl, const float* __restrict__ bias,
    int N,
    unsigned short* __restrict__ out0, size_t o0Pl,
    unsigned short* __restrict__ out1, size_t o1Pl,
    unsigned short* __restrict__ out2, size_t o2Pl) {
  int wid = threadIdx.x >> 6, lane = threadIdx.x & 63;
  int lr = lane & 15, lg = lane >> 4;
  int row0 = blockIdx.x * 64 + wid * 16;
  int n0 = blockIdx.y * 64;
  f32x4 acc[4] = {};
  const unsigned short* aP = A + (size_t)(row0 + lr) * aStride + lg * 8;
  const unsigned short* bP = BT + (size_t)n0 * K + lg * 8;
  #pragma unroll
  for (int k0 = 0; k0 < K; k0 += 32) {
    bf16x8 ah = *reinterpret_cast<const bf16x8*>(aP + k0);
    bf16x8 al = *reinterpret_cast<const bf16x8*>(aP + aPl + k0);
    #pragma unroll
    for (int nf = 0; nf < 4; ++nf) {
      const unsigned short* bpp = bP + (size_t)(nf * 16 + lr) * K + k0;
      bf16x8 bh = *reinterpret_cast<const bf16x8*>(bpp);
      bf16x8 bl = *reinterpret_cast<const bf16x8*>(bpp + bPl);
      acc[nf] = __builtin_amdgcn_mfma_f32_16x16x32_bf16(ah, bh, acc[nf], 0, 0, 0);
      acc[nf] = __builtin_amdgcn_mfma_f32_16x16x32_bf16(al, bh, acc[nf], 0, 0, 0);
      acc[nf] = __builtin_amdgcn_mfma_f32_16x16x32_bf16(ah, bl, acc[nf], 0, 0, 0);
    }
  }
  int rowb = row0 + lg * 4;
  #pragma unroll
  for (int nf = 0; nf < 4; ++nf) {
    int c = n0 + nf * 16 + lr;
    float bv = bias ? bias[c] : 0.f;
    float vr[4];
    #pragma unroll
    for (int r = 0; r < 4; ++r) {
      float v = acc[nf][r] + bv;
      vr[r] = RELU ? fmaxf(v, 0.f) : v;
    }
    if (MODE == 0) {
      #pragma unroll
      for (int r = 0; r < 4; ++r) {
        unsigned short hi, lo; split2(vr[r], hi, lo);
        size_t o = (size_t)(rowb + r) * N + c;
        out0[o] = hi; out0[o0Pl + o] = lo;
      }
    } else if (MODE == 2) {
      int tsel = c >> 9, c2 = c & 511, hh = c2 >> 7, d = c2 & 127;
      int b = rowb >> 10, t = rowb & 1023;
      size_t bh = (size_t)b * NHEAD + hh;
      if (tsel < 2) {
        unsigned short* base = tsel ? out1 : out0;
        size_t pl = tsel ? o1Pl : o0Pl;
        #pragma unroll
        for (int r = 0; r < 4; ++r) {
          unsigned short hi, lo; split2(vr[r], hi, lo);
          size_t o = (bh * SEQ + (size_t)(t + r)) * 128 + d;
          base[o] = hi; base[pl + o] = lo;
        }
      } else {
        u16x4 hv, lv;
        #pragma unroll
        for (int r = 0; r < 4; ++r) { unsigned short hi, lo; split2(vr[r], hi, lo); hv[r] = hi; lv[r] = lo; }
        size_t addr = (bh * 128 + d) * SEQ + t;
        *reinterpret_cast<u16x4*>(out2 + addr) = hv;
        *reinterpret_cast<u16x4*>(out2 + o2Pl + addr) = lv;
      }
    } else {  // MODE 3
      int b = rowb >> 10, t = rowb & 1023;
      if (c < 256) {
        int hh, d; bool pad = (c >= 252);
        if (!pad) { hh = c / 63; d = c - hh * 63; } else { hh = c - 252; d = 63; }
        size_t bh = (size_t)b * NHEAD + hh;
        #pragma unroll
        for (int r = 0; r < 4; ++r) {
          float v = pad ? 0.f : vr[r];
          unsigned short hi, lo; split2(v, hi, lo);
          size_t o = (bh * SEQ + (size_t)(t + r)) * 64 + d;
          out0[o] = hi; out0[o0Pl + o] = lo;
        }
      } else {
        int cc = c - 256; int hh, d; bool pad = (cc >= 252);
        if (!pad) { hh = cc / 63; d = cc - hh * 63; } else { hh = cc - 252; d = 63; }
        size_t bh = (size_t)b * NHEAD + hh;
        u16x4 hv, lv;
        #pragma unroll
        for (int r = 0; r < 4; ++r) {
          float v = pad ? 0.f : vr[r];
          unsigned short hi, lo; split2(v, hi, lo); hv[r] = hi; lv[r] = lo;
        }
        size_t addr = (bh * 64 + d) * SEQ + t;
        *reinterpret_cast<u16x4*>(out1 + addr) = hv;
        *reinterpret_cast<u16x4*>(out1 + o1Pl + addr) = lv;
      }
    }
  }
}

// ---------------- attention v6 (layers 0-10, D=64): K LDS-staged, shared across heads+tiles ----------------
// Block = (b, pair). 8 waves = 4 heads x 2 j-groups. Per 64-key superstep:
// stage K (Hbf rows, hi+lo) coalesced -> LDS (XOR-swizzled, double-buffered),
// each wave loads V frags once and runs QK/PV substeps for BOTH q-tiles.
// Fused head-sum (LDS tree) + residual + LN1.
__global__ __launch_bounds__(512) void k_attn_v6(
    const unsigned short* __restrict__ q, size_t qPl,
    const unsigned short* __restrict__ Hbf, size_t hPl,
    const unsigned short* __restrict__ vT, size_t vPl,
    const float* __restrict__ head_mask,
    float* __restrict__ Hst, unsigned short* __restrict__ HbfOut, size_t hbPl,
    const float* __restrict__ g, const float* __restrict__ bta) {
  extern __shared__ char sh[];             // 64KB Kbuf[2] + 40KB sS
  int bid = blockIdx.x;
  int xcd = bid & 7, u = bid >> 3;
  int b = xcd * 2 + (u >> 4);
  int pidx = u & 15;
  int tid = threadIdx.x;
  int wid = tid >> 6, lane = tid & 63;
  int h = wid & 3, grp = wid >> 2;
  int lr = lane & 15, lg = lane >> 4;
  int i0t[2] = { pidx * 32, (31 - pidx) * 32 };
  int NSS = (33 - pidx) >> 1;              // supersteps of 64 keys

  const char* gK = (const char*)(Hbf + (size_t)b * SEQ * EMB);
  const size_t loOffB = hPl * 2;           // bytes to lo plane of Hbf
  char* KBc = sh;
  unsigned short* sw = (unsigned short*)(sh + 65536 + wid * 5120);  // [2][32][40]

  const unsigned short* qh = q + (size_t)(b * NHEAD + h) * SEQ * 64;
  const unsigned short* vh = vT + (size_t)(b * NHEAD + h) * 64 * SEQ;

  // Q fragments for both tiles (resident)
  bf16x8 qfh[2][2][2], qfl[2][2][2];       // [tile][mf][kf]
  #pragma unroll
  for (int t = 0; t < 2; ++t)
    #pragma unroll
    for (int mf = 0; mf < 2; ++mf)
      #pragma unroll
      for (int kf = 0; kf < 2; ++kf) {
        const unsigned short* qp = qh + (size_t)(i0t[t] + mf * 16 + lr) * 64 + kf * 32 + lg * 8;
        qfh[t][mf][kf] = *reinterpret_cast<const bf16x8*>(qp);
        qfl[t][mf][kf] = *reinterpret_cast<const bf16x8*>(qp + qPl);
      }
  f32x4 oacc[2][2][4] = {};                // [tile][mf][nf]

  u32x4 sreg[4];
  auto SLOAD = [&](int ss) {
    size_t base = (size_t)ss * 16384;
    #pragma unroll
    for (int c = 0; c < 4; ++c) {
      int po = tid * 16 + (c & 1) * 8192;
      const char* src = gK + ((c >> 1) ? loOffB : 0) + base + po;
      sreg[c] = *reinterpret_cast<const u32x4*>(src);
    }
  };
  auto SWRITE = [&](int buf) {
    #pragma unroll
    for (int c = 0; c < 4; ++c) {
      int po = tid * 16 + (c & 1) * 8192;
      int dst = buf * 32768 + (c >> 1) * 16384 + (po ^ (((po >> 8) & 7) << 4));
      *reinterpret_cast<u32x4*>(KBc + dst) = sreg[c];
    }
  };

  SLOAD(0); SWRITE(0);
  __syncthreads();

  for (int ss = 0; ss < NSS; ++ss) {
    int cur = ss & 1;
    bool more = (ss + 1 < NSS);
    if (more) SLOAD(ss + 1);               // issue early (T14)
    int js = ss * 64 + grp * 32;           // this wave's 32-key window (absolute)
    if (js < i0t[1] + 32) {                // wave-uniform: any work at all
      // V frags for the window (shared by both tiles)
      bf16x8 vch[4], vcl[4];
      #pragma unroll
      for (int nf = 0; nf < 4; ++nf) {
        const unsigned short* vp = vh + (size_t)(nf * 16 + lr) * SEQ + js + lg * 8;
        vch[nf] = *reinterpret_cast<const bf16x8*>(vp);
        vcl[nf] = *reinterpret_cast<const bf16x8*>(vp + vPl);
      }
      // K frags from LDS (swizzled)
      bf16x8 kfh[2][2], kfl[2][2];
      #pragma unroll
      for (int nf2 = 0; nf2 < 2; ++nf2)
        #pragma unroll
        for (int kf = 0; kf < 2; ++kf) {
          int lrow = grp * 32 + nf2 * 16 + lr;
          int off = cur * 32768 + ((lrow * 256 + kf * 64 + lg * 16) ^ ((lrow & 7) << 4));
          kfh[nf2][kf] = *reinterpret_cast<const bf16x8*>(KBc + off);
          kfl[nf2][kf] = *reinterpret_cast<const bf16x8*>(KBc + 16384 + off);
        }
      #pragma unroll
      for (int t = 0; t < 2; ++t) {
        if (js < i0t[t] + 32) {            // wave-uniform
          #pragma unroll
          for (int nf2 = 0; nf2 < 2; ++nf2) {
            #pragma unroll
            for (int mf = 0; mf < 2; ++mf) {
              f32x4 sacc = {};
              #pragma unroll
              for (int kf = 0; kf < 2; ++kf) {
                sacc = __builtin_amdgcn_mfma_f32_16x16x32_bf16(qfh[t][mf][kf], kfh[nf2][kf], sacc, 0, 0, 0);
                sacc = __builtin_amdgcn_mfma_f32_16x16x32_bf16(qfl[t][mf][kf], kfh[nf2][kf], sacc, 0, 0, 0);
                sacc = __builtin_amdgcn_mfma_f32_16x16x32_bf16(qfh[t][mf][kf], kfl[nf2][kf], sacc, 0, 0, 0);
              }
              #pragma unroll
              for (int r = 0; r < 4; ++r) {
                int i = i0t[t] + mf * 16 + lg * 4 + r;
                int j = js + nf2 * 16 + lr;
                float v = (j <= i) ? fmaxf(sacc[r], 0.f) : 0.f;
                unsigned short shi, slo; split2(v, shi, slo);
                sw[0 * 1280 + (mf * 16 + lg * 4 + r) * 40 + nf2 * 16 + lr] = shi;
                sw[1 * 1280 + (mf * 16 + lg * 4 + r) * 40 + nf2 * 16 + lr] = slo;
              }
            }
          }
          asm volatile("s_waitcnt lgkmcnt(0)" ::: "memory");
          __builtin_amdgcn_sched_barrier(0);
          #pragma unroll
          for (int mf = 0; mf < 2; ++mf) {
            bf16x8 sfh = *reinterpret_cast<const bf16x8*>(&sw[0 * 1280 + (mf * 16 + lr) * 40 + lg * 8]);
            bf16x8 sfl = *reinterpret_cast<const bf16x8*>(&sw[1 * 1280 + (mf * 16 + lr) * 40 + lg * 8]);
            #pragma unroll
            for (int nf = 0; nf < 4; ++nf) {
              oacc[t][mf][nf] = __builtin_amdgcn_mfma_f32_16x16x32_bf16(sfh, vch[nf], oacc[t][mf][nf], 0, 0, 0);
              oacc[t][mf][nf] = __builtin_amdgcn_mfma_f32_16x16x32_bf16(sfl, vch[nf], oacc[t][mf][nf], 0, 0, 0);
              oacc[t][mf][nf] = __builtin_amdgcn_mfma_f32_16x16x32_bf16(sfh, vcl[nf], oacc[t][mf][nf], 0, 0, 0);
            }
          }
        }
      }
    }
    if (more) SWRITE(cur ^ 1);             // write late; ds-drain by syncthreads
    __syncthreads();
  }

  // ---- epilogue: head-sum tree + 1/(i+1) + residual + LN1 (both tiles) ----
  float hm = head_mask[h];
  float hm3 = hm * hm * hm;
  float* f8 = (float*)sh;                  // [8][32][64] f32, aliases Kbuf
  for (int t = 0; t < 2; ++t) {
    #pragma unroll
    for (int mf = 0; mf < 2; ++mf)
      #pragma unroll
      for (int nf = 0; nf < 4; ++nf)
        #pragma unroll
        for (int r = 0; r < 4; ++r)
          f8[wid * 2048 + (mf * 16 + lg * 4 + r) * 64 + nf * 16 + lr] = oacc[t][mf][nf][r] * hm3;
    __syncthreads();
    for (int idx = tid; idx < 8192; idx += 512) f8[idx] += f8[idx + 8192];
    __syncthreads();
    for (int idx = tid; idx < 4096; idx += 512) f8[idx] += f8[idx + 4096];
    __syncthreads();
    for (int idx = tid; idx < 2048; idx += 512) {
      int rr = idx >> 6;
      f8[idx] = (f8[idx] + f8[idx + 2048]) / (float)(i0t[t] + rr + 1);
    }
    __syncthreads();
    for (int rl = 0; rl < 4; ++rl) {
      int rr = wid * 4 + rl;
      size_t row = ((size_t)b * SEQ + i0t[t] + rr) * EMB;
      int c0 = lane, c1 = lane + 64;
      float x0 = Hst[row + c0];
      float x1 = Hst[row + c1] + f8[rr * 64 + lane];
      float s1 = x0 + x1, s2 = x0 * x0 + x1 * x1;
      #pragma unroll
      for (int off = 1; off < 64; off <<= 1) {
        s1 += __shfl_xor(s1, off);
        s2 += __shfl_xor(s2, off);
      }
      float mu = s1 * (1.f / 128.f);
      float var = s2 * (1.f / 128.f) - mu * mu;
      float rs = rsqrt_acc(var + LN_EPS);
      float y0 = (x0 - mu) * rs * g[c0] + bta[c0];
      float y1 = (x1 - mu) * rs * g[c1] + bta[c1];
      Hst[row + c0] = y0; Hst[row + c1] = y1;
      unsigned short h0, l0, h1, l1; split2(y0, h0, l0); split2(y1, h1, l1);
      HbfOut[row + c0] = h0; HbfOut[hbPl + row + c0] = l0;
      HbfOut[row + c1] = h1; HbfOut[hbPl + row + c1] = l1;
    }
    __syncthreads();
  }
}

// ---------------- fused attention (+LN1), last layer (DHEAD=128), 8-wave ----------------
template<int DHEAD>
__global__ __launch_bounds__(512) void k_attn_fused(
    const unsigned short* __restrict__ q, size_t qPl,
    const unsigned short* __restrict__ kbase, size_t kPl, size_t kBStride, size_t kHStride,
    const unsigned short* __restrict__ vT, size_t vPl,
    const float* __restrict__ head_mask,
    float* __restrict__ Hst, unsigned short* __restrict__ HbfOut, size_t hbPl,
    const float* __restrict__ g, const float* __restrict__ bta) {
  constexpr int KF = DHEAD / 32, NFO = DHEAD / 16;
  constexpr int NT = SEQ / 32;
  constexpr int SSB = 8 * 2 * 32 * 40 * 2;   // 40 KB
  constexpr int SH_BYTES = (SSB > 32 * DHEAD * 4) ? SSB : 32 * DHEAD * 4;
  int bid = blockIdx.x;
  int xcd = bid & 7, u = bid >> 3;
  int b = xcd * 2 + (u >> 4);
  int pidx = u & 15;
  int wid = threadIdx.x >> 6, lane = threadIdx.x & 63;
  int h = wid & 3, grp = wid >> 2;
  int lr = lane & 15, lg = lane >> 4;
  __shared__ __align__(16) char shraw[SH_BYTES];
  typedef unsigned short SArr[2][32][40];
  SArr* sS = (SArr*)shraw;
  typedef float FRow[DHEAD];
  FRow* facc = (FRow*)shraw;
  const unsigned short* qh = q + (size_t)(b * NHEAD + h) * SEQ * DHEAD;
  const unsigned short* kh = kbase + (size_t)b * kBStride + (size_t)h * kHStride;
  const unsigned short* vh = vT + (size_t)(b * NHEAD + h) * DHEAD * SEQ;
  float hm = head_mask[h];
  float hm3 = hm * hm * hm;

  for (int s = 0; s < 2; ++s) {
    int tile = (s == 0) ? pidx : (NT - 1 - pidx);
    int i0 = tile * 32;
    bf16x8 qfh[2][KF], qfl[2][KF];
    #pragma unroll
    for (int mf = 0; mf < 2; ++mf)
      #pragma unroll
      for (int kf = 0; kf < KF; ++kf) {
        const unsigned short* qp = qh + (size_t)(i0 + mf * 16 + lr) * DHEAD + kf * 32 + lg * 8;
        qfh[mf][kf] = *reinterpret_cast<const bf16x8*>(qp);
        qfl[mf][kf] = *reinterpret_cast<const bf16x8*>(qp + qPl);
      }
    f32x4 oacc[2][NFO] = {};
    int jend = i0 + 32;
    for (int j0 = grp * 32; j0 < jend; j0 += 64) {
      #pragma unroll
      for (int nf2 = 0; nf2 < 2; ++nf2) {
        int j16 = j0 + nf2 * 16;
        bf16x8 kfh[KF], kfl[KF];
        #pragma unroll
        for (int kf = 0; kf < KF; ++kf) {
          const unsigned short* kp = kh + (size_t)(j16 + lr) * EMB + kf * 32 + lg * 8;
          kfh[kf] = *reinterpret_cast<const bf16x8*>(kp);
          kfl[kf] = *reinterpret_cast<const bf16x8*>(kp + kPl);
        }
        #pragma unroll
        for (int mf = 0; mf < 2; ++mf) {
          f32x4 sacc = {};
          #pragma unroll
          for (int kf = 0; kf < KF; ++kf) {
            sacc = __builtin_amdgcn_mfma_f32_16x16x32_bf16(qfh[mf][kf], kfh[kf], sacc, 0, 0, 0);
            sacc = __builtin_amdgcn_mfma_f32_16x16x32_bf16(qfl[mf][kf], kfh[kf], sacc, 0, 0, 0);
            sacc = __builtin_amdgcn_mfma_f32_16x16x32_bf16(qfh[mf][kf], kfl[kf], sacc, 0, 0, 0);
          }
          #pragma unroll
          for (int r = 0; r < 4; ++r) {
            int i = i0 + mf * 16 + lg * 4 + r;
            int j = j16 + lr;
            float v = (j <= i) ? fmaxf(sacc[r], 0.f) : 0.f;
            unsigned short shi, slo; split2(v, shi, slo);
            sS[wid][0][mf * 16 + lg * 4 + r][nf2 * 16 + lr] = shi;
            sS[wid][1][mf * 16 + lg * 4 + r][nf2 * 16 + lr] = slo;
          }
        }
      }
      asm volatile("s_waitcnt lgkmcnt(0)" ::: "memory");
      __builtin_amdgcn_sched_barrier(0);
      #pragma unroll
      for (int mf = 0; mf < 2; ++mf) {
        bf16x8 sfh = *reinterpret_cast<const bf16x8*>(&sS[wid][0][mf * 16 + lr][lg * 8]);
        bf16x8 sfl = *reinterpret_cast<const bf16x8*>(&sS[wid][1][mf * 16 + lr][lg * 8]);
        #pragma unroll
        for (int nf = 0; nf < NFO; ++nf) {
          const unsigned short* vp = vh + (size_t)(nf * 16 + lr) * SEQ + j0 + lg * 8;
          bf16x8 vfh = *reinterpret_cast<const bf16x8*>(vp);
          bf16x8 vfl = *reinterpret_cast<const bf16x8*>(vp + vPl);
          oacc[mf][nf] = __builtin_amdgcn_mfma_f32_16x16x32_bf16(sfh, vfh, oacc[mf][nf], 0, 0, 0);
          oacc[mf][nf] = __builtin_amdgcn_mfma_f32_16x16x32_bf16(sfl, vfh, oacc[mf][nf], 0, 0, 0);
          oacc[mf][nf] = __builtin_amdgcn_mfma_f32_16x16x32_bf16(sfh, vfl, oacc[mf][nf], 0, 0, 0);
        }
      }
    }
    __syncthreads();
    for (int x = threadIdx.x; x < 32 * DHEAD; x += 512) ((float*)shraw)[x] = 0.f;
    __syncthreads();
    for (int w = 0; w < 8; ++w) {
      if (wid == w) {
        #pragma unroll
        for (int mf = 0; mf < 2; ++mf)
          #pragma unroll
          for (int nf = 0; nf < NFO; ++nf)
            #pragma unroll
            for (int r = 0; r < 4; ++r) {
              int rr = mf * 16 + lg * 4 + r;
              facc[rr][nf * 16 + lr] += oacc[mf][nf][r] * hm3 / (float)(i0 + rr + 1);
            }
      }
      __syncthreads();
    }
    for (int rl = 0; rl < 4; ++rl) {
      int rr = wid * 4 + rl;
      size_t row = ((size_t)b * SEQ + i0 + rr) * EMB;
      int c0 = lane, c1 = lane + 64;
      float a0 = (DHEAD == 128) ? facc[rr][c0] : 0.f;
      float a1 = (DHEAD == 128) ? facc[rr][c1] : facc[rr][lane];
      float x0 = Hst[row + c0] + a0;
      float x1 = Hst[row + c1] + a1;
      float s1 = x0 + x1, s2 = x0 * x0 + x1 * x1;
      #pragma unroll
      for (int off = 1; off < 64; off <<= 1) {
        s1 += __shfl_xor(s1, off);
        s2 += __shfl_xor(s2, off);
      }
      float mu = s1 * (1.f / 128.f);
      float var = s2 * (1.f / 128.f) - mu * mu;
      float rs = rsqrt_acc(var + LN_EPS);
      float y0 = (x0 - mu) * rs * g[c0] + bta[c0];
      float y1 = (x1 - mu) * rs * g[c1] + bta[c1];
      Hst[row + c0] = y0; Hst[row + c1] = y1;
      unsigned short h0, l0, h1, l1; split2(y0, h0, l0); split2(y1, h1, l1);
      HbfOut[row + c0] = h0; HbfOut[hbPl + row + c0] = l0;
      HbfOut[row + c1] = h1; HbfOut[hbPl + row + c1] = l1;
    }
    __syncthreads();
  }
}

// ---------------- fused MLP2 + residual + LN2 ----------------
__global__ __launch_bounds__(256) void k_mlp2ln(
    const unsigned short* __restrict__ A, size_t aPl,
    const unsigned short* __restrict__ BT, size_t bPl, const float* __restrict__ bias,
    float* __restrict__ Hst, unsigned short* __restrict__ HbfOut, size_t hbPl,
    const float* __restrict__ g, const float* __restrict__ bta) {
  int wid = threadIdx.x >> 6, lane = threadIdx.x & 63;
  int lr = lane & 15, lg = lane >> 4;
  int row0 = blockIdx.x * 64 + wid * 16;
  f32x4 acc[8] = {};
  const unsigned short* aP = A + (size_t)(row0 + lr) * 512 + lg * 8;
  const unsigned short* bP = BT + lg * 8;
  for (int k0 = 0; k0 < 512; k0 += 32) {
    bf16x8 ah = *reinterpret_cast<const bf16x8*>(aP + k0);
    bf16x8 al = *reinterpret_cast<const bf16x8*>(aP + aPl + k0);
    #pragma unroll
    for (int nf = 0; nf < 8; ++nf) {
      const unsigned short* bpp = bP + (size_t)(nf * 16 + lr) * 512 + k0;
      bf16x8 bh = *reinterpret_cast<const bf16x8*>(bpp);
      bf16x8 bl = *reinterpret_cast<const bf16x8*>(bpp + bPl);
      acc[nf] = __builtin_amdgcn_mfma_f32_16x16x32_bf16(ah, bh, acc[nf], 0, 0, 0);
      acc[nf] = __builtin_amdgcn_mfma_f32_16x16x32_bf16(al, bh, acc[nf], 0, 0, 0);
      acc[nf] = __builtin_amdgcn_mfma_f32_16x16x32_bf16(ah, bl, acc[nf], 0, 0, 0);
    }
  }
  int rowb = row0 + lg * 4;
  float xv[8][4];
  float s1[4] = {}, s2[4] = {};
  #pragma unroll
  for (int nf = 0; nf < 8; ++nf) {
    int c = nf * 16 + lr;
    float bv = bias[c];
    #pragma unroll
    for (int r = 0; r < 4; ++r) {
      float x = acc[nf][r] + bv + Hst[(size_t)(rowb + r) * EMB + c];
      xv[nf][r] = x; s1[r] += x; s2[r] += x * x;
    }
  }
  #pragma unroll
  for (int off = 1; off < 16; off <<= 1) {
    #pragma unroll
    for (int r = 0; r < 4; ++r) {
      s1[r] += __shfl_xor(s1[r], off);
      s2[r] += __shfl_xor(s2[r], off);
    }
  }
  #pragma unroll
  for (int r = 0; r < 4; ++r) {
    float mu = s1[r] * (1.f / 128.f);
    float var = s2[r] * (1.f / 128.f) - mu * mu;
    float rs = rsqrt_acc(var + LN_EPS);
    #pragma unroll
    for (int nf = 0; nf < 8; ++nf) {
      int c = nf * 16 + lr;
      float y = (xv[nf][r] - mu) * rs * g[c] + bta[c];
      size_t o = (size_t)(rowb + r) * EMB + c;
      Hst[o] = y;
      unsigned short hi, lo; split2(y, hi, lo);
      HbfOut[o] = hi; HbfOut[hbPl + o] = lo;
    }
  }
}

// ---------------- readout ----------------
__global__ __launch_bounds__(64) void k_readout(const float* __restrict__ H,
                                                const float* __restrict__ W, const float* __restrict__ b0,
                                                float* __restrict__ out) {
  int idx = blockIdx.x;           // b*512 + p
  int b = idx >> 9, p = idx & 511;
  size_t row = ((size_t)b * SEQ + 2 * p) * EMB;
  int lane = threadIdx.x;
  float acc = H[row + lane] * W[lane] + H[row + 64 + lane] * W[64 + lane];
  #pragma unroll
  for (int off = 1; off < 64; off <<= 1) acc += __shfl_xor(acc, off);
  if (lane == 0) out[idx] = acc + b0[0];
}

extern "C" void kernel_launch(void* const* d_in, const int* in_sizes, int n_in,
                              void* d_out, int out_size, void* d_ws, size_t ws_size,
                              hipStream_t stream) {
  (void)in_sizes; (void)n_in; (void)out_size; (void)ws_size;
  const float* xs        = (const float*)d_in[0];
  const float* ys        = (const float*)d_in[1];
  const float* head_mask = (const float*)d_in[2];
  const float* read_in_W = (const float*)d_in[3];
  const float* read_in_b = (const float*)d_in[4];
  const float* qW        = (const float*)d_in[5];
  const float* vW        = (const float*)d_in[6];
  const float* qW_last   = (const float*)d_in[7];
  const float* kW_last   = (const float*)d_in[8];
  const float* vW_last   = (const float*)d_in[9];
  const float* ln1_g     = (const float*)d_in[10];
  const float* ln1_b     = (const float*)d_in[11];
  const float* ln2_g     = (const float*)d_in[12];
  const float* ln2_b     = (const float*)d_in[13];
  const float* mlp_W1    = (const float*)d_in[14];
  const float* mlp_b1    = (const float*)d_in[15];
  const float* mlp_W2    = (const float*)d_in[16];
  const float* mlp_b2    = (const float*)d_in[17];
  const float* ro_W      = (const float*)d_in[18];
  const float* ro_b      = (const float*)d_in[19];

  const size_t HPL   = (size_t)BS * SEQ * EMB;          // 2M
  const size_t QPL   = (size_t)BS * NHEAD * SEQ * 128;  // 8M
  const size_t VT64PL= (size_t)BS * NHEAD * 64 * SEQ;   // 4M
  const size_t MIDPL = (size_t)BS * SEQ * 512;          // 8M
  const size_t KMPL  = QPL;
  const size_t VTLPL = QPL;
  const size_t QVWPL = (size_t)11 * 512 * 128;
  const size_t W1PL  = (size_t)12 * 128 * 512;
  const size_t W2PL  = (size_t)12 * 512 * 128;
  const size_t LASTPL= (size_t)3 * 512 * 128;

  char* ws = (char*)d_ws;
  size_t off = 0;
  auto alloc = [&](size_t bytes) -> void* {
    void* p = ws + off;
    off += (bytes + 255) & ~(size_t)255;
    return p;
  };
  float* H             = (float*)alloc(HPL * 4);                  // 8 MB (in-place state)
  unsigned short* Hbf  = (unsigned short*)alloc(2 * HPL * 2);     // 8 MB
  unsigned short* Hbf2 = (unsigned short*)alloc(2 * HPL * 2);     // 8 MB
  unsigned short* qbuf = (unsigned short*)alloc(2 * QPL * 2);     // 32 MB
  unsigned short* kmid = (unsigned short*)alloc(2 * KMPL * 2);    // 32 MB (vT64 / mid / K-last)
  unsigned short* vTl  = (unsigned short*)alloc(2 * VTLPL * 2);   // 32 MB (last-layer vT)
  unsigned short* qvWT = (unsigned short*)alloc(2 * QVWPL * 2);
  unsigned short* W1T  = (unsigned short*)alloc(2 * W1PL * 2);
  unsigned short* W2T  = (unsigned short*)alloc(2 * W2PL * 2);
  unsigned short* lastT= (unsigned short*)alloc(2 * LASTPL * 2);

  { int tot = 11 * 512 * 128; k_prep_qv<<<dim3((tot + 255) / 256), 256, 0, stream>>>(qW, vW, qvWT, QVWPL); }
  { int tot = 12 * 512 * 128; k_transpose_pad<<<dim3((tot + 255) / 256), 256, 0, stream>>>(mlp_W1, W1T, W1PL, 12, 128, 512, 128, 512); }
  { int tot = 12 * 128 * 512; k_transpose_pad<<<dim3((tot + 255) / 256), 256, 0, stream>>>(mlp_W2, W2T, W2PL, 12, 512, 128, 512, 128); }
  { int tot = 512 * 128;
    k_transpose_pad<<<dim3((tot + 255) / 256), 256, 0, stream>>>(qW_last, lastT,          LASTPL, 1, 128, 512, 128, 512);
    k_transpose_pad<<<dim3((tot + 255) / 256), 256, 0, stream>>>(kW_last, lastT + 65536,  LASTPL, 1, 128, 512, 128, 512);
    k_transpose_pad<<<dim3((tot + 255) / 256), 256, 0, stream>>>(vW_last, lastT + 131072, LASTPL, 1, 128, 512, 128, 512); }

  k_combine_readin<<<dim3(BS * SEQ), 128, 0, stream>>>(xs, ys, read_in_W, read_in_b, H, Hbf, HPL);

  const int ATTN_LDS = 65536 + 8 * 5120;   // 104 KB
  for (int l = 0; l < 11; ++l) {
    k_gemm<3, false, 128><<<dim3(256, 8), 256, 0, stream>>>(
        Hbf, 128, HPL, qvWT + (size_t)l * 65536, QVWPL, nullptr, 512,
        qbuf, QPL, kmid, VT64PL, nullptr, 0);
    k_attn_v6<<<dim3(256), 512, ATTN_LDS, stream>>>(
        qbuf, QPL, Hbf, HPL, kmid, VT64PL, head_mask,
        H, Hbf2, HPL, ln1_g + l * 128, ln1_b + l * 128);
    k_gemm<0, true, 128><<<dim3(256, 8), 256, 0, stream>>>(
        Hbf2, 128, HPL, W1T + (size_t)l * 65536, W1PL, mlp_b1 + l * 512, 512,
        kmid, MIDPL, nullptr, 0, nullptr, 0);
    k_mlp2ln<<<dim3(256), 256, 0, stream>>>(
        kmid, MIDPL, W2T + (size_t)l * 65536, W2PL, mlp_b2 + l * 128,
        H, Hbf, HPL, ln2_g + l * 128, ln2_b + l * 128);
  }
  // last layer
  k_gemm<2, false, 128><<<dim3(256, 24), 256, 0, stream>>>(
      Hbf, 128, HPL, lastT, LASTPL, nullptr, 1536,
      qbuf, QPL, kmid, KMPL, vTl, VTLPL);
  k_attn_fused<128><<<dim3(256), 512, 0, stream>>>(
      qbuf, QPL, kmid, KMPL, (size_t)NHEAD * SEQ * 128, (size_t)SEQ * 128, vTl, VTLPL, head_mask,
      H, Hbf2, HPL, ln1_g + 11 * 128, ln1_b + 11 * 128);
  k_gemm<0, true, 128><<<dim3(256, 8), 256, 0, stream>>>(
      Hbf2, 128, HPL, W1T + (size_t)11 * 65536, W1PL, mlp_b1 + 11 * 512, 512,
      kmid, MIDPL, nullptr, 0, nullptr, 0);
  k_mlp2ln<<<dim3(256), 256, 0, stream>>>(
      kmid, MIDPL, W2T + (size_t)11 * 65536, W2PL, mlp_b2 + 11 * 128,
      H, Hbf, HPL, ln2_g + 11 * 128, ln2_b + 11 * 128);

  k_readout<<<dim3(8192), 64, 0, stream>>>(H, ro_W, ro_b, (float*)d_out);
}

// Round 7
// 2140.221 us; speedup vs baseline: 1.2884x; 1.1330x over previous
//
#include <hip/hip_runtime.h>

#define BS 16
#define SEQ 1024
#define EMB 128
#define NHEAD 4
#define LN_EPS 1e-5f

typedef __attribute__((ext_vector_type(8))) short bf16x8;
typedef __attribute__((ext_vector_type(8))) _Float16 f16x8;
typedef __attribute__((ext_vector_type(4))) float f32x4;
typedef __attribute__((ext_vector_type(4))) unsigned short u16x4;
typedef __attribute__((ext_vector_type(4))) unsigned int u32x4;

__device__ __forceinline__ unsigned short f2b(float f) {
  union { float f; unsigned u; } v; v.f = f;
  unsigned r = v.u + 0x7fff + ((v.u >> 16) & 1);
  return (unsigned short)(r >> 16);
}
__device__ __forceinline__ unsigned short f2h(float f) {
  union { _Float16 h; unsigned short u; } v; v.h = (_Float16)f; return v.u;
}
// split x into hi+lo bf16 (3-term Markidis precision: rel err ~2^-17)
__device__ __forceinline__ void split2(float x, unsigned short& hi, unsigned short& lo) {
  unsigned short h = f2b(x);
  float hf = __uint_as_float((unsigned)h << 16);
  hi = h; lo = f2b(x - hf);
}
__device__ __forceinline__ float rsqrt_acc(float v) {
  float r = rsqrtf(v);
  return r * (1.5f - 0.5f * v * r * r);   // one Newton step -> ~f32-exact
}

// ---------------- weight prep ----------------
__global__ void k_transpose_pad(const float* __restrict__ in, unsigned short* __restrict__ out,
                                size_t PL, int L, int Kin, int Nin, int Kout, int Nout) {
  int idx = blockIdx.x * 256 + threadIdx.x;
  int total = L * Kout * Nout;
  if (idx >= total) return;
  int k = idx % Kout;
  int n = (idx / Kout) % Nout;
  int l = idx / (Kout * Nout);
  float v = (k < Kin && n < Nin) ? in[(size_t)l * Kin * Nin + (size_t)k * Nin + n] : 0.f;
  unsigned short hi, lo; split2(v, hi, lo);
  out[idx] = hi; out[PL + idx] = lo;
}

// qvWT[l][512][128]: n<256 -> q (qW rows -> H dims 64..126), n>=256 -> v (H dims 0..62)
__global__ void k_prep_qv(const float* __restrict__ qW, const float* __restrict__ vW,
                          unsigned short* __restrict__ out, size_t PL) {
  int idx = blockIdx.x * 256 + threadIdx.x;
  int total = 11 * 512 * 128;
  if (idx >= total) return;
  int k = idx & 127;
  int n = (idx >> 7) & 511;
  int l = idx >> 16;
  float v = 0.f;
  if (n < 256) {
    if (n < 252 && k >= 64 && k < 127) v = qW[(size_t)l * 63 * 252 + (size_t)(k - 64) * 252 + n];
  } else {
    int n2 = n - 256;
    if (n2 < 252 && k < 63) v = vW[(size_t)l * 63 * 252 + (size_t)k * 252 + n2];
  }
  unsigned short hi, lo; split2(v, hi, lo);
  out[idx] = hi; out[PL + idx] = lo;
}

// ---------------- combine + read_in ----------------
__global__ void k_combine_readin(const float* __restrict__ xs, const float* __restrict__ ys,
                                 const float* __restrict__ W, const float* __restrict__ bias,
                                 float* __restrict__ H, unsigned short* __restrict__ Hbf, size_t hbPl,
                                 unsigned short* __restrict__ Hh) {
  int blk = blockIdx.x;            // b*1024 + t
  int b = blk >> 10, t = blk & 1023, p = t >> 1;
  __shared__ float zs[64];
  int tid = threadIdx.x;           // 128
  if (tid < 64) {
    float v;
    if (tid < 63) v = xs[((size_t)b * 512 + p) * 63 + tid];
    else v = (t & 1) ? ys[(size_t)b * 512 + p] : 0.f;
    zs[tid] = v;
  }
  __syncthreads();
  float acc = bias[tid];
  #pragma unroll 8
  for (int d = 0; d < 64; ++d) acc += zs[d] * W[d * 128 + tid];
  size_t o = (size_t)blk * 128 + tid;
  H[o] = acc;
  unsigned short hi, lo; split2(acc, hi, lo);
  Hbf[o] = hi; Hbf[hbPl + o] = lo;
  if (tid < 64) Hh[(size_t)blk * 64 + tid] = f2h(acc);  // fp16 K image (dims 0..63)
}

// ---------------- generic split-precision MFMA GEMM (K compile-time) ----------------
// MODE 0: bf16-split out0[row*N+c]
// MODE 2: last qkv (N=1536) fp16: q,k normal [b][h][t][128]; v transposed [b][h][d][t]
// MODE 3: qv63 (N=512) fp16: c<256 q [b][h][t][64] (d63=0); else vT [b][h][d][t] (d63=0)
template<int MODE, bool RELU, int K>
__global__ __launch_bounds__(256) void k_gemm(
    const unsigned short* __restrict__ A, int aStride, size_t aPl,
    const unsigned short* __restrict__ BT, size_t bPl, const float* __restrict__ bias,
    int N,
    unsigned short* __restrict__ out0, size_t o0Pl,
    unsigned short* __restrict__ out1, size_t o1Pl,
    unsigned short* __restrict__ out2) {
  int wid = threadIdx.x >> 6, lane = threadIdx.x & 63;
  int lr = lane & 15, lg = lane >> 4;
  int row0 = blockIdx.x * 64 + wid * 16;
  int n0 = blockIdx.y * 64;
  f32x4 acc[4] = {};
  const unsigned short* aP = A + (size_t)(row0 + lr) * aStride + lg * 8;
  const unsigned short* bP = BT + (size_t)n0 * K + lg * 8;
  #pragma unroll
  for (int k0 = 0; k0 < K; k0 += 32) {
    bf16x8 ah = *reinterpret_cast<const bf16x8*>(aP + k0);
    bf16x8 al = *reinterpret_cast<const bf16x8*>(aP + aPl + k0);
    #pragma unroll
    for (int nf = 0; nf < 4; ++nf) {
      const unsigned short* bpp = bP + (size_t)(nf * 16 + lr) * K + k0;
      bf16x8 bh = *reinterpret_cast<const bf16x8*>(bpp);
      bf16x8 bl = *reinterpret_cast<const bf16x8*>(bpp + bPl);
      acc[nf] = __builtin_amdgcn_mfma_f32_16x16x32_bf16(ah, bh, acc[nf], 0, 0, 0);
      acc[nf] = __builtin_amdgcn_mfma_f32_16x16x32_bf16(al, bh, acc[nf], 0, 0, 0);
      acc[nf] = __builtin_amdgcn_mfma_f32_16x16x32_bf16(ah, bl, acc[nf], 0, 0, 0);
    }
  }
  int rowb = row0 + lg * 4;
  #pragma unroll
  for (int nf = 0; nf < 4; ++nf) {
    int c = n0 + nf * 16 + lr;
    float bv = bias ? bias[c] : 0.f;
    float vr[4];
    #pragma unroll
    for (int r = 0; r < 4; ++r) {
      float v = acc[nf][r] + bv;
      vr[r] = RELU ? fmaxf(v, 0.f) : v;
    }
    if (MODE == 0) {
      #pragma unroll
      for (int r = 0; r < 4; ++r) {
        unsigned short hi, lo; split2(vr[r], hi, lo);
        size_t o = (size_t)(rowb + r) * N + c;
        out0[o] = hi; out0[o0Pl + o] = lo;
      }
    } else if (MODE == 2) {
      int tsel = c >> 9, c2 = c & 511, hh = c2 >> 7, d = c2 & 127;
      int b = rowb >> 10, t = rowb & 1023;
      size_t bh = (size_t)b * NHEAD + hh;
      if (tsel < 2) {
        unsigned short* base = tsel ? out1 : out0;
        #pragma unroll
        for (int r = 0; r < 4; ++r)
          base[(bh * SEQ + (size_t)(t + r)) * 128 + d] = f2h(vr[r]);
      } else {
        u16x4 hv;
        #pragma unroll
        for (int r = 0; r < 4; ++r) hv[r] = f2h(vr[r]);
        *reinterpret_cast<u16x4*>(out2 + (bh * 128 + d) * SEQ + t) = hv;
      }
    } else {  // MODE 3
      int b = rowb >> 10, t = rowb & 1023;
      if (c < 256) {
        int hh, d; bool pad = (c >= 252);
        if (!pad) { hh = c / 63; d = c - hh * 63; } else { hh = c - 252; d = 63; }
        size_t bh = (size_t)b * NHEAD + hh;
        #pragma unroll
        for (int r = 0; r < 4; ++r)
          out0[(bh * SEQ + (size_t)(t + r)) * 64 + d] = f2h(pad ? 0.f : vr[r]);
      } else {
        int cc = c - 256; int hh, d; bool pad = (cc >= 252);
        if (!pad) { hh = cc / 63; d = cc - hh * 63; } else { hh = cc - 252; d = 63; }
        size_t bh = (size_t)b * NHEAD + hh;
        u16x4 hv;
        #pragma unroll
        for (int r = 0; r < 4; ++r) hv[r] = f2h(pad ? 0.f : vr[r]);
        *reinterpret_cast<u16x4*>(out1 + (bh * 64 + d) * SEQ + t) = hv;
      }
    }
  }
}

// ---------------- attention v7 (layers 0-10, D=64): fp16 single-plane, L2-resident ----------------
// Block = (b, pair). 8 waves = 4 heads x 2 j-groups. K (Hh, contiguous 8KB/superstep)
// staged to LDS (XOR-swizzled, double-buffered); V fp16 per wave; S fp16 in LDS.
// Fused j-group tree-sum + residual + LN1.
__global__ __launch_bounds__(512) void k_attn_v7(
    const unsigned short* __restrict__ q,      // fp16 [b][h][t][64]
    const unsigned short* __restrict__ Hh,     // fp16 [b][t][64]
    const unsigned short* __restrict__ vT,     // fp16 [b][h][d][t]
    const float* __restrict__ head_mask,
    float* __restrict__ Hst, unsigned short* __restrict__ HbfOut, size_t hbPl,
    const float* __restrict__ g, const float* __restrict__ bta) {
  extern __shared__ char sh[];  // [0,16K) Kbuf x2; [16K,36K) S; epilogue aliases [0,64K)
  int bid = blockIdx.x;
  int xcd = bid & 7, u = bid >> 3;
  int b = xcd * 2 + (u >> 4);
  int pidx = u & 15;
  int tid = threadIdx.x;
  int wid = tid >> 6, lane = tid & 63;
  int h = wid & 3, grp = wid >> 2;
  int lr = lane & 15, lg = lane >> 4;
  int i0t[2] = { pidx * 32, (31 - pidx) * 32 };
  int NSS = (33 - pidx) >> 1;              // supersteps of 64 keys

  const char* gK = (const char*)(Hh + (size_t)b * SEQ * 64);
  char* KB = sh;
  unsigned short* sw = (unsigned short*)(sh + 16384 + wid * 2560);  // [32][40] fp16

  const unsigned short* qh = q + (size_t)(b * NHEAD + h) * SEQ * 64;
  const unsigned short* vh = vT + (size_t)(b * NHEAD + h) * 64 * SEQ;

  f16x8 qf[2][2][2];                       // [tile][mf][kf]
  #pragma unroll
  for (int t = 0; t < 2; ++t)
    #pragma unroll
    for (int mf = 0; mf < 2; ++mf)
      #pragma unroll
      for (int kf = 0; kf < 2; ++kf)
        qf[t][mf][kf] = *reinterpret_cast<const f16x8*>(
            qh + (size_t)(i0t[t] + mf * 16 + lr) * 64 + kf * 32 + lg * 8);
  f32x4 oacc[2][2][4] = {};                // [tile][mf][nf]

  u32x4 sreg;
  auto SLOAD = [&](int ss) {
    sreg = *reinterpret_cast<const u32x4*>(gK + (size_t)ss * 8192 + tid * 16);
  };
  auto SWRITE = [&](int buf) {
    int row = tid >> 3, colb = (tid & 7) * 16;
    *reinterpret_cast<u32x4*>(KB + buf * 8192 + row * 128 + (colb ^ ((row & 7) << 4))) = sreg;
  };

  SLOAD(0); SWRITE(0);
  __syncthreads();

  for (int ss = 0; ss < NSS; ++ss) {
    int cur = ss & 1;
    bool more = (ss + 1 < NSS);
    if (more) SLOAD(ss + 1);               // issue early
    int js = ss * 64 + grp * 32;
    if (js < i0t[1] + 32) {                // wave-uniform
      f16x8 vch[4];
      #pragma unroll
      for (int nf = 0; nf < 4; ++nf)
        vch[nf] = *reinterpret_cast<const f16x8*>(vh + (size_t)(nf * 16 + lr) * SEQ + js + lg * 8);
      f16x8 kfr[2][2];
      #pragma unroll
      for (int nf2 = 0; nf2 < 2; ++nf2)
        #pragma unroll
        for (int kf = 0; kf < 2; ++kf) {
          int row = grp * 32 + nf2 * 16 + lr;
          int colb = kf * 64 + lg * 16;
          kfr[nf2][kf] = *reinterpret_cast<const f16x8*>(
              KB + cur * 8192 + row * 128 + (colb ^ ((row & 7) << 4)));
        }
      #pragma unroll
      for (int t = 0; t < 2; ++t) {
        if (js < i0t[t] + 32) {            // wave-uniform
          #pragma unroll
          for (int nf2 = 0; nf2 < 2; ++nf2) {
            #pragma unroll
            for (int mf = 0; mf < 2; ++mf) {
              f32x4 sacc = {};
              #pragma unroll
              for (int kf = 0; kf < 2; ++kf)
                sacc = __builtin_amdgcn_mfma_f32_16x16x32_f16(qf[t][mf][kf], kfr[nf2][kf], sacc, 0, 0, 0);
              #pragma unroll
              for (int r = 0; r < 4; ++r) {
                int i = i0t[t] + mf * 16 + lg * 4 + r;
                int j = js + nf2 * 16 + lr;
                float v = (j <= i) ? fmaxf(sacc[r], 0.f) : 0.f;
                sw[(mf * 16 + lg * 4 + r) * 40 + nf2 * 16 + lr] = f2h(v);
              }
            }
          }
          asm volatile("s_waitcnt lgkmcnt(0)" ::: "memory");
          __builtin_amdgcn_sched_barrier(0);
          #pragma unroll
          for (int mf = 0; mf < 2; ++mf) {
            f16x8 sf = *reinterpret_cast<const f16x8*>(&sw[(mf * 16 + lr) * 40 + lg * 8]);
            #pragma unroll
            for (int nf = 0; nf < 4; ++nf)
              oacc[t][mf][nf] = __builtin_amdgcn_mfma_f32_16x16x32_f16(sf, vch[nf], oacc[t][mf][nf], 0, 0, 0);
          }
        }
      }
    }
    if (more) SWRITE(cur ^ 1);             // write late; drained by syncthreads
    __syncthreads();
  }

  // ---- epilogue: tree-sum over 8 waves + 1/(i+1) + residual + LN1 (both tiles) ----
  float hm = head_mask[h];
  float hm3 = hm * hm * hm;
  float* f8 = (float*)sh;                  // [8][32][64] f32, aliases Kbuf+S
  for (int t = 0; t < 2; ++t) {
    #pragma unroll
    for (int mf = 0; mf < 2; ++mf)
      #pragma unroll
      for (int nf = 0; nf < 4; ++nf)
        #pragma unroll
        for (int r = 0; r < 4; ++r)
          f8[wid * 2048 + (mf * 16 + lg * 4 + r) * 64 + nf * 16 + lr] = oacc[t][mf][nf][r] * hm3;
    __syncthreads();
    for (int idx = tid; idx < 8192; idx += 512) f8[idx] += f8[idx + 8192];
    __syncthreads();
    for (int idx = tid; idx < 4096; idx += 512) f8[idx] += f8[idx + 4096];
    __syncthreads();
    for (int idx = tid; idx < 2048; idx += 512) {
      int rr = idx >> 6;
      f8[idx] = (f8[idx] + f8[idx + 2048]) / (float)(i0t[t] + rr + 1);
    }
    __syncthreads();
    for (int rl = 0; rl < 4; ++rl) {
      int rr = wid * 4 + rl;
      size_t row = ((size_t)b * SEQ + i0t[t] + rr) * EMB;
      int c0 = lane, c1 = lane + 64;
      float x0 = Hst[row + c0];
      float x1 = Hst[row + c1] + f8[rr * 64 + lane];
      float s1 = x0 + x1, s2 = x0 * x0 + x1 * x1;
      #pragma unroll
      for (int off = 1; off < 64; off <<= 1) {
        s1 += __shfl_xor(s1, off);
        s2 += __shfl_xor(s2, off);
      }
      float mu = s1 * (1.f / 128.f);
      float var = s2 * (1.f / 128.f) - mu * mu;
      float rs = rsqrt_acc(var + LN_EPS);
      float y0 = (x0 - mu) * rs * g[c0] + bta[c0];
      float y1 = (x1 - mu) * rs * g[c1] + bta[c1];
      Hst[row + c0] = y0; Hst[row + c1] = y1;
      unsigned short h0, l0, h1, l1; split2(y0, h0, l0); split2(y1, h1, l1);
      HbfOut[row + c0] = h0; HbfOut[hbPl + row + c0] = l0;
      HbfOut[row + c1] = h1; HbfOut[hbPl + row + c1] = l1;
    }
    __syncthreads();
  }
}

// ---------------- fused attention (+LN1), last layer (DHEAD=128), fp16, 8-wave ----------------
__global__ __launch_bounds__(512) void k_attn_fused(
    const unsigned short* __restrict__ q,      // fp16 [b][h][t][128]
    const unsigned short* __restrict__ kbuf,   // fp16 [b][h][t][128]
    const unsigned short* __restrict__ vT,     // fp16 [b][h][d][t]
    const float* __restrict__ head_mask,
    float* __restrict__ Hst, unsigned short* __restrict__ HbfOut, size_t hbPl,
    const float* __restrict__ g, const float* __restrict__ bta) {
  constexpr int KF = 4, NFO = 8, DHEAD = 128;
  constexpr int NT = SEQ / 32;
  __shared__ __align__(16) char shraw[8 * 32 * 40 * 2];  // 20KB (S); facc 16KB aliases
  int bid = blockIdx.x;
  int xcd = bid & 7, u = bid >> 3;
  int b = xcd * 2 + (u >> 4);
  int pidx = u & 15;
  int wid = threadIdx.x >> 6, lane = threadIdx.x & 63;
  int h = wid & 3, grp = wid >> 2;
  int lr = lane & 15, lg = lane >> 4;
  unsigned short* sw = (unsigned short*)(shraw + wid * 2560);  // [32][40]
  typedef float FRow[DHEAD];
  FRow* facc = (FRow*)shraw;
  const unsigned short* qh = q + (size_t)(b * NHEAD + h) * SEQ * DHEAD;
  const unsigned short* kh = kbuf + (size_t)(b * NHEAD + h) * SEQ * DHEAD;
  const unsigned short* vh = vT + (size_t)(b * NHEAD + h) * DHEAD * SEQ;
  float hm = head_mask[h];
  float hm3 = hm * hm * hm;

  for (int s = 0; s < 2; ++s) {
    int tile = (s == 0) ? pidx : (NT - 1 - pidx);
    int i0 = tile * 32;
    f16x8 qf[2][KF];
    #pragma unroll
    for (int mf = 0; mf < 2; ++mf)
      #pragma unroll
      for (int kf = 0; kf < KF; ++kf)
        qf[mf][kf] = *reinterpret_cast<const f16x8*>(
            qh + (size_t)(i0 + mf * 16 + lr) * DHEAD + kf * 32 + lg * 8);
    f32x4 oacc[2][NFO] = {};
    int jend = i0 + 32;
    for (int j0 = grp * 32; j0 < jend; j0 += 64) {
      f16x8 vch[NFO];
      #pragma unroll
      for (int nf = 0; nf < NFO; ++nf)
        vch[nf] = *reinterpret_cast<const f16x8*>(vh + (size_t)(nf * 16 + lr) * SEQ + j0 + lg * 8);
      #pragma unroll
      for (int nf2 = 0; nf2 < 2; ++nf2) {
        int j16 = j0 + nf2 * 16;
        f16x8 kfr[KF];
        #pragma unroll
        for (int kf = 0; kf < KF; ++kf)
          kfr[kf] = *reinterpret_cast<const f16x8*>(kh + (size_t)(j16 + lr) * DHEAD + kf * 32 + lg * 8);
        #pragma unroll
        for (int mf = 0; mf < 2; ++mf) {
          f32x4 sacc = {};
          #pragma unroll
          for (int kf = 0; kf < KF; ++kf)
            sacc = __builtin_amdgcn_mfma_f32_16x16x32_f16(qf[mf][kf], kfr[kf], sacc, 0, 0, 0);
          #pragma unroll
          for (int r = 0; r < 4; ++r) {
            int i = i0 + mf * 16 + lg * 4 + r;
            int j = j16 + lr;
            float v = (j <= i) ? fmaxf(sacc[r], 0.f) : 0.f;
            sw[(mf * 16 + lg * 4 + r) * 40 + nf2 * 16 + lr] = f2h(v);
          }
        }
      }
      asm volatile("s_waitcnt lgkmcnt(0)" ::: "memory");
      __builtin_amdgcn_sched_barrier(0);
      #pragma unroll
      for (int mf = 0; mf < 2; ++mf) {
        f16x8 sf = *reinterpret_cast<const f16x8*>(&sw[(mf * 16 + lr) * 40 + lg * 8]);
        #pragma unroll
        for (int nf = 0; nf < NFO; ++nf)
          oacc[mf][nf] = __builtin_amdgcn_mfma_f32_16x16x32_f16(sf, vch[nf], oacc[mf][nf], 0, 0, 0);
      }
    }
    __syncthreads();
    for (int x = threadIdx.x; x < 32 * DHEAD; x += 512) ((float*)shraw)[x] = 0.f;
    __syncthreads();
    for (int w = 0; w < 8; ++w) {
      if (wid == w) {
        #pragma unroll
        for (int mf = 0; mf < 2; ++mf)
          #pragma unroll
          for (int nf = 0; nf < NFO; ++nf)
            #pragma unroll
            for (int r = 0; r < 4; ++r) {
              int rr = mf * 16 + lg * 4 + r;
              facc[rr][nf * 16 + lr] += oacc[mf][nf][r] * hm3 / (float)(i0 + rr + 1);
            }
      }
      __syncthreads();
    }
    for (int rl = 0; rl < 4; ++rl) {
      int rr = wid * 4 + rl;
      size_t row = ((size_t)b * SEQ + i0 + rr) * EMB;
      int c0 = lane, c1 = lane + 64;
      float x0 = Hst[row + c0] + facc[rr][c0];
      float x1 = Hst[row + c1] + facc[rr][c1];
      float s1 = x0 + x1, s2 = x0 * x0 + x1 * x1;
      #pragma unroll
      for (int off = 1; off < 64; off <<= 1) {
        s1 += __shfl_xor(s1, off);
        s2 += __shfl_xor(s2, off);
      }
      float mu = s1 * (1.f / 128.f);
      float var = s2 * (1.f / 128.f) - mu * mu;
      float rs = rsqrt_acc(var + LN_EPS);
      float y0 = (x0 - mu) * rs * g[c0] + bta[c0];
      float y1 = (x1 - mu) * rs * g[c1] + bta[c1];
      Hst[row + c0] = y0; Hst[row + c1] = y1;
      unsigned short h0, l0, h1, l1; split2(y0, h0, l0); split2(y1, h1, l1);
      HbfOut[row + c0] = h0; HbfOut[hbPl + row + c0] = l0;
      HbfOut[row + c1] = h1; HbfOut[hbPl + row + c1] = l1;
    }
    __syncthreads();
  }
}

// ---------------- fused MLP2 + residual + LN2 (+Hh fp16 image for next layer's K) ----------------
__global__ __launch_bounds__(256) void k_mlp2ln(
    const unsigned short* __restrict__ A, size_t aPl,
    const unsigned short* __restrict__ BT, size_t bPl, const float* __restrict__ bias,
    float* __restrict__ Hst, unsigned short* __restrict__ HbfOut, size_t hbPl,
    unsigned short* __restrict__ Hh,
    const float* __restrict__ g, const float* __restrict__ bta) {
  int wid = threadIdx.x >> 6, lane = threadIdx.x & 63;
  int lr = lane & 15, lg = lane >> 4;
  int row0 = blockIdx.x * 64 + wid * 16;
  f32x4 acc[8] = {};
  const unsigned short* aP = A + (size_t)(row0 + lr) * 512 + lg * 8;
  const unsigned short* bP = BT + lg * 8;
  for (int k0 = 0; k0 < 512; k0 += 32) {
    bf16x8 ah = *reinterpret_cast<const bf16x8*>(aP + k0);
    bf16x8 al = *reinterpret_cast<const bf16x8*>(aP + aPl + k0);
    #pragma unroll
    for (int nf = 0; nf < 8; ++nf) {
      const unsigned short* bpp = bP + (size_t)(nf * 16 + lr) * 512 + k0;
      bf16x8 bh = *reinterpret_cast<const bf16x8*>(bpp);
      bf16x8 bl = *reinterpret_cast<const bf16x8*>(bpp + bPl);
      acc[nf] = __builtin_amdgcn_mfma_f32_16x16x32_bf16(ah, bh, acc[nf], 0, 0, 0);
      acc[nf] = __builtin_amdgcn_mfma_f32_16x16x32_bf16(al, bh, acc[nf], 0, 0, 0);
      acc[nf] = __builtin_amdgcn_mfma_f32_16x16x32_bf16(ah, bl, acc[nf], 0, 0, 0);
    }
  }
  int rowb = row0 + lg * 4;
  float xv[8][4];
  float s1[4] = {}, s2[4] = {};
  #pragma unroll
  for (int nf = 0; nf < 8; ++nf) {
    int c = nf * 16 + lr;
    float bv = bias[c];
    #pragma unroll
    for (int r = 0; r < 4; ++r) {
      float x = acc[nf][r] + bv + Hst[(size_t)(rowb + r) * EMB + c];
      xv[nf][r] = x; s1[r] += x; s2[r] += x * x;
    }
  }
  #pragma unroll
  for (int off = 1; off < 16; off <<= 1) {
    #pragma unroll
    for (int r = 0; r < 4; ++r) {
      s1[r] += __shfl_xor(s1[r], off);
      s2[r] += __shfl_xor(s2[r], off);
    }
  }
  #pragma unroll
  for (int r = 0; r < 4; ++r) {
    float mu = s1[r] * (1.f / 128.f);
    float var = s2[r] * (1.f / 128.f) - mu * mu;
    float rs = rsqrt_acc(var + LN_EPS);
    #pragma unroll
    for (int nf = 0; nf < 8; ++nf) {
      int c = nf * 16 + lr;
      float y = (xv[nf][r] - mu) * rs * g[c] + bta[c];
      size_t o = (size_t)(rowb + r) * EMB + c;
      Hst[o] = y;
      unsigned short hi, lo; split2(y, hi, lo);
      HbfOut[o] = hi; HbfOut[hbPl + o] = lo;
      if (c < 64) Hh[(size_t)(rowb + r) * 64 + c] = f2h(y);
    }
  }
}

// ---------------- readout ----------------
__global__ __launch_bounds__(64) void k_readout(const float* __restrict__ H,
                                                const float* __restrict__ W, const float* __restrict__ b0,
                                                float* __restrict__ out) {
  int idx = blockIdx.x;           // b*512 + p
  int b = idx >> 9, p = idx & 511;
  size_t row = ((size_t)b * SEQ + 2 * p) * EMB;
  int lane = threadIdx.x;
  float acc = H[row + lane] * W[lane] + H[row + 64 + lane] * W[64 + lane];
  #pragma unroll
  for (int off = 1; off < 64; off <<= 1) acc += __shfl_xor(acc, off);
  if (lane == 0) out[idx] = acc + b0[0];
}

extern "C" void kernel_launch(void* const* d_in, const int* in_sizes, int n_in,
                              void* d_out, int out_size, void* d_ws, size_t ws_size,
                              hipStream_t stream) {
  (void)in_sizes; (void)n_in; (void)out_size; (void)ws_size;
  const float* xs        = (const float*)d_in[0];
  const float* ys        = (const float*)d_in[1];
  const float* head_mask = (const float*)d_in[2];
  const float* read_in_W = (const float*)d_in[3];
  const float* read_in_b = (const float*)d_in[4];
  const float* qW        = (const float*)d_in[5];
  const float* vW        = (const float*)d_in[6];
  const float* qW_last   = (const float*)d_in[7];
  const float* kW_last   = (const float*)d_in[8];
  const float* vW_last   = (const float*)d_in[9];
  const float* ln1_g     = (const float*)d_in[10];
  const float* ln1_b     = (const float*)d_in[11];
  const float* ln2_g     = (const float*)d_in[12];
  const float* ln2_b     = (const float*)d_in[13];
  const float* mlp_W1    = (const float*)d_in[14];
  const float* mlp_b1    = (const float*)d_in[15];
  const float* mlp_W2    = (const float*)d_in[16];
  const float* mlp_b2    = (const float*)d_in[17];
  const float* ro_W      = (const float*)d_in[18];
  const float* ro_b      = (const float*)d_in[19];

  const size_t HPL   = (size_t)BS * SEQ * EMB;          // 2M
  const size_t MIDPL = (size_t)BS * SEQ * 512;          // 8M
  const size_t QVWPL = (size_t)11 * 512 * 128;
  const size_t W1PL  = (size_t)12 * 128 * 512;
  const size_t W2PL  = (size_t)12 * 512 * 128;
  const size_t LASTPL= (size_t)3 * 512 * 128;

  char* ws = (char*)d_ws;
  size_t off = 0;
  auto alloc = [&](size_t bytes) -> void* {
    void* p = ws + off;
    off += (bytes + 255) & ~(size_t)255;
    return p;
  };
  float* H             = (float*)alloc(HPL * 4);                  // 8 MB (in-place state)
  unsigned short* Hbf  = (unsigned short*)alloc(2 * HPL * 2);     // 8 MB bf16 split
  unsigned short* Hbf2 = (unsigned short*)alloc(2 * HPL * 2);     // 8 MB bf16 split
  unsigned short* Hh   = (unsigned short*)alloc((size_t)BS * SEQ * 64 * 2);  // 2 MB fp16 K image
  unsigned short* qbuf = (unsigned short*)alloc((size_t)BS * NHEAD * SEQ * 128 * 2); // 16 MB fp16
  unsigned short* kmid = (unsigned short*)alloc(2 * MIDPL * 2);   // 32 MB (vT64/K-last fp16; mid bf16 split)
  unsigned short* vTl  = (unsigned short*)alloc((size_t)BS * NHEAD * SEQ * 128 * 2); // 16 MB fp16
  unsigned short* qvWT = (unsigned short*)alloc(2 * QVWPL * 2);
  unsigned short* W1T  = (unsigned short*)alloc(2 * W1PL * 2);
  unsigned short* W2T  = (unsigned short*)alloc(2 * W2PL * 2);
  unsigned short* lastT= (unsigned short*)alloc(2 * LASTPL * 2);

  { int tot = 11 * 512 * 128; k_prep_qv<<<dim3((tot + 255) / 256), 256, 0, stream>>>(qW, vW, qvWT, QVWPL); }
  { int tot = 12 * 512 * 128; k_transpose_pad<<<dim3((tot + 255) / 256), 256, 0, stream>>>(mlp_W1, W1T, W1PL, 12, 128, 512, 128, 512); }
  { int tot = 12 * 128 * 512; k_transpose_pad<<<dim3((tot + 255) / 256), 256, 0, stream>>>(mlp_W2, W2T, W2PL, 12, 512, 128, 512, 128); }
  { int tot = 512 * 128;
    k_transpose_pad<<<dim3((tot + 255) / 256), 256, 0, stream>>>(qW_last, lastT,          LASTPL, 1, 128, 512, 128, 512);
    k_transpose_pad<<<dim3((tot + 255) / 256), 256, 0, stream>>>(kW_last, lastT + 65536,  LASTPL, 1, 128, 512, 128, 512);
    k_transpose_pad<<<dim3((tot + 255) / 256), 256, 0, stream>>>(vW_last, lastT + 131072, LASTPL, 1, 128, 512, 128, 512); }

  k_combine_readin<<<dim3(BS * SEQ), 128, 0, stream>>>(xs, ys, read_in_W, read_in_b, H, Hbf, HPL, Hh);

  for (int l = 0; l < 11; ++l) {
    k_gemm<3, false, 128><<<dim3(256, 8), 256, 0, stream>>>(
        Hbf, 128, HPL, qvWT + (size_t)l * 65536, QVWPL, nullptr, 512,
        qbuf, 0, kmid, 0, nullptr);
    k_attn_v7<<<dim3(256), 512, 65536, stream>>>(
        qbuf, Hh, kmid, head_mask, H, Hbf2, HPL, ln1_g + l * 128, ln1_b + l * 128);
    k_gemm<0, true, 128><<<dim3(256, 8), 256, 0, stream>>>(
        Hbf2, 128, HPL, W1T + (size_t)l * 65536, W1PL, mlp_b1 + l * 512, 512,
        kmid, MIDPL, nullptr, 0, nullptr);
    k_mlp2ln<<<dim3(256), 256, 0, stream>>>(
        kmid, MIDPL, W2T + (size_t)l * 65536, W2PL, mlp_b2 + l * 128,
        H, Hbf, HPL, Hh, ln2_g + l * 128, ln2_b + l * 128);
  }
  // last layer: q,k,v fp16 projections in one GEMM (N=1536)
  k_gemm<2, false, 128><<<dim3(256, 24), 256, 0, stream>>>(
      Hbf, 128, HPL, lastT, LASTPL, nullptr, 1536,
      qbuf, 0, kmid, 0, vTl);
  k_attn_fused<<<dim3(256), 512, 0, stream>>>(
      qbuf, kmid, vTl, head_mask, H, Hbf2, HPL, ln1_g + 11 * 128, ln1_b + 11 * 128);
  k_gemm<0, true, 128><<<dim3(256, 8), 256, 0, stream>>>(
      Hbf2, 128, HPL, W1T + (size_t)11 * 65536, W1PL, mlp_b1 + 11 * 512, 512,
      kmid, MIDPL, nullptr, 0, nullptr);
  k_mlp2ln<<<dim3(256), 256, 0, stream>>>(
      kmid, MIDPL, W2T + (size_t)11 * 65536, W2PL, mlp_b2 + 11 * 128,
      H, Hbf, HPL, Hh, ln2_g + 11 * 128, ln2_b + 11 * 128);

  k_readout<<<dim3(8192), 64, 0, stream>>>(H, ro_W, ro_b, (float*)d_out);
}

// Round 8
// 2109.804 us; speedup vs baseline: 1.3070x; 1.0144x over previous
//
#include <hip/hip_runtime.h>

#define BS 16
#define SEQ 1024
#define EMB 128
#define NHEAD 4
#define LN_EPS 1e-5f

typedef __attribute__((ext_vector_type(8))) short bf16x8;
typedef __attribute__((ext_vector_type(8))) _Float16 f16x8;
typedef __attribute__((ext_vector_type(4))) float f32x4;
typedef __attribute__((ext_vector_type(4))) unsigned short u16x4;
typedef __attribute__((ext_vector_type(4))) unsigned int u32x4;

__device__ __forceinline__ unsigned short f2b(float f) {
  union { float f; unsigned u; } v; v.f = f;
  unsigned r = v.u + 0x7fff + ((v.u >> 16) & 1);
  return (unsigned short)(r >> 16);
}
__device__ __forceinline__ unsigned short f2h(float f) {
  union { _Float16 h; unsigned short u; } v; v.h = (_Float16)f; return v.u;
}
// split x into hi+lo bf16 (3-term Markidis precision: rel err ~2^-17)
__device__ __forceinline__ void split2(float x, unsigned short& hi, unsigned short& lo) {
  unsigned short h = f2b(x);
  float hf = __uint_as_float((unsigned)h << 16);
  hi = h; lo = f2b(x - hf);
}
__device__ __forceinline__ float rsqrt_acc(float v) {
  float r = rsqrtf(v);
  return r * (1.5f - 0.5f * v * r * r);   // one Newton step -> ~f32-exact
}

// ---------------- weight prep ----------------
__global__ void k_transpose_pad(const float* __restrict__ in, unsigned short* __restrict__ out,
                                size_t PL, int L, int Kin, int Nin, int Kout, int Nout) {
  int idx = blockIdx.x * 256 + threadIdx.x;
  int total = L * Kout * Nout;
  if (idx >= total) return;
  int k = idx % Kout;
  int n = (idx / Kout) % Nout;
  int l = idx / (Kout * Nout);
  float v = (k < Kin && n < Nin) ? in[(size_t)l * Kin * Nin + (size_t)k * Nin + n] : 0.f;
  unsigned short hi, lo; split2(v, hi, lo);
  out[idx] = hi; out[PL + idx] = lo;
}

// qvWT[l][512][128]: n<256 -> q (qW rows -> H dims 64..126), n>=256 -> v (H dims 0..62)
__global__ void k_prep_qv(const float* __restrict__ qW, const float* __restrict__ vW,
                          unsigned short* __restrict__ out, size_t PL) {
  int idx = blockIdx.x * 256 + threadIdx.x;
  int total = 11 * 512 * 128;
  if (idx >= total) return;
  int k = idx & 127;
  int n = (idx >> 7) & 511;
  int l = idx >> 16;
  float v = 0.f;
  if (n < 256) {
    if (n < 252 && k >= 64 && k < 127) v = qW[(size_t)l * 63 * 252 + (size_t)(k - 64) * 252 + n];
  } else {
    int n2 = n - 256;
    if (n2 < 252 && k < 63) v = vW[(size_t)l * 63 * 252 + (size_t)k * 252 + n2];
  }
  unsigned short hi, lo; split2(v, hi, lo);
  out[idx] = hi; out[PL + idx] = lo;
}

// ---------------- combine + read_in ----------------
__global__ void k_combine_readin(const float* __restrict__ xs, const float* __restrict__ ys,
                                 const float* __restrict__ W, const float* __restrict__ bias,
                                 float* __restrict__ H, unsigned short* __restrict__ Hbf, size_t hbPl,
                                 unsigned short* __restrict__ Hh) {
  int blk = blockIdx.x;            // b*1024 + t
  int b = blk >> 10, t = blk & 1023, p = t >> 1;
  __shared__ float zs[64];
  int tid = threadIdx.x;           // 128
  if (tid < 64) {
    float v;
    if (tid < 63) v = xs[((size_t)b * 512 + p) * 63 + tid];
    else v = (t & 1) ? ys[(size_t)b * 512 + p] : 0.f;
    zs[tid] = v;
  }
  __syncthreads();
  float acc = bias[tid];
  #pragma unroll 8
  for (int d = 0; d < 64; ++d) acc += zs[d] * W[d * 128 + tid];
  size_t o = (size_t)blk * 128 + tid;
  H[o] = acc;
  unsigned short hi, lo; split2(acc, hi, lo);
  Hbf[o] = hi; Hbf[hbPl + o] = lo;
  if (tid < 64) Hh[(size_t)blk * 64 + tid] = f2h(acc);  // fp16 K image (dims 0..63)
}

// ---------------- generic split-precision MFMA GEMM, coalesced LDS epilogues ----------------
// MODE 0: packed u32 (hi | lo<<16) out0[row*N+c]  (mlp1 mid)
// MODE 2: last qkv (N=1536) fp16: q,k [b][h][t][128]; v transposed [b][h][d][t]
// MODE 3: qv63 (N=512) fp16: c<256 q [b][h][t][64] (d63=0); else vT [b][h][d][t] (d63=0)
template<int MODE, bool RELU, int K>
__global__ __launch_bounds__(256) void k_gemm(
    const unsigned short* __restrict__ A, int aStride, size_t aPl,
    const unsigned short* __restrict__ BT, size_t bPl, const float* __restrict__ bias,
    int N,
    unsigned short* __restrict__ out0,
    unsigned short* __restrict__ out1,
    unsigned short* __restrict__ out2) {
  constexpr int SMEMB = (MODE == 0) ? (64 * 65 * 4) : (64 * 66 * 2);
  __shared__ __align__(16) char smem[SMEMB];
  int wid = threadIdx.x >> 6, lane = threadIdx.x & 63;
  int lr = lane & 15, lg = lane >> 4;
  int row0 = blockIdx.x * 64 + wid * 16;
  int n0 = blockIdx.y * 64;
  f32x4 acc[4] = {};
  const unsigned short* aP = A + (size_t)(row0 + lr) * aStride + lg * 8;
  const unsigned short* bP = BT + (size_t)n0 * K + lg * 8;
  #pragma unroll
  for (int k0 = 0; k0 < K; k0 += 32) {
    bf16x8 ah = *reinterpret_cast<const bf16x8*>(aP + k0);
    bf16x8 al = *reinterpret_cast<const bf16x8*>(aP + aPl + k0);
    #pragma unroll
    for (int nf = 0; nf < 4; ++nf) {
      const unsigned short* bpp = bP + (size_t)(nf * 16 + lr) * K + k0;
      bf16x8 bh = *reinterpret_cast<const bf16x8*>(bpp);
      bf16x8 bl = *reinterpret_cast<const bf16x8*>(bpp + bPl);
      acc[nf] = __builtin_amdgcn_mfma_f32_16x16x32_bf16(ah, bh, acc[nf], 0, 0, 0);
      acc[nf] = __builtin_amdgcn_mfma_f32_16x16x32_bf16(al, bh, acc[nf], 0, 0, 0);
      acc[nf] = __builtin_amdgcn_mfma_f32_16x16x32_bf16(ah, bl, acc[nf], 0, 0, 0);
    }
  }
  // ---- stage tile in LDS ----
  #pragma unroll
  for (int nf = 0; nf < 4; ++nf) {
    int c = n0 + nf * 16 + lr;
    float bv = bias ? bias[c] : 0.f;
    #pragma unroll
    for (int r = 0; r < 4; ++r) {
      float v = acc[nf][r] + bv;
      if (RELU) v = fmaxf(v, 0.f);
      int rL = wid * 16 + lg * 4 + r, cL = nf * 16 + lr;
      if (MODE == 0) {
        unsigned short hi, lo; split2(v, hi, lo);
        ((unsigned int(*)[65])smem)[rL][cL] = (unsigned)hi | ((unsigned)lo << 16);
      } else {
        ((unsigned short(*)[66])smem)[rL][cL] = f2h(v);
      }
    }
  }
  __syncthreads();
  // ---- coalesced writes ----
  int rowb0 = blockIdx.x * 64;
  if (MODE == 0) {
    unsigned int* o32 = (unsigned int*)out0;
    unsigned int (*tile)[65] = (unsigned int(*)[65])smem;
    for (int rr = wid; rr < 64; rr += 4)
      o32[(size_t)(rowb0 + rr) * N + n0 + lane] = tile[rr][lane];
  } else if (MODE == 2) {
    unsigned short (*t16)[66] = (unsigned short(*)[66])smem;
    int b = rowb0 >> 10, t0 = rowb0 & 1023;
    int tsel = n0 >> 9, c2b = n0 & 511, hh = c2b >> 7, dbase = c2b & 127;
    size_t bh = (size_t)b * NHEAD + hh;
    if (tsel < 2) {
      unsigned short* base = tsel ? out1 : out0;
      size_t rowbase = bh * SEQ * 128 + dbase + lane;
      for (int rr = wid; rr < 64; rr += 4)
        base[rowbase + (size_t)(t0 + rr) * 128] = t16[rr][lane];
    } else {
      for (int rr = wid; rr < 64; rr += 4) {
        int d = dbase + rr;
        out2[(bh * 128 + d) * SEQ + t0 + lane] = t16[lane][rr];
      }
    }
  } else {  // MODE 3
    unsigned short (*t16)[66] = (unsigned short(*)[66])smem;
    int b = rowb0 >> 10, t0 = rowb0 & 1023;
    if (n0 < 256) {              // q-half: [b][h][t][64], lanes -> d (contiguous)
      int c = n0 + lane;
      bool pad = (c >= 252);
      int hh = pad ? c - 252 : c / 63;
      int d  = pad ? 63 : c - hh * 63;
      size_t base = ((size_t)(b * NHEAD + hh) * SEQ) * 64 + d;
      for (int rr = wid; rr < 64; rr += 4)
        out0[base + (size_t)(t0 + rr) * 64] = pad ? (unsigned short)0 : t16[rr][lane];
    } else {                     // v-half: [b][h][d][t], lanes -> t (128B lines)
      for (int rr = wid; rr < 64; rr += 4) {
        int cc = n0 - 256 + rr;
        bool pad = (cc >= 252);
        int hh = pad ? cc - 252 : cc / 63;
        int d  = pad ? 63 : cc - hh * 63;
        size_t addr = ((size_t)(b * NHEAD + hh) * 64 + d) * SEQ + t0 + lane;
        out1[addr] = pad ? (unsigned short)0 : t16[lane][rr];
      }
    }
  }
}

// ---------------- attention v7 (layers 0-10, D=64): fp16 single-plane, L2-resident ----------------
__global__ __launch_bounds__(512) void k_attn_v7(
    const unsigned short* __restrict__ q,      // fp16 [b][h][t][64]
    const unsigned short* __restrict__ Hh,     // fp16 [b][t][64]
    const unsigned short* __restrict__ vT,     // fp16 [b][h][d][t]
    const float* __restrict__ head_mask,
    float* __restrict__ Hst, unsigned short* __restrict__ HbfOut, size_t hbPl,
    const float* __restrict__ g, const float* __restrict__ bta) {
  extern __shared__ char sh[];  // [0,16K) Kbuf x2; [16K,36K) S; epilogue aliases [0,64K)
  int bid = blockIdx.x;
  int xcd = bid & 7, u = bid >> 3;
  int b = xcd * 2 + (u >> 4);
  int pidx = u & 15;
  int tid = threadIdx.x;
  int wid = tid >> 6, lane = tid & 63;
  int h = wid & 3, grp = wid >> 2;
  int lr = lane & 15, lg = lane >> 4;
  int i0t[2] = { pidx * 32, (31 - pidx) * 32 };
  int NSS = (33 - pidx) >> 1;              // supersteps of 64 keys

  const char* gK = (const char*)(Hh + (size_t)b * SEQ * 64);
  char* KB = sh;
  unsigned short* sw = (unsigned short*)(sh + 16384 + wid * 2560);  // [32][40] fp16

  const unsigned short* qh = q + (size_t)(b * NHEAD + h) * SEQ * 64;
  const unsigned short* vh = vT + (size_t)(b * NHEAD + h) * 64 * SEQ;

  f16x8 qf[2][2][2];                       // [tile][mf][kf]
  #pragma unroll
  for (int t = 0; t < 2; ++t)
    #pragma unroll
    for (int mf = 0; mf < 2; ++mf)
      #pragma unroll
      for (int kf = 0; kf < 2; ++kf)
        qf[t][mf][kf] = *reinterpret_cast<const f16x8*>(
            qh + (size_t)(i0t[t] + mf * 16 + lr) * 64 + kf * 32 + lg * 8);
  f32x4 oacc[2][2][4] = {};                // [tile][mf][nf]

  u32x4 sreg;
  auto SLOAD = [&](int ss) {
    sreg = *reinterpret_cast<const u32x4*>(gK + (size_t)ss * 8192 + tid * 16);
  };
  auto SWRITE = [&](int buf) {
    int row = tid >> 3, colb = (tid & 7) * 16;
    *reinterpret_cast<u32x4*>(KB + buf * 8192 + row * 128 + (colb ^ ((row & 7) << 4))) = sreg;
  };

  SLOAD(0); SWRITE(0);
  __syncthreads();

  for (int ss = 0; ss < NSS; ++ss) {
    int cur = ss & 1;
    bool more = (ss + 1 < NSS);
    if (more) SLOAD(ss + 1);               // issue early
    int js = ss * 64 + grp * 32;
    if (js < i0t[1] + 32) {                // wave-uniform
      f16x8 vch[4];
      #pragma unroll
      for (int nf = 0; nf < 4; ++nf)
        vch[nf] = *reinterpret_cast<const f16x8*>(vh + (size_t)(nf * 16 + lr) * SEQ + js + lg * 8);
      f16x8 kfr[2][2];
      #pragma unroll
      for (int nf2 = 0; nf2 < 2; ++nf2)
        #pragma unroll
        for (int kf = 0; kf < 2; ++kf) {
          int row = grp * 32 + nf2 * 16 + lr;
          int colb = kf * 64 + lg * 16;
          kfr[nf2][kf] = *reinterpret_cast<const f16x8*>(
              KB + cur * 8192 + row * 128 + (colb ^ ((row & 7) << 4)));
        }
      #pragma unroll
      for (int t = 0; t < 2; ++t) {
        if (js < i0t[t] + 32) {            // wave-uniform
          #pragma unroll
          for (int nf2 = 0; nf2 < 2; ++nf2) {
            #pragma unroll
            for (int mf = 0; mf < 2; ++mf) {
              f32x4 sacc = {};
              #pragma unroll
              for (int kf = 0; kf < 2; ++kf)
                sacc = __builtin_amdgcn_mfma_f32_16x16x32_f16(qf[t][mf][kf], kfr[nf2][kf], sacc, 0, 0, 0);
              #pragma unroll
              for (int r = 0; r < 4; ++r) {
                int i = i0t[t] + mf * 16 + lg * 4 + r;
                int j = js + nf2 * 16 + lr;
                float v = (j <= i) ? fmaxf(sacc[r], 0.f) : 0.f;
                sw[(mf * 16 + lg * 4 + r) * 40 + nf2 * 16 + lr] = f2h(v);
              }
            }
          }
          asm volatile("s_waitcnt lgkmcnt(0)" ::: "memory");
          __builtin_amdgcn_sched_barrier(0);
          #pragma unroll
          for (int mf = 0; mf < 2; ++mf) {
            f16x8 sf = *reinterpret_cast<const f16x8*>(&sw[(mf * 16 + lr) * 40 + lg * 8]);
            #pragma unroll
            for (int nf = 0; nf < 4; ++nf)
              oacc[t][mf][nf] = __builtin_amdgcn_mfma_f32_16x16x32_f16(sf, vch[nf], oacc[t][mf][nf], 0, 0, 0);
          }
        }
      }
    }
    if (more) SWRITE(cur ^ 1);             // write late; drained by syncthreads
    __syncthreads();
  }

  // ---- epilogue: tree-sum over 8 waves + 1/(i+1) + residual + LN1 (both tiles) ----
  float hm = head_mask[h];
  float hm3 = hm * hm * hm;
  float* f8 = (float*)sh;                  // [8][32][64] f32, aliases Kbuf+S
  for (int t = 0; t < 2; ++t) {
    #pragma unroll
    for (int mf = 0; mf < 2; ++mf)
      #pragma unroll
      for (int nf = 0; nf < 4; ++nf)
        #pragma unroll
        for (int r = 0; r < 4; ++r)
          f8[wid * 2048 + (mf * 16 + lg * 4 + r) * 64 + nf * 16 + lr] = oacc[t][mf][nf][r] * hm3;
    __syncthreads();
    for (int idx = tid; idx < 8192; idx += 512) f8[idx] += f8[idx + 8192];
    __syncthreads();
    for (int idx = tid; idx < 4096; idx += 512) f8[idx] += f8[idx + 4096];
    __syncthreads();
    for (int idx = tid; idx < 2048; idx += 512) {
      int rr = idx >> 6;
      f8[idx] = (f8[idx] + f8[idx + 2048]) / (float)(i0t[t] + rr + 1);
    }
    __syncthreads();
    for (int rl = 0; rl < 4; ++rl) {
      int rr = wid * 4 + rl;
      size_t row = ((size_t)b * SEQ + i0t[t] + rr) * EMB;
      int c0 = lane, c1 = lane + 64;
      float x0 = Hst[row + c0];
      float x1 = Hst[row + c1] + f8[rr * 64 + lane];
      float s1 = x0 + x1, s2 = x0 * x0 + x1 * x1;
      #pragma unroll
      for (int off = 1; off < 64; off <<= 1) {
        s1 += __shfl_xor(s1, off);
        s2 += __shfl_xor(s2, off);
      }
      float mu = s1 * (1.f / 128.f);
      float var = s2 * (1.f / 128.f) - mu * mu;
      float rs = rsqrt_acc(var + LN_EPS);
      float y0 = (x0 - mu) * rs * g[c0] + bta[c0];
      float y1 = (x1 - mu) * rs * g[c1] + bta[c1];
      Hst[row + c0] = y0; Hst[row + c1] = y1;
      unsigned short h0, l0, h1, l1; split2(y0, h0, l0); split2(y1, h1, l1);
      HbfOut[row + c0] = h0; HbfOut[hbPl + row + c0] = l0;
      HbfOut[row + c1] = h1; HbfOut[hbPl + row + c1] = l1;
    }
    __syncthreads();
  }
}

// ---------------- fused attention (+LN1), last layer (DHEAD=128), fp16, 8-wave ----------------
__global__ __launch_bounds__(512) void k_attn_fused(
    const unsigned short* __restrict__ q,      // fp16 [b][h][t][128]
    const unsigned short* __restrict__ kbuf,   // fp16 [b][h][t][128]
    const unsigned short* __restrict__ vT,     // fp16 [b][h][d][t]
    const float* __restrict__ head_mask,
    float* __restrict__ Hst, unsigned short* __restrict__ HbfOut, size_t hbPl,
    const float* __restrict__ g, const float* __restrict__ bta) {
  constexpr int KF = 4, NFO = 8, DHEAD = 128;
  constexpr int NT = SEQ / 32;
  __shared__ __align__(16) char shraw[8 * 32 * 40 * 2];  // 20KB (S); facc 16KB aliases
  int bid = blockIdx.x;
  int xcd = bid & 7, u = bid >> 3;
  int b = xcd * 2 + (u >> 4);
  int pidx = u & 15;
  int wid = threadIdx.x >> 6, lane = threadIdx.x & 63;
  int h = wid & 3, grp = wid >> 2;
  int lr = lane & 15, lg = lane >> 4;
  unsigned short* sw = (unsigned short*)(shraw + wid * 2560);  // [32][40]
  typedef float FRow[DHEAD];
  FRow* facc = (FRow*)shraw;
  const unsigned short* qh = q + (size_t)(b * NHEAD + h) * SEQ * DHEAD;
  const unsigned short* kh = kbuf + (size_t)(b * NHEAD + h) * SEQ * DHEAD;
  const unsigned short* vh = vT + (size_t)(b * NHEAD + h) * DHEAD * SEQ;
  float hm = head_mask[h];
  float hm3 = hm * hm * hm;

  for (int s = 0; s < 2; ++s) {
    int tile = (s == 0) ? pidx : (NT - 1 - pidx);
    int i0 = tile * 32;
    f16x8 qf[2][KF];
    #pragma unroll
    for (int mf = 0; mf < 2; ++mf)
      #pragma unroll
      for (int kf = 0; kf < KF; ++kf)
        qf[mf][kf] = *reinterpret_cast<const f16x8*>(
            qh + (size_t)(i0 + mf * 16 + lr) * DHEAD + kf * 32 + lg * 8);
    f32x4 oacc[2][NFO] = {};
    int jend = i0 + 32;
    for (int j0 = grp * 32; j0 < jend; j0 += 64) {
      f16x8 vch[NFO];
      #pragma unroll
      for (int nf = 0; nf < NFO; ++nf)
        vch[nf] = *reinterpret_cast<const f16x8*>(vh + (size_t)(nf * 16 + lr) * SEQ + j0 + lg * 8);
      #pragma unroll
      for (int nf2 = 0; nf2 < 2; ++nf2) {
        int j16 = j0 + nf2 * 16;
        f16x8 kfr[KF];
        #pragma unroll
        for (int kf = 0; kf < KF; ++kf)
          kfr[kf] = *reinterpret_cast<const f16x8*>(kh + (size_t)(j16 + lr) * DHEAD + kf * 32 + lg * 8);
        #pragma unroll
        for (int mf = 0; mf < 2; ++mf) {
          f32x4 sacc = {};
          #pragma unroll
          for (int kf = 0; kf < KF; ++kf)
            sacc = __builtin_amdgcn_mfma_f32_16x16x32_f16(qf[mf][kf], kfr[kf], sacc, 0, 0, 0);
          #pragma unroll
          for (int r = 0; r < 4; ++r) {
            int i = i0 + mf * 16 + lg * 4 + r;
            int j = j16 + lr;
            float v = (j <= i) ? fmaxf(sacc[r], 0.f) : 0.f;
            sw[(mf * 16 + lg * 4 + r) * 40 + nf2 * 16 + lr] = f2h(v);
          }
        }
      }
      asm volatile("s_waitcnt lgkmcnt(0)" ::: "memory");
      __builtin_amdgcn_sched_barrier(0);
      #pragma unroll
      for (int mf = 0; mf < 2; ++mf) {
        f16x8 sf = *reinterpret_cast<const f16x8*>(&sw[(mf * 16 + lr) * 40 + lg * 8]);
        #pragma unroll
        for (int nf = 0; nf < NFO; ++nf)
          oacc[mf][nf] = __builtin_amdgcn_mfma_f32_16x16x32_f16(sf, vch[nf], oacc[mf][nf], 0, 0, 0);
      }
    }
    __syncthreads();
    for (int x = threadIdx.x; x < 32 * DHEAD; x += 512) ((float*)shraw)[x] = 0.f;
    __syncthreads();
    for (int w = 0; w < 8; ++w) {
      if (wid == w) {
        #pragma unroll
        for (int mf = 0; mf < 2; ++mf)
          #pragma unroll
          for (int nf = 0; nf < NFO; ++nf)
            #pragma unroll
            for (int r = 0; r < 4; ++r) {
              int rr = mf * 16 + lg * 4 + r;
              facc[rr][nf * 16 + lr] += oacc[mf][nf][r] * hm3 / (float)(i0 + rr + 1);
            }
      }
      __syncthreads();
    }
    for (int rl = 0; rl < 4; ++rl) {
      int rr = wid * 4 + rl;
      size_t row = ((size_t)b * SEQ + i0 + rr) * EMB;
      int c0 = lane, c1 = lane + 64;
      float x0 = Hst[row + c0] + facc[rr][c0];
      float x1 = Hst[row + c1] + facc[rr][c1];
      float s1 = x0 + x1, s2 = x0 * x0 + x1 * x1;
      #pragma unroll
      for (int off = 1; off < 64; off <<= 1) {
        s1 += __shfl_xor(s1, off);
        s2 += __shfl_xor(s2, off);
      }
      float mu = s1 * (1.f / 128.f);
      float var = s2 * (1.f / 128.f) - mu * mu;
      float rs = rsqrt_acc(var + LN_EPS);
      float y0 = (x0 - mu) * rs * g[c0] + bta[c0];
      float y1 = (x1 - mu) * rs * g[c1] + bta[c1];
      Hst[row + c0] = y0; Hst[row + c1] = y1;
      unsigned short h0, l0, h1, l1; split2(y0, h0, l0); split2(y1, h1, l1);
      HbfOut[row + c0] = h0; HbfOut[hbPl + row + c0] = l0;
      HbfOut[row + c1] = h1; HbfOut[hbPl + row + c1] = l1;
    }
    __syncthreads();
  }
}

// ---------------- fused MLP2 + residual + LN2 (reads packed-u32 mid) ----------------
__global__ __launch_bounds__(256) void k_mlp2ln(
    const unsigned short* __restrict__ A,      // packed u32 plane [row][512]
    const unsigned short* __restrict__ BT, size_t bPl, const float* __restrict__ bias,
    float* __restrict__ Hst, unsigned short* __restrict__ HbfOut, size_t hbPl,
    unsigned short* __restrict__ Hh,
    const float* __restrict__ g, const float* __restrict__ bta) {
  int wid = threadIdx.x >> 6, lane = threadIdx.x & 63;
  int lr = lane & 15, lg = lane >> 4;
  int row0 = blockIdx.x * 64 + wid * 16;
  f32x4 acc[8] = {};
  const unsigned int* aP32 = (const unsigned int*)A + (size_t)(row0 + lr) * 512 + lg * 8;
  const unsigned short* bP = BT + lg * 8;
  for (int k0 = 0; k0 < 512; k0 += 32) {
    u32x4 pa = *reinterpret_cast<const u32x4*>(aP32 + k0);
    u32x4 pb = *reinterpret_cast<const u32x4*>(aP32 + k0 + 4);
    bf16x8 ah, al;
    #pragma unroll
    for (int j = 0; j < 4; ++j) {
      ah[j] = (short)(pa[j] & 0xffff);  al[j] = (short)(pa[j] >> 16);
      ah[4 + j] = (short)(pb[j] & 0xffff);  al[4 + j] = (short)(pb[j] >> 16);
    }
    #pragma unroll
    for (int nf = 0; nf < 8; ++nf) {
      const unsigned short* bpp = bP + (size_t)(nf * 16 + lr) * 512 + k0;
      bf16x8 bh = *reinterpret_cast<const bf16x8*>(bpp);
      bf16x8 bl = *reinterpret_cast<const bf16x8*>(bpp + bPl);
      acc[nf] = __builtin_amdgcn_mfma_f32_16x16x32_bf16(ah, bh, acc[nf], 0, 0, 0);
      acc[nf] = __builtin_amdgcn_mfma_f32_16x16x32_bf16(al, bh, acc[nf], 0, 0, 0);
      acc[nf] = __builtin_amdgcn_mfma_f32_16x16x32_bf16(ah, bl, acc[nf], 0, 0, 0);
    }
  }
  int rowb = row0 + lg * 4;
  float xv[8][4];
  float s1[4] = {}, s2[4] = {};
  #pragma unroll
  for (int nf = 0; nf < 8; ++nf) {
    int c = nf * 16 + lr;
    float bv = bias[c];
    #pragma unroll
    for (int r = 0; r < 4; ++r) {
      float x = acc[nf][r] + bv + Hst[(size_t)(rowb + r) * EMB + c];
      xv[nf][r] = x; s1[r] += x; s2[r] += x * x;
    }
  }
  #pragma unroll
  for (int off = 1; off < 16; off <<= 1) {
    #pragma unroll
    for (int r = 0; r < 4; ++r) {
      s1[r] += __shfl_xor(s1[r], off);
      s2[r] += __shfl_xor(s2[r], off);
    }
  }
  #pragma unroll
  for (int r = 0; r < 4; ++r) {
    float mu = s1[r] * (1.f / 128.f);
    float var = s2[r] * (1.f / 128.f) - mu * mu;
    float rs = rsqrt_acc(var + LN_EPS);
    #pragma unroll
    for (int nf = 0; nf < 8; ++nf) {
      int c = nf * 16 + lr;
      float y = (xv[nf][r] - mu) * rs * g[c] + bta[c];
      size_t o = (size_t)(rowb + r) * EMB + c;
      Hst[o] = y;
      unsigned short hi, lo; split2(y, hi, lo);
      HbfOut[o] = hi; HbfOut[hbPl + o] = lo;
      if (c < 64) Hh[(size_t)(rowb + r) * 64 + c] = f2h(y);
    }
  }
}

// ---------------- readout ----------------
__global__ __launch_bounds__(64) void k_readout(const float* __restrict__ H,
                                                const float* __restrict__ W, const float* __restrict__ b0,
                                                float* __restrict__ out) {
  int idx = blockIdx.x;           // b*512 + p
  int b = idx >> 9, p = idx & 511;
  size_t row = ((size_t)b * SEQ + 2 * p) * EMB;
  int lane = threadIdx.x;
  float acc = H[row + lane] * W[lane] + H[row + 64 + lane] * W[64 + lane];
  #pragma unroll
  for (int off = 1; off < 64; off <<= 1) acc += __shfl_xor(acc, off);
  if (lane == 0) out[idx] = acc + b0[0];
}

extern "C" void kernel_launch(void* const* d_in, const int* in_sizes, int n_in,
                              void* d_out, int out_size, void* d_ws, size_t ws_size,
                              hipStream_t stream) {
  (void)in_sizes; (void)n_in; (void)out_size; (void)ws_size;
  const float* xs        = (const float*)d_in[0];
  const float* ys        = (const float*)d_in[1];
  const float* head_mask = (const float*)d_in[2];
  const float* read_in_W = (const float*)d_in[3];
  const float* read_in_b = (const float*)d_in[4];
  const float* qW        = (const float*)d_in[5];
  const float* vW        = (const float*)d_in[6];
  const float* qW_last   = (const float*)d_in[7];
  const float* kW_last   = (const float*)d_in[8];
  const float* vW_last   = (const float*)d_in[9];
  const float* ln1_g     = (const float*)d_in[10];
  const float* ln1_b     = (const float*)d_in[11];
  const float* ln2_g     = (const float*)d_in[12];
  const float* ln2_b     = (const float*)d_in[13];
  const float* mlp_W1    = (const float*)d_in[14];
  const float* mlp_b1    = (const float*)d_in[15];
  const float* mlp_W2    = (const float*)d_in[16];
  const float* mlp_b2    = (const float*)d_in[17];
  const float* ro_W      = (const float*)d_in[18];
  const float* ro_b      = (const float*)d_in[19];

  const size_t HPL   = (size_t)BS * SEQ * EMB;          // 2M
  const size_t QVWPL = (size_t)11 * 512 * 128;
  const size_t W1PL  = (size_t)12 * 128 * 512;
  const size_t W2PL  = (size_t)12 * 512 * 128;
  const size_t LASTPL= (size_t)3 * 512 * 128;

  char* ws = (char*)d_ws;
  size_t off = 0;
  auto alloc = [&](size_t bytes) -> void* {
    void* p = ws + off;
    off += (bytes + 255) & ~(size_t)255;
    return p;
  };
  float* H             = (float*)alloc(HPL * 4);                  // 8 MB (in-place state)
  unsigned short* Hbf  = (unsigned short*)alloc(2 * HPL * 2);     // 8 MB bf16 split
  unsigned short* Hbf2 = (unsigned short*)alloc(2 * HPL * 2);     // 8 MB bf16 split
  unsigned short* Hh   = (unsigned short*)alloc((size_t)BS * SEQ * 64 * 2);  // 2 MB fp16 K image
  unsigned short* qbuf = (unsigned short*)alloc((size_t)BS * NHEAD * SEQ * 128 * 2); // 16 MB fp16
  unsigned short* kmid = (unsigned short*)alloc((size_t)BS * SEQ * 512 * 4);  // 32 MB (vT64/K-last fp16; mid packed u32)
  unsigned short* vTl  = (unsigned short*)alloc((size_t)BS * NHEAD * SEQ * 128 * 2); // 16 MB fp16
  unsigned short* qvWT = (unsigned short*)alloc(2 * QVWPL * 2);
  unsigned short* W1T  = (unsigned short*)alloc(2 * W1PL * 2);
  unsigned short* W2T  = (unsigned short*)alloc(2 * W2PL * 2);
  unsigned short* lastT= (unsigned short*)alloc(2 * LASTPL * 2);

  { int tot = 11 * 512 * 128; k_prep_qv<<<dim3((tot + 255) / 256), 256, 0, stream>>>(qW, vW, qvWT, QVWPL); }
  { int tot = 12 * 512 * 128; k_transpose_pad<<<dim3((tot + 255) / 256), 256, 0, stream>>>(mlp_W1, W1T, W1PL, 12, 128, 512, 128, 512); }
  { int tot = 12 * 128 * 512; k_transpose_pad<<<dim3((tot + 255) / 256), 256, 0, stream>>>(mlp_W2, W2T, W2PL, 12, 512, 128, 512, 128); }
  { int tot = 512 * 128;
    k_transpose_pad<<<dim3((tot + 255) / 256), 256, 0, stream>>>(qW_last, lastT,          LASTPL, 1, 128, 512, 128, 512);
    k_transpose_pad<<<dim3((tot + 255) / 256), 256, 0, stream>>>(kW_last, lastT + 65536,  LASTPL, 1, 128, 512, 128, 512);
    k_transpose_pad<<<dim3((tot + 255) / 256), 256, 0, stream>>>(vW_last, lastT + 131072, LASTPL, 1, 128, 512, 128, 512); }

  k_combine_readin<<<dim3(BS * SEQ), 128, 0, stream>>>(xs, ys, read_in_W, read_in_b, H, Hbf, HPL, Hh);

  for (int l = 0; l < 11; ++l) {
    k_gemm<3, false, 128><<<dim3(256, 8), 256, 0, stream>>>(
        Hbf, 128, HPL, qvWT + (size_t)l * 65536, QVWPL, nullptr, 512,
        qbuf, kmid, nullptr);
    k_attn_v7<<<dim3(256), 512, 65536, stream>>>(
        qbuf, Hh, kmid, head_mask, H, Hbf2, HPL, ln1_g + l * 128, ln1_b + l * 128);
    k_gemm<0, true, 128><<<dim3(256, 8), 256, 0, stream>>>(
        Hbf2, 128, HPL, W1T + (size_t)l * 65536, W1PL, mlp_b1 + l * 512, 512,
        kmid, nullptr, nullptr);
    k_mlp2ln<<<dim3(256), 256, 0, stream>>>(
        kmid, W2T + (size_t)l * 65536, W2PL, mlp_b2 + l * 128,
        H, Hbf, HPL, Hh, ln2_g + l * 128, ln2_b + l * 128);
  }
  // last layer: q,k,v fp16 projections in one GEMM (N=1536)
  k_gemm<2, false, 128><<<dim3(256, 24), 256, 0, stream>>>(
      Hbf, 128, HPL, lastT, LASTPL, nullptr, 1536,
      qbuf, kmid, vTl);
  k_attn_fused<<<dim3(256), 512, 0, stream>>>(
      qbuf, kmid, vTl, head_mask, H, Hbf2, HPL, ln1_g + 11 * 128, ln1_b + 11 * 128);
  k_gemm<0, true, 128><<<dim3(256, 8), 256, 0, stream>>>(
      Hbf2, 128, HPL, W1T + (size_t)11 * 65536, W1PL, mlp_b1 + 11 * 512, 512,
      kmid, nullptr, nullptr);
  k_mlp2ln<<<dim3(256), 256, 0, stream>>>(
      kmid, W2T + (size_t)11 * 65536, W2PL, mlp_b2 + 11 * 128,
      H, Hbf, HPL, Hh, ln2_g + 11 * 128, ln2_b + 11 * 128);

  k_readout<<<dim3(8192), 64, 0, stream>>>(H, ro_W, ro_b, (float*)d_out);
}

// Round 9
// 1562.769 us; speedup vs baseline: 1.7645x; 1.3500x over previous
//
#include <hip/hip_runtime.h>

#define BS 16
#define SEQ 1024
#define EMB 128
#define NHEAD 4
#define LN_EPS 1e-5f

typedef __attribute__((ext_vector_type(8))) short bf16x8;
typedef __attribute__((ext_vector_type(8))) _Float16 f16x8;
typedef __attribute__((ext_vector_type(4))) float f32x4;
typedef __attribute__((ext_vector_type(4))) unsigned short u16x4;
typedef __attribute__((ext_vector_type(4))) unsigned int u32x4;

__device__ __forceinline__ unsigned short f2b(float f) {
  union { float f; unsigned u; } v; v.f = f;
  unsigned r = v.u + 0x7fff + ((v.u >> 16) & 1);
  return (unsigned short)(r >> 16);
}
__device__ __forceinline__ unsigned short f2h(float f) {
  union { _Float16 h; unsigned short u; } v; v.h = (_Float16)f; return v.u;
}
// split x into hi+lo bf16 (3-term Markidis precision: rel err ~2^-17)
__device__ __forceinline__ void split2(float x, unsigned short& hi, unsigned short& lo) {
  unsigned short h = f2b(x);
  float hf = __uint_as_float((unsigned)h << 16);
  hi = h; lo = f2b(x - hf);
}
__device__ __forceinline__ float rsqrt_acc(float v) {
  float r = rsqrtf(v);
  return r * (1.5f - 0.5f * v * r * r);   // one Newton step -> ~f32-exact
}

// ---------------- weight prep ----------------
__global__ void k_transpose_pad(const float* __restrict__ in, unsigned short* __restrict__ out,
                                size_t PL, int L, int Kin, int Nin, int Kout, int Nout) {
  int idx = blockIdx.x * 256 + threadIdx.x;
  int total = L * Kout * Nout;
  if (idx >= total) return;
  int k = idx % Kout;
  int n = (idx / Kout) % Nout;
  int l = idx / (Kout * Nout);
  float v = (k < Kin && n < Nin) ? in[(size_t)l * Kin * Nin + (size_t)k * Nin + n] : 0.f;
  unsigned short hi, lo; split2(v, hi, lo);
  out[idx] = hi; out[PL + idx] = lo;
}

// qvWT[l][512][128]: n<256 -> q (qW rows -> H dims 64..126), n>=256 -> v (H dims 0..62)
__global__ void k_prep_qv(const float* __restrict__ qW, const float* __restrict__ vW,
                          unsigned short* __restrict__ out, size_t PL) {
  int idx = blockIdx.x * 256 + threadIdx.x;
  int total = 11 * 512 * 128;
  if (idx >= total) return;
  int k = idx & 127;
  int n = (idx >> 7) & 511;
  int l = idx >> 16;
  float v = 0.f;
  if (n < 256) {
    if (n < 252 && k >= 64 && k < 127) v = qW[(size_t)l * 63 * 252 + (size_t)(k - 64) * 252 + n];
  } else {
    int n2 = n - 256;
    if (n2 < 252 && k < 63) v = vW[(size_t)l * 63 * 252 + (size_t)k * 252 + n2];
  }
  unsigned short hi, lo; split2(v, hi, lo);
  out[idx] = hi; out[PL + idx] = lo;
}

// ---------------- combine + read_in ----------------
__global__ void k_combine_readin(const float* __restrict__ xs, const float* __restrict__ ys,
                                 const float* __restrict__ W, const float* __restrict__ bias,
                                 float* __restrict__ H, unsigned short* __restrict__ Hbf, size_t hbPl,
                                 unsigned short* __restrict__ Hh) {
  int blk = blockIdx.x;            // b*1024 + t
  int b = blk >> 10, t = blk & 1023, p = t >> 1;
  __shared__ float zs[64];
  int tid = threadIdx.x;           // 128
  if (tid < 64) {
    float v;
    if (tid < 63) v = xs[((size_t)b * 512 + p) * 63 + tid];
    else v = (t & 1) ? ys[(size_t)b * 512 + p] : 0.f;
    zs[tid] = v;
  }
  __syncthreads();
  float acc = bias[tid];
  #pragma unroll 8
  for (int d = 0; d < 64; ++d) acc += zs[d] * W[d * 128 + tid];
  size_t o = (size_t)blk * 128 + tid;
  H[o] = acc;
  unsigned short hi, lo; split2(acc, hi, lo);
  Hbf[o] = hi; Hbf[hbPl + o] = lo;
  if (tid < 64) Hh[(size_t)blk * 64 + tid] = f2h(acc);  // fp16 K image (dims 0..63)
}

// ---------------- LDS-staged split-precision MFMA GEMM (K=128 staged whole) ----------------
// Inputs: A rows contiguous 128-wide (2-plane), BT rows contiguous 128-wide (2-plane).
// Stage A-tile(64x128 x2pl) + B-tile(64x128 x2pl) into LDS with coalesced 16B/lane loads,
// fragments come from LDS (pad 136: b128 reads at the 8-way floor).
// MODE 0: packed u32 (hi | lo<<16) out0[row*N+c]  (mlp1 mid)
// MODE 2: last qkv (N=1536) fp16: q,k [b][h][t][128]; v transposed [b][h][d][t]
// MODE 3: qv63 (N=512) fp16: c<256 q [b][h][t][64] (d63=0); else vT [b][h][d][t] (d63=0)
template<int MODE, bool RELU>
__global__ __launch_bounds__(256) void k_gemm(
    const unsigned short* __restrict__ A, size_t aPl,
    const unsigned short* __restrict__ BT, size_t bPl, const float* __restrict__ bias,
    int N,
    unsigned short* __restrict__ out0,
    unsigned short* __restrict__ out1,
    unsigned short* __restrict__ out2) {
  extern __shared__ unsigned short lds[];   // 4 planes x [64][136] = 69632 B
  int tid = threadIdx.x;
  int wid = tid >> 6, lane = tid & 63;
  int lr = lane & 15, lg = lane >> 4;
  int row0g = blockIdx.x * 64;
  int n0 = blockIdx.y * 64;
  unsigned short* Ah = lds;
  unsigned short* Al = Ah + 64 * 136;
  unsigned short* Bh = Al + 64 * 136;
  unsigned short* Bl = Bh + 64 * 136;
  {
    const unsigned short* gA = A + (size_t)row0g * 128;
    const unsigned short* gB = BT + (size_t)n0 * 128;
    const unsigned short* srcs[4] = { gA, gA + aPl, gB, gB + bPl };
    unsigned short* dsts[4] = { Ah, Al, Bh, Bl };
    #pragma unroll
    for (int p = 0; p < 4; ++p)
      #pragma unroll
      for (int it = 0; it < 4; ++it) {
        int e = it * 2048 + tid * 8;
        bf16x8 v = *reinterpret_cast<const bf16x8*>(srcs[p] + e);
        *reinterpret_cast<bf16x8*>(dsts[p] + (e >> 7) * 136 + (e & 127)) = v;
      }
  }
  __syncthreads();
  bf16x8 afh[4], afl[4];
  #pragma unroll
  for (int kf = 0; kf < 4; ++kf) {
    int o = (wid * 16 + lr) * 136 + kf * 32 + lg * 8;
    afh[kf] = *reinterpret_cast<const bf16x8*>(Ah + o);
    afl[kf] = *reinterpret_cast<const bf16x8*>(Al + o);
  }
  f32x4 acc[4] = {};
  #pragma unroll
  for (int nf = 0; nf < 4; ++nf) {
    #pragma unroll
    for (int kf = 0; kf < 4; ++kf) {
      int o = (nf * 16 + lr) * 136 + kf * 32 + lg * 8;
      bf16x8 bh = *reinterpret_cast<const bf16x8*>(Bh + o);
      bf16x8 bl = *reinterpret_cast<const bf16x8*>(Bl + o);
      acc[nf] = __builtin_amdgcn_mfma_f32_16x16x32_bf16(afh[kf], bh, acc[nf], 0, 0, 0);
      acc[nf] = __builtin_amdgcn_mfma_f32_16x16x32_bf16(afl[kf], bh, acc[nf], 0, 0, 0);
      acc[nf] = __builtin_amdgcn_mfma_f32_16x16x32_bf16(afh[kf], bl, acc[nf], 0, 0, 0);
    }
  }
  __syncthreads();   // done with staged inputs; reuse lds for the output tile
  // ---- stage output tile ----
  #pragma unroll
  for (int nf = 0; nf < 4; ++nf) {
    int c = n0 + nf * 16 + lr;
    float bv = bias ? bias[c] : 0.f;
    #pragma unroll
    for (int r = 0; r < 4; ++r) {
      float v = acc[nf][r] + bv;
      if (RELU) v = fmaxf(v, 0.f);
      int rL = wid * 16 + lg * 4 + r, cL = nf * 16 + lr;
      if (MODE == 0) {
        unsigned short hi, lo; split2(v, hi, lo);
        ((unsigned int(*)[65])lds)[rL][cL] = (unsigned)hi | ((unsigned)lo << 16);
      } else {
        ((unsigned short(*)[66])lds)[rL][cL] = f2h(v);
      }
    }
  }
  __syncthreads();
  // ---- coalesced writes ----
  if (MODE == 0) {
    unsigned int* o32 = (unsigned int*)out0;
    unsigned int (*tile)[65] = (unsigned int(*)[65])lds;
    for (int rr = wid; rr < 64; rr += 4)
      o32[(size_t)(row0g + rr) * N + n0 + lane] = tile[rr][lane];
  } else if (MODE == 2) {
    unsigned short (*t16)[66] = (unsigned short(*)[66])lds;
    int b = row0g >> 10, t0 = row0g & 1023;
    int tsel = n0 >> 9, c2b = n0 & 511, hh = c2b >> 7, dbase = c2b & 127;
    size_t bh = (size_t)b * NHEAD + hh;
    if (tsel < 2) {
      unsigned short* base = tsel ? out1 : out0;
      size_t rowbase = bh * SEQ * 128 + dbase + lane;
      for (int rr = wid; rr < 64; rr += 4)
        base[rowbase + (size_t)(t0 + rr) * 128] = t16[rr][lane];
    } else {
      for (int rr = wid; rr < 64; rr += 4) {
        int d = dbase + rr;
        out2[(bh * 128 + d) * SEQ + t0 + lane] = t16[lane][rr];
      }
    }
  } else {  // MODE 3
    unsigned short (*t16)[66] = (unsigned short(*)[66])lds;
    int b = row0g >> 10, t0 = row0g & 1023;
    if (n0 < 256) {              // q-half: [b][h][t][64], lanes -> d (contiguous)
      int c = n0 + lane;
      bool pad = (c >= 252);
      int hh = pad ? c - 252 : c / 63;
      int d  = pad ? 63 : c - hh * 63;
      size_t base = ((size_t)(b * NHEAD + hh) * SEQ) * 64 + d;
      for (int rr = wid; rr < 64; rr += 4)
        out0[base + (size_t)(t0 + rr) * 64] = pad ? (unsigned short)0 : t16[rr][lane];
    } else {                     // v-half: [b][h][d][t], lanes -> t (128B lines)
      for (int rr = wid; rr < 64; rr += 4) {
        int cc = n0 - 256 + rr;
        bool pad = (cc >= 252);
        int hh = pad ? cc - 252 : cc / 63;
        int d  = pad ? 63 : cc - hh * 63;
        size_t addr = ((size_t)(b * NHEAD + hh) * 64 + d) * SEQ + t0 + lane;
        out1[addr] = pad ? (unsigned short)0 : t16[lane][rr];
      }
    }
  }
}

// ---------------- attention v7 (layers 0-10, D=64): fp16 single-plane, L2-resident ----------------
__global__ __launch_bounds__(512) void k_attn_v7(
    const unsigned short* __restrict__ q,      // fp16 [b][h][t][64]
    const unsigned short* __restrict__ Hh,     // fp16 [b][t][64]
    const unsigned short* __restrict__ vT,     // fp16 [b][h][d][t]
    const float* __restrict__ head_mask,
    float* __restrict__ Hst, unsigned short* __restrict__ HbfOut, size_t hbPl,
    const float* __restrict__ g, const float* __restrict__ bta) {
  extern __shared__ char sh[];  // [0,16K) Kbuf x2; [16K,36K) S; epilogue aliases [0,64K)
  int bid = blockIdx.x;
  int xcd = bid & 7, u = bid >> 3;
  int b = xcd * 2 + (u >> 4);
  int pidx = u & 15;
  int tid = threadIdx.x;
  int wid = tid >> 6, lane = tid & 63;
  int h = wid & 3, grp = wid >> 2;
  int lr = lane & 15, lg = lane >> 4;
  int i0t[2] = { pidx * 32, (31 - pidx) * 32 };
  int NSS = (33 - pidx) >> 1;              // supersteps of 64 keys

  const char* gK = (const char*)(Hh + (size_t)b * SEQ * 64);
  char* KB = sh;
  unsigned short* sw = (unsigned short*)(sh + 16384 + wid * 2560);  // [32][40] fp16

  const unsigned short* qh = q + (size_t)(b * NHEAD + h) * SEQ * 64;
  const unsigned short* vh = vT + (size_t)(b * NHEAD + h) * 64 * SEQ;

  f16x8 qf[2][2][2];                       // [tile][mf][kf]
  #pragma unroll
  for (int t = 0; t < 2; ++t)
    #pragma unroll
    for (int mf = 0; mf < 2; ++mf)
      #pragma unroll
      for (int kf = 0; kf < 2; ++kf)
        qf[t][mf][kf] = *reinterpret_cast<const f16x8*>(
            qh + (size_t)(i0t[t] + mf * 16 + lr) * 64 + kf * 32 + lg * 8);
  f32x4 oacc[2][2][4] = {};                // [tile][mf][nf]

  u32x4 sreg;
  auto SLOAD = [&](int ss) {
    sreg = *reinterpret_cast<const u32x4*>(gK + (size_t)ss * 8192 + tid * 16);
  };
  auto SWRITE = [&](int buf) {
    int row = tid >> 3, colb = (tid & 7) * 16;
    *reinterpret_cast<u32x4*>(KB + buf * 8192 + row * 128 + (colb ^ ((row & 7) << 4))) = sreg;
  };

  SLOAD(0); SWRITE(0);
  __syncthreads();

  for (int ss = 0; ss < NSS; ++ss) {
    int cur = ss & 1;
    bool more = (ss + 1 < NSS);
    if (more) SLOAD(ss + 1);               // issue early
    int js = ss * 64 + grp * 32;
    if (js < i0t[1] + 32) {                // wave-uniform
      f16x8 vch[4];
      #pragma unroll
      for (int nf = 0; nf < 4; ++nf)
        vch[nf] = *reinterpret_cast<const f16x8*>(vh + (size_t)(nf * 16 + lr) * SEQ + js + lg * 8);
      f16x8 kfr[2][2];
      #pragma unroll
      for (int nf2 = 0; nf2 < 2; ++nf2)
        #pragma unroll
        for (int kf = 0; kf < 2; ++kf) {
          int row = grp * 32 + nf2 * 16 + lr;
          int colb = kf * 64 + lg * 16;
          kfr[nf2][kf] = *reinterpret_cast<const f16x8*>(
              KB + cur * 8192 + row * 128 + (colb ^ ((row & 7) << 4)));
        }
      #pragma unroll
      for (int t = 0; t < 2; ++t) {
        if (js < i0t[t] + 32) {            // wave-uniform
          #pragma unroll
          for (int nf2 = 0; nf2 < 2; ++nf2) {
            #pragma unroll
            for (int mf = 0; mf < 2; ++mf) {
              f32x4 sacc = {};
              #pragma unroll
              for (int kf = 0; kf < 2; ++kf)
                sacc = __builtin_amdgcn_mfma_f32_16x16x32_f16(qf[t][mf][kf], kfr[nf2][kf], sacc, 0, 0, 0);
              #pragma unroll
              for (int r = 0; r < 4; ++r) {
                int i = i0t[t] + mf * 16 + lg * 4 + r;
                int j = js + nf2 * 16 + lr;
                float v = (j <= i) ? fmaxf(sacc[r], 0.f) : 0.f;
                sw[(mf * 16 + lg * 4 + r) * 40 + nf2 * 16 + lr] = f2h(v);
              }
            }
          }
          asm volatile("s_waitcnt lgkmcnt(0)" ::: "memory");
          __builtin_amdgcn_sched_barrier(0);
          #pragma unroll
          for (int mf = 0; mf < 2; ++mf) {
            f16x8 sf = *reinterpret_cast<const f16x8*>(&sw[(mf * 16 + lr) * 40 + lg * 8]);
            #pragma unroll
            for (int nf = 0; nf < 4; ++nf)
              oacc[t][mf][nf] = __builtin_amdgcn_mfma_f32_16x16x32_f16(sf, vch[nf], oacc[t][mf][nf], 0, 0, 0);
          }
        }
      }
    }
    if (more) SWRITE(cur ^ 1);             // write late; drained by syncthreads
    __syncthreads();
  }

  // ---- epilogue: tree-sum over 8 waves + 1/(i+1) + residual + LN1 (both tiles) ----
  float hm = head_mask[h];
  float hm3 = hm * hm * hm;
  float* f8 = (float*)sh;                  // [8][32][64] f32, aliases Kbuf+S
  for (int t = 0; t < 2; ++t) {
    #pragma unroll
    for (int mf = 0; mf < 2; ++mf)
      #pragma unroll
      for (int nf = 0; nf < 4; ++nf)
        #pragma unroll
        for (int r = 0; r < 4; ++r)
          f8[wid * 2048 + (mf * 16 + lg * 4 + r) * 64 + nf * 16 + lr] = oacc[t][mf][nf][r] * hm3;
    __syncthreads();
    for (int idx = tid; idx < 8192; idx += 512) f8[idx] += f8[idx + 8192];
    __syncthreads();
    for (int idx = tid; idx < 4096; idx += 512) f8[idx] += f8[idx + 4096];
    __syncthreads();
    for (int idx = tid; idx < 2048; idx += 512) {
      int rr = idx >> 6;
      f8[idx] = (f8[idx] + f8[idx + 2048]) / (float)(i0t[t] + rr + 1);
    }
    __syncthreads();
    for (int rl = 0; rl < 4; ++rl) {
      int rr = wid * 4 + rl;
      size_t row = ((size_t)b * SEQ + i0t[t] + rr) * EMB;
      int c0 = lane, c1 = lane + 64;
      float x0 = Hst[row + c0];
      float x1 = Hst[row + c1] + f8[rr * 64 + lane];
      float s1 = x0 + x1, s2 = x0 * x0 + x1 * x1;
      #pragma unroll
      for (int off = 1; off < 64; off <<= 1) {
        s1 += __shfl_xor(s1, off);
        s2 += __shfl_xor(s2, off);
      }
      float mu = s1 * (1.f / 128.f);
      float var = s2 * (1.f / 128.f) - mu * mu;
      float rs = rsqrt_acc(var + LN_EPS);
      float y0 = (x0 - mu) * rs * g[c0] + bta[c0];
      float y1 = (x1 - mu) * rs * g[c1] + bta[c1];
      Hst[row + c0] = y0; Hst[row + c1] = y1;
      unsigned short h0, l0, h1, l1; split2(y0, h0, l0); split2(y1, h1, l1);
      HbfOut[row + c0] = h0; HbfOut[hbPl + row + c0] = l0;
      HbfOut[row + c1] = h1; HbfOut[hbPl + row + c1] = l1;
    }
    __syncthreads();
  }
}

// ---------------- fused attention (+LN1), last layer (DHEAD=128), fp16, 8-wave ----------------
__global__ __launch_bounds__(512) void k_attn_fused(
    const unsigned short* __restrict__ q,      // fp16 [b][h][t][128]
    const unsigned short* __restrict__ kbuf,   // fp16 [b][h][t][128]
    const unsigned short* __restrict__ vT,     // fp16 [b][h][d][t]
    const float* __restrict__ head_mask,
    float* __restrict__ Hst, unsigned short* __restrict__ HbfOut, size_t hbPl,
    const float* __restrict__ g, const float* __restrict__ bta) {
  constexpr int KF = 4, NFO = 8, DHEAD = 128;
  constexpr int NT = SEQ / 32;
  __shared__ __align__(16) char shraw[8 * 32 * 40 * 2];  // 20KB (S); facc 16KB aliases
  int bid = blockIdx.x;
  int xcd = bid & 7, u = bid >> 3;
  int b = xcd * 2 + (u >> 4);
  int pidx = u & 15;
  int wid = threadIdx.x >> 6, lane = threadIdx.x & 63;
  int h = wid & 3, grp = wid >> 2;
  int lr = lane & 15, lg = lane >> 4;
  unsigned short* sw = (unsigned short*)(shraw + wid * 2560);  // [32][40]
  typedef float FRow[DHEAD];
  FRow* facc = (FRow*)shraw;
  const unsigned short* qh = q + (size_t)(b * NHEAD + h) * SEQ * DHEAD;
  const unsigned short* kh = kbuf + (size_t)(b * NHEAD + h) * SEQ * DHEAD;
  const unsigned short* vh = vT + (size_t)(b * NHEAD + h) * DHEAD * SEQ;
  float hm = head_mask[h];
  float hm3 = hm * hm * hm;

  for (int s = 0; s < 2; ++s) {
    int tile = (s == 0) ? pidx : (NT - 1 - pidx);
    int i0 = tile * 32;
    f16x8 qf[2][KF];
    #pragma unroll
    for (int mf = 0; mf < 2; ++mf)
      #pragma unroll
      for (int kf = 0; kf < KF; ++kf)
        qf[mf][kf] = *reinterpret_cast<const f16x8*>(
            qh + (size_t)(i0 + mf * 16 + lr) * DHEAD + kf * 32 + lg * 8);
    f32x4 oacc[2][NFO] = {};
    int jend = i0 + 32;
    for (int j0 = grp * 32; j0 < jend; j0 += 64) {
      f16x8 vch[NFO];
      #pragma unroll
      for (int nf = 0; nf < NFO; ++nf)
        vch[nf] = *reinterpret_cast<const f16x8*>(vh + (size_t)(nf * 16 + lr) * SEQ + j0 + lg * 8);
      #pragma unroll
      for (int nf2 = 0; nf2 < 2; ++nf2) {
        int j16 = j0 + nf2 * 16;
        f16x8 kfr[KF];
        #pragma unroll
        for (int kf = 0; kf < KF; ++kf)
          kfr[kf] = *reinterpret_cast<const f16x8*>(kh + (size_t)(j16 + lr) * DHEAD + kf * 32 + lg * 8);
        #pragma unroll
        for (int mf = 0; mf < 2; ++mf) {
          f32x4 sacc = {};
          #pragma unroll
          for (int kf = 0; kf < KF; ++kf)
            sacc = __builtin_amdgcn_mfma_f32_16x16x32_f16(qf[mf][kf], kfr[kf], sacc, 0, 0, 0);
          #pragma unroll
          for (int r = 0; r < 4; ++r) {
            int i = i0 + mf * 16 + lg * 4 + r;
            int j = j16 + lr;
            float v = (j <= i) ? fmaxf(sacc[r], 0.f) : 0.f;
            sw[(mf * 16 + lg * 4 + r) * 40 + nf2 * 16 + lr] = f2h(v);
          }
        }
      }
      asm volatile("s_waitcnt lgkmcnt(0)" ::: "memory");
      __builtin_amdgcn_sched_barrier(0);
      #pragma unroll
      for (int mf = 0; mf < 2; ++mf) {
        f16x8 sf = *reinterpret_cast<const f16x8*>(&sw[(mf * 16 + lr) * 40 + lg * 8]);
        #pragma unroll
        for (int nf = 0; nf < NFO; ++nf)
          oacc[mf][nf] = __builtin_amdgcn_mfma_f32_16x16x32_f16(sf, vch[nf], oacc[mf][nf], 0, 0, 0);
      }
    }
    __syncthreads();
    for (int x = threadIdx.x; x < 32 * DHEAD; x += 512) ((float*)shraw)[x] = 0.f;
    __syncthreads();
    for (int w = 0; w < 8; ++w) {
      if (wid == w) {
        #pragma unroll
        for (int mf = 0; mf < 2; ++mf)
          #pragma unroll
          for (int nf = 0; nf < NFO; ++nf)
            #pragma unroll
            for (int r = 0; r < 4; ++r) {
              int rr = mf * 16 + lg * 4 + r;
              facc[rr][nf * 16 + lr] += oacc[mf][nf][r] * hm3 / (float)(i0 + rr + 1);
            }
      }
      __syncthreads();
    }
    for (int rl = 0; rl < 4; ++rl) {
      int rr = wid * 4 + rl;
      size_t row = ((size_t)b * SEQ + i0 + rr) * EMB;
      int c0 = lane, c1 = lane + 64;
      float x0 = Hst[row + c0] + facc[rr][c0];
      float x1 = Hst[row + c1] + facc[rr][c1];
      float s1 = x0 + x1, s2 = x0 * x0 + x1 * x1;
      #pragma unroll
      for (int off = 1; off < 64; off <<= 1) {
        s1 += __shfl_xor(s1, off);
        s2 += __shfl_xor(s2, off);
      }
      float mu = s1 * (1.f / 128.f);
      float var = s2 * (1.f / 128.f) - mu * mu;
      float rs = rsqrt_acc(var + LN_EPS);
      float y0 = (x0 - mu) * rs * g[c0] + bta[c0];
      float y1 = (x1 - mu) * rs * g[c1] + bta[c1];
      Hst[row + c0] = y0; Hst[row + c1] = y1;
      unsigned short h0, l0, h1, l1; split2(y0, h0, l0); split2(y1, h1, l1);
      HbfOut[row + c0] = h0; HbfOut[hbPl + row + c0] = l0;
      HbfOut[row + c1] = h1; HbfOut[hbPl + row + c1] = l1;
    }
    __syncthreads();
  }
}

// ---------------- fused MLP2 + residual + LN2 (reads packed-u32 mid) ----------------
__global__ __launch_bounds__(256) void k_mlp2ln(
    const unsigned short* __restrict__ A,      // packed u32 plane [row][512]
    const unsigned short* __restrict__ BT, size_t bPl, const float* __restrict__ bias,
    float* __restrict__ Hst, unsigned short* __restrict__ HbfOut, size_t hbPl,
    unsigned short* __restrict__ Hh,
    const float* __restrict__ g, const float* __restrict__ bta) {
  int wid = threadIdx.x >> 6, lane = threadIdx.x & 63;
  int lr = lane & 15, lg = lane >> 4;
  int row0 = blockIdx.x * 64 + wid * 16;
  f32x4 acc[8] = {};
  const unsigned int* aP32 = (const unsigned int*)A + (size_t)(row0 + lr) * 512 + lg * 8;
  const unsigned short* bP = BT + lg * 8;
  for (int k0 = 0; k0 < 512; k0 += 32) {
    u32x4 pa = *reinterpret_cast<const u32x4*>(aP32 + k0);
    u32x4 pb = *reinterpret_cast<const u32x4*>(aP32 + k0 + 4);
    bf16x8 ah, al;
    #pragma unroll
    for (int j = 0; j < 4; ++j) {
      ah[j] = (short)(pa[j] & 0xffff);  al[j] = (short)(pa[j] >> 16);
      ah[4 + j] = (short)(pb[j] & 0xffff);  al[4 + j] = (short)(pb[j] >> 16);
    }
    #pragma unroll
    for (int nf = 0; nf < 8; ++nf) {
      const unsigned short* bpp = bP + (size_t)(nf * 16 + lr) * 512 + k0;
      bf16x8 bh = *reinterpret_cast<const bf16x8*>(bpp);
      bf16x8 bl = *reinterpret_cast<const bf16x8*>(bpp + bPl);
      acc[nf] = __builtin_amdgcn_mfma_f32_16x16x32_bf16(ah, bh, acc[nf], 0, 0, 0);
      acc[nf] = __builtin_amdgcn_mfma_f32_16x16x32_bf16(al, bh, acc[nf], 0, 0, 0);
      acc[nf] = __builtin_amdgcn_mfma_f32_16x16x32_bf16(ah, bl, acc[nf], 0, 0, 0);
    }
  }
  int rowb = row0 + lg * 4;
  float xv[8][4];
  float s1[4] = {}, s2[4] = {};
  #pragma unroll
  for (int nf = 0; nf < 8; ++nf) {
    int c = nf * 16 + lr;
    float bv = bias[c];
    #pragma unroll
    for (int r = 0; r < 4; ++r) {
      float x = acc[nf][r] + bv + Hst[(size_t)(rowb + r) * EMB + c];
      xv[nf][r] = x; s1[r] += x; s2[r] += x * x;
    }
  }
  #pragma unroll
  for (int off = 1; off < 16; off <<= 1) {
    #pragma unroll
    for (int r = 0; r < 4; ++r) {
      s1[r] += __shfl_xor(s1[r], off);
      s2[r] += __shfl_xor(s2[r], off);
    }
  }
  #pragma unroll
  for (int r = 0; r < 4; ++r) {
    float mu = s1[r] * (1.f / 128.f);
    float var = s2[r] * (1.f / 128.f) - mu * mu;
    float rs = rsqrt_acc(var + LN_EPS);
    #pragma unroll
    for (int nf = 0; nf < 8; ++nf) {
      int c = nf * 16 + lr;
      float y = (xv[nf][r] - mu) * rs * g[c] + bta[c];
      size_t o = (size_t)(rowb + r) * EMB + c;
      Hst[o] = y;
      unsigned short hi, lo; split2(y, hi, lo);
      HbfOut[o] = hi; HbfOut[hbPl + o] = lo;
      if (c < 64) Hh[(size_t)(rowb + r) * 64 + c] = f2h(y);
    }
  }
}

// ---------------- readout ----------------
__global__ __launch_bounds__(64) void k_readout(const float* __restrict__ H,
                                                const float* __restrict__ W, const float* __restrict__ b0,
                                                float* __restrict__ out) {
  int idx = blockIdx.x;           // b*512 + p
  int b = idx >> 9, p = idx & 511;
  size_t row = ((size_t)b * SEQ + 2 * p) * EMB;
  int lane = threadIdx.x;
  float acc = H[row + lane] * W[lane] + H[row + 64 + lane] * W[64 + lane];
  #pragma unroll
  for (int off = 1; off < 64; off <<= 1) acc += __shfl_xor(acc, off);
  if (lane == 0) out[idx] = acc + b0[0];
}

extern "C" void kernel_launch(void* const* d_in, const int* in_sizes, int n_in,
                              void* d_out, int out_size, void* d_ws, size_t ws_size,
                              hipStream_t stream) {
  (void)in_sizes; (void)n_in; (void)out_size; (void)ws_size;
  const float* xs        = (const float*)d_in[0];
  const float* ys        = (const float*)d_in[1];
  const float* head_mask = (const float*)d_in[2];
  const float* read_in_W = (const float*)d_in[3];
  const float* read_in_b = (const float*)d_in[4];
  const float* qW        = (const float*)d_in[5];
  const float* vW        = (const float*)d_in[6];
  const float* qW_last   = (const float*)d_in[7];
  const float* kW_last   = (const float*)d_in[8];
  const float* vW_last   = (const float*)d_in[9];
  const float* ln1_g     = (const float*)d_in[10];
  const float* ln1_b     = (const float*)d_in[11];
  const float* ln2_g     = (const float*)d_in[12];
  const float* ln2_b     = (const float*)d_in[13];
  const float* mlp_W1    = (const float*)d_in[14];
  const float* mlp_b1    = (const float*)d_in[15];
  const float* mlp_W2    = (const float*)d_in[16];
  const float* mlp_b2    = (const float*)d_in[17];
  const float* ro_W      = (const float*)d_in[18];
  const float* ro_b      = (const float*)d_in[19];

  const size_t HPL   = (size_t)BS * SEQ * EMB;          // 2M
  const size_t QVWPL = (size_t)11 * 512 * 128;
  const size_t W1PL  = (size_t)12 * 128 * 512;
  const size_t W2PL  = (size_t)12 * 512 * 128;
  const size_t LASTPL= (size_t)3 * 512 * 128;

  char* ws = (char*)d_ws;
  size_t off = 0;
  auto alloc = [&](size_t bytes) -> void* {
    void* p = ws + off;
    off += (bytes + 255) & ~(size_t)255;
    return p;
  };
  float* H             = (float*)alloc(HPL * 4);                  // 8 MB (in-place state)
  unsigned short* Hbf  = (unsigned short*)alloc(2 * HPL * 2);     // 8 MB bf16 split
  unsigned short* Hbf2 = (unsigned short*)alloc(2 * HPL * 2);     // 8 MB bf16 split
  unsigned short* Hh   = (unsigned short*)alloc((size_t)BS * SEQ * 64 * 2);  // 2 MB fp16 K image
  unsigned short* qbuf = (unsigned short*)alloc((size_t)BS * NHEAD * SEQ * 128 * 2); // 16 MB fp16
  unsigned short* kmid = (unsigned short*)alloc((size_t)BS * SEQ * 512 * 4);  // 32 MB (vT64/K-last fp16; mid packed u32)
  unsigned short* vTl  = (unsigned short*)alloc((size_t)BS * NHEAD * SEQ * 128 * 2); // 16 MB fp16
  unsigned short* qvWT = (unsigned short*)alloc(2 * QVWPL * 2);
  unsigned short* W1T  = (unsigned short*)alloc(2 * W1PL * 2);
  unsigned short* W2T  = (unsigned short*)alloc(2 * W2PL * 2);
  unsigned short* lastT= (unsigned short*)alloc(2 * LASTPL * 2);

  { int tot = 11 * 512 * 128; k_prep_qv<<<dim3((tot + 255) / 256), 256, 0, stream>>>(qW, vW, qvWT, QVWPL); }
  { int tot = 12 * 512 * 128; k_transpose_pad<<<dim3((tot + 255) / 256), 256, 0, stream>>>(mlp_W1, W1T, W1PL, 12, 128, 512, 128, 512); }
  { int tot = 12 * 128 * 512; k_transpose_pad<<<dim3((tot + 255) / 256), 256, 0, stream>>>(mlp_W2, W2T, W2PL, 12, 512, 128, 512, 128); }
  { int tot = 512 * 128;
    k_transpose_pad<<<dim3((tot + 255) / 256), 256, 0, stream>>>(qW_last, lastT,          LASTPL, 1, 128, 512, 128, 512);
    k_transpose_pad<<<dim3((tot + 255) / 256), 256, 0, stream>>>(kW_last, lastT + 65536,  LASTPL, 1, 128, 512, 128, 512);
    k_transpose_pad<<<dim3((tot + 255) / 256), 256, 0, stream>>>(vW_last, lastT + 131072, LASTPL, 1, 128, 512, 128, 512); }

  k_combine_readin<<<dim3(BS * SEQ), 128, 0, stream>>>(xs, ys, read_in_W, read_in_b, H, Hbf, HPL, Hh);

  const int GEMM_LDS = 4 * 64 * 136 * 2;   // 69632 B
  for (int l = 0; l < 11; ++l) {
    k_gemm<3, false><<<dim3(256, 8), 256, GEMM_LDS, stream>>>(
        Hbf, HPL, qvWT + (size_t)l * 65536, QVWPL, nullptr, 512,
        qbuf, kmid, nullptr);
    k_attn_v7<<<dim3(256), 512, 65536, stream>>>(
        qbuf, Hh, kmid, head_mask, H, Hbf2, HPL, ln1_g + l * 128, ln1_b + l * 128);
    k_gemm<0, true><<<dim3(256, 8), 256, GEMM_LDS, stream>>>(
        Hbf2, HPL, W1T + (size_t)l * 65536, W1PL, mlp_b1 + l * 512, 512,
        kmid, nullptr, nullptr);
    k_mlp2ln<<<dim3(256), 256, 0, stream>>>(
        kmid, W2T + (size_t)l * 65536, W2PL, mlp_b2 + l * 128,
        H, Hbf, HPL, Hh, ln2_g + l * 128, ln2_b + l * 128);
  }
  // last layer: q,k,v fp16 projections in one GEMM (N=1536)
  k_gemm<2, false><<<dim3(256, 24), 256, GEMM_LDS, stream>>>(
      Hbf, HPL, lastT, LASTPL, nullptr, 1536,
      qbuf, kmid, vTl);
  k_attn_fused<<<dim3(256), 512, 0, stream>>>(
      qbuf, kmid, vTl, head_mask, H, Hbf2, HPL, ln1_g + 11 * 128, ln1_b + 11 * 128);
  k_gemm<0, true><<<dim3(256, 8), 256, GEMM_LDS, stream>>>(
      Hbf2, HPL, W1T + (size_t)11 * 65536, W1PL, mlp_b1 + 11 * 512, 512,
      kmid, nullptr, nullptr);
  k_mlp2ln<<<dim3(256), 256, 0, stream>>>(
      kmid, W2T + (size_t)11 * 65536, W2PL, mlp_b2 + 11 * 128,
      H, Hbf, HPL, Hh, ln2_g + 11 * 128, ln2_b + 11 * 128);

  k_readout<<<dim3(8192), 64, 0, stream>>>(H, ro_W, ro_b, (float*)d_out);
}

// Round 10
// 1209.779 us; speedup vs baseline: 2.2793x; 1.2918x over previous
//
#include <hip/hip_runtime.h>

#define BS 16
#define SEQ 1024
#define EMB 128
#define NHEAD 4
#define LN_EPS 1e-5f

typedef __attribute__((ext_vector_type(8))) short bf16x8;
typedef __attribute__((ext_vector_type(8))) _Float16 f16x8;
typedef __attribute__((ext_vector_type(4))) float f32x4;
typedef __attribute__((ext_vector_type(4))) unsigned short u16x4;
typedef __attribute__((ext_vector_type(4))) unsigned int u32x4;

__device__ __forceinline__ unsigned short f2b(float f) {
  union { float f; unsigned u; } v; v.f = f;
  unsigned r = v.u + 0x7fff + ((v.u >> 16) & 1);
  return (unsigned short)(r >> 16);
}
__device__ __forceinline__ unsigned short f2h(float f) {
  union { _Float16 h; unsigned short u; } v; v.h = (_Float16)f; return v.u;
}
// split x into hi+lo bf16 (3-term Markidis precision: rel err ~2^-17)
__device__ __forceinline__ void split2(float x, unsigned short& hi, unsigned short& lo) {
  unsigned short h = f2b(x);
  float hf = __uint_as_float((unsigned)h << 16);
  hi = h; lo = f2b(x - hf);
}
__device__ __forceinline__ float rsqrt_acc(float v) {
  float r = rsqrtf(v);
  return r * (1.5f - 0.5f * v * r * r);   // one Newton step -> ~f32-exact
}

// ---------------- weight prep: fragment-ordered 2-plane bf16 ----------------
// layout: flat = ((l*nblk + kc*(N/16) + nb)*64 + lane)*8 + e ; n = nb*16+(lane&15),
// k = kc*32 + (lane>>4)*8 + e. val = in[l][k][n] (transpose), zero-padded.
__global__ void k_prep_fragT(const float* __restrict__ in, unsigned short* __restrict__ out,
                             size_t PL, int L, int Kin, int Nin, int N, int K) {
  int idx = blockIdx.x * 256 + threadIdx.x;
  int nblk = (N >> 4) * (K >> 5);
  int total = L * N * K;
  if (idx >= total) return;
  int e = idx & 7;
  int lane = (idx >> 3) & 63;
  int blk = (idx >> 9) % nblk;
  int l = idx / (512 * nblk);
  int nb = blk % (N >> 4), kc = blk / (N >> 4);
  int n = nb * 16 + (lane & 15);
  int k = kc * 32 + (lane >> 4) * 8 + e;
  float v = (k < Kin && n < Nin) ? in[(size_t)l * Kin * Nin + (size_t)k * Nin + n] : 0.f;
  unsigned short hi, lo; split2(v, hi, lo);
  out[idx] = hi; out[PL + idx] = lo;
}

// qvW frag: N=512, K=128; n<256 -> q side: h=n>>6, d=n&63 (d=63 zero; qW rows = H dims 64..126)
//           n>=256 -> v side: h=(n-256)>>6, d=(n-256)&63 (d=63 zero; vW rows = H dims 0..62)
__global__ void k_prep_qvfrag(const float* __restrict__ qW, const float* __restrict__ vW,
                              unsigned short* __restrict__ out, size_t PL) {
  int idx = blockIdx.x * 256 + threadIdx.x;
  int total = 11 * 512 * 128;
  if (idx >= total) return;
  int e = idx & 7;
  int lane = (idx >> 3) & 63;
  int blk = (idx >> 9) & 127;       // kc*32 + nb
  int l = idx >> 16;
  int nb = blk & 31, kc = blk >> 5;
  int n = nb * 16 + (lane & 15);
  int k = kc * 32 + (lane >> 4) * 8 + e;
  float v = 0.f;
  if (n < 256) {
    int hh = n >> 6, d = n & 63;
    if (d < 63 && k >= 64 && k < 127) v = qW[(size_t)l * 63 * 252 + (size_t)(k - 64) * 252 + hh * 63 + d];
  } else {
    int n2 = n - 256, hh = n2 >> 6, d = n2 & 63;
    if (d < 63 && k < 63) v = vW[(size_t)l * 63 * 252 + (size_t)k * 252 + hh * 63 + d];
  }
  unsigned short hi, lo; split2(v, hi, lo);
  out[idx] = hi; out[PL + idx] = lo;
}

// last-layer qkv frag: N=1536, K=128; n -> tsel = n>>9, col n&511 of {qW,kW,vW}_last [128][512]
__global__ void k_prep_lastfrag(const float* __restrict__ qW, const float* __restrict__ kW,
                                const float* __restrict__ vW,
                                unsigned short* __restrict__ out, size_t PL) {
  int idx = blockIdx.x * 256 + threadIdx.x;
  int total = 1536 * 128;
  if (idx >= total) return;
  int e = idx & 7;
  int lane = (idx >> 3) & 63;
  int blk = idx >> 9;               // kc*96 + nb
  int nb = blk % 96, kc = blk / 96;
  int n = nb * 16 + (lane & 15);
  int k = kc * 32 + (lane >> 4) * 8 + e;
  int tsel = n >> 9, n2 = n & 511;
  const float* W = tsel == 0 ? qW : (tsel == 1 ? kW : vW);
  float v = W[(size_t)k * 512 + n2];
  unsigned short hi, lo; split2(v, hi, lo);
  out[idx] = hi; out[PL + idx] = lo;
}

// ---------------- combine + read_in ----------------
__global__ void k_combine_readin(const float* __restrict__ xs, const float* __restrict__ ys,
                                 const float* __restrict__ W, const float* __restrict__ bias,
                                 float* __restrict__ H, unsigned short* __restrict__ Hbf, size_t hbPl,
                                 unsigned short* __restrict__ Hh) {
  int blk = blockIdx.x;            // b*1024 + t
  int b = blk >> 10, t = blk & 1023, p = t >> 1;
  __shared__ float zs[64];
  int tid = threadIdx.x;           // 128
  if (tid < 64) {
    float v;
    if (tid < 63) v = xs[((size_t)b * 512 + p) * 63 + tid];
    else v = (t & 1) ? ys[(size_t)b * 512 + p] : 0.f;
    zs[tid] = v;
  }
  __syncthreads();
  float acc = bias[tid];
  #pragma unroll 8
  for (int d = 0; d < 64; ++d) acc += zs[d] * W[d * 128 + tid];
  size_t o = (size_t)blk * 128 + tid;
  H[o] = acc;
  unsigned short hi, lo; split2(acc, hi, lo);
  Hbf[o] = hi; Hbf[hbPl + o] = lo;
  if (tid < 64) Hh[(size_t)blk * 64 + tid] = f2h(acc);  // fp16 K image (dims 0..63)
}

// ---------------- split-precision MFMA GEMM: A LDS-staged, B fragment-ordered ----------------
// MODE 0: mid frag-ordered packed u32 (hi|lo<<16): flat32 = ((rb*16+kc)*64+lane)*8+e
// MODE 2: last qkv frag fp16: q/k [bh][tb 64][kc 4][512]; v [bh][db 8][jc 32][512]
// MODE 3: qv frag fp16 (64-aligned heads): q [bh][tb 64][kc 2][512]; v [bh][db 4][jc 32][512]
template<int MODE, bool RELU>
__global__ __launch_bounds__(256) void k_gemm(
    const unsigned short* __restrict__ A, size_t aPl,
    const unsigned short* __restrict__ BT, size_t bPl, const float* __restrict__ bias,
    int N,
    unsigned short* __restrict__ out0,
    unsigned short* __restrict__ out1,
    unsigned short* __restrict__ out2) {
  extern __shared__ unsigned short lds[];   // A 2 planes [64][136] = 34816 B; tile reuse
  int tid = threadIdx.x;
  int wid = tid >> 6, lane = tid & 63;
  int lr = lane & 15, lg = lane >> 4;
  int row0g = blockIdx.x * 64;
  int n0 = blockIdx.y * 64;
  unsigned short* Ah = lds;
  unsigned short* Al = Ah + 64 * 136;
  {
    const unsigned short* gA = A + (size_t)row0g * 128;
    const unsigned short* srcs[2] = { gA, gA + aPl };
    unsigned short* dsts[2] = { Ah, Al };
    #pragma unroll
    for (int p = 0; p < 2; ++p)
      #pragma unroll
      for (int it = 0; it < 4; ++it) {
        int e = it * 2048 + tid * 8;
        bf16x8 v = *reinterpret_cast<const bf16x8*>(srcs[p] + e);
        *reinterpret_cast<bf16x8*>(dsts[p] + (e >> 7) * 136 + (e & 127)) = v;
      }
  }
  __syncthreads();
  bf16x8 afh[4], afl[4];
  #pragma unroll
  for (int kf = 0; kf < 4; ++kf) {
    int o = (wid * 16 + lr) * 136 + kf * 32 + lg * 8;
    afh[kf] = *reinterpret_cast<const bf16x8*>(Ah + o);
    afl[kf] = *reinterpret_cast<const bf16x8*>(Al + o);
  }
  f32x4 acc[4] = {};
  int nhw = N >> 4;
  #pragma unroll
  for (int nf = 0; nf < 4; ++nf) {
    #pragma unroll
    for (int kf = 0; kf < 4; ++kf) {
      size_t bo = ((size_t)kf * nhw + (n0 >> 4) + nf) * 512 + lane * 8;
      bf16x8 bh = *reinterpret_cast<const bf16x8*>(BT + bo);
      bf16x8 bl = *reinterpret_cast<const bf16x8*>(BT + bPl + bo);
      acc[nf] = __builtin_amdgcn_mfma_f32_16x16x32_bf16(afh[kf], bh, acc[nf], 0, 0, 0);
      acc[nf] = __builtin_amdgcn_mfma_f32_16x16x32_bf16(afl[kf], bh, acc[nf], 0, 0, 0);
      acc[nf] = __builtin_amdgcn_mfma_f32_16x16x32_bf16(afh[kf], bl, acc[nf], 0, 0, 0);
    }
  }
  __syncthreads();   // done with staged A; reuse lds for the output tile
  // ---- stage output tile ----
  #pragma unroll
  for (int nf = 0; nf < 4; ++nf) {
    int c = n0 + nf * 16 + lr;
    float bv = bias ? bias[c] : 0.f;
    #pragma unroll
    for (int r = 0; r < 4; ++r) {
      float v = acc[nf][r] + bv;
      if (RELU) v = fmaxf(v, 0.f);
      int rL = wid * 16 + lg * 4 + r, cL = nf * 16 + lr;
      if (MODE == 0) {
        unsigned short hi, lo; split2(v, hi, lo);
        ((unsigned int(*)[65])lds)[rL][cL] = (unsigned)hi | ((unsigned)lo << 16);
      } else {
        ((unsigned short(*)[66])lds)[rL][cL] = f2h(v);
      }
    }
  }
  __syncthreads();
  // ---- fragment-ordered coalesced writes ----
  int u = tid * 2;
  int lane2 = u >> 3, e0 = u & 7;
  if (MODE == 0) {
    unsigned int* o32 = (unsigned int*)out0;
    unsigned int (*tile)[65] = (unsigned int(*)[65])lds;
    int rb0 = row0g >> 4, kc0 = n0 >> 5;
    #pragma unroll
    for (int fb = 0; fb < 8; ++fb) {
      int rbl = fb >> 1, kcl = fb & 1;
      int row_l = rbl * 16 + (lane2 & 15);
      int c_l = kcl * 32 + ((lane2 >> 4) << 3) + e0;
      size_t dst = ((((size_t)rb0 + rbl) * 16 + kc0 + kcl) * 64 + lane2) * 8 + e0;
      o32[dst] = tile[row_l][c_l];
      o32[dst + 1] = tile[row_l][c_l + 1];
    }
  } else if (MODE == 2) {
    unsigned short (*t16)[66] = (unsigned short(*)[66])lds;
    int b = row0g >> 10, t0 = row0g & 1023;
    int tsel = n0 >> 9, c2b = n0 & 511, hh = c2b >> 7, dbase = c2b & 127;
    size_t bh = (size_t)b * NHEAD + hh;
    if (tsel < 2) {
      unsigned short* base = tsel ? out1 : out0;
      int tb0 = t0 >> 4, kc0 = dbase >> 5;
      #pragma unroll
      for (int fb = 0; fb < 8; ++fb) {
        int tbl = fb >> 1, kcl = fb & 1;
        int t_l = tbl * 16 + (lane2 & 15);
        int c_l = kcl * 32 + ((lane2 >> 4) << 3) + e0;
        size_t dst = ((bh * 64 + tb0 + tbl) * 4 + kc0 + kcl) * 512 + lane2 * 8 + e0;
        base[dst] = t16[t_l][c_l];
        base[dst + 1] = t16[t_l][c_l + 1];
      }
    } else {
      int db0 = dbase >> 4, jc0 = t0 >> 5;
      #pragma unroll
      for (int fb = 0; fb < 8; ++fb) {
        int dbl = fb >> 1, jcl = fb & 1;
        int c_l = dbl * 16 + (lane2 & 15);
        int t_l = jcl * 32 + ((lane2 >> 4) << 3) + e0;
        size_t dst = ((bh * 8 + db0 + dbl) * 32 + jc0 + jcl) * 512 + lane2 * 8 + e0;
        out2[dst] = t16[t_l][c_l];
        out2[dst + 1] = t16[t_l + 1][c_l];
      }
    }
  } else {  // MODE 3
    unsigned short (*t16)[66] = (unsigned short(*)[66])lds;
    int b = row0g >> 10, t0 = row0g & 1023;
    if (n0 < 256) {               // q: one 64-aligned head per block
      size_t bh = (size_t)b * NHEAD + (n0 >> 6);
      int tb0 = t0 >> 4;
      #pragma unroll
      for (int fb = 0; fb < 8; ++fb) {
        int tbl = fb >> 1, kcl = fb & 1;
        int t_l = tbl * 16 + (lane2 & 15);
        int c_l = kcl * 32 + ((lane2 >> 4) << 3) + e0;
        size_t dst = ((bh * 64 + tb0 + tbl) * 2 + kcl) * 512 + lane2 * 8 + e0;
        out0[dst] = t16[t_l][c_l];
        out0[dst + 1] = t16[t_l][c_l + 1];
      }
    } else {                      // v: one 64-aligned head per block
      size_t bh = (size_t)b * NHEAD + ((n0 - 256) >> 6);
      int jc0 = t0 >> 5;
      #pragma unroll
      for (int fb = 0; fb < 8; ++fb) {
        int dbl = fb >> 1, jcl = fb & 1;
        int c_l = dbl * 16 + (lane2 & 15);
        int t_l = jcl * 32 + ((lane2 >> 4) << 3) + e0;
        size_t dst = ((bh * 4 + dbl) * 32 + jc0 + jcl) * 512 + lane2 * 8 + e0;
        out1[dst] = t16[t_l][c_l];
        out1[dst + 1] = t16[t_l + 1][c_l];
      }
    }
  }
}

// ---------------- attention v7 (layers 0-10, D=64): fp16, frag-ordered q/v, K LDS-staged ----------------
__global__ __launch_bounds__(512) void k_attn_v7(
    const unsigned short* __restrict__ q,      // fp16 frag [bh][tb 64][kc 2][512]
    const unsigned short* __restrict__ Hh,     // fp16 [b][t][64]
    const unsigned short* __restrict__ vT,     // fp16 frag [bh][db 4][jc 32][512]
    const float* __restrict__ head_mask,
    float* __restrict__ Hst, unsigned short* __restrict__ HbfOut, size_t hbPl,
    const float* __restrict__ g, const float* __restrict__ bta) {
  extern __shared__ char sh[];  // [0,16K) Kbuf x2; [16K,36K) S; epilogue aliases [0,64K)
  int bid = blockIdx.x;
  int xcd = bid & 7, u = bid >> 3;
  int b = xcd * 2 + (u >> 4);
  int pidx = u & 15;
  int tid = threadIdx.x;
  int wid = tid >> 6, lane = tid & 63;
  int h = wid & 3, grp = wid >> 2;
  int lr = lane & 15, lg = lane >> 4;
  int i0t[2] = { pidx * 32, (31 - pidx) * 32 };
  int NSS = (33 - pidx) >> 1;              // supersteps of 64 keys

  const char* gK = (const char*)(Hh + (size_t)b * SEQ * 64);
  char* KB = sh;
  unsigned short* sw = (unsigned short*)(sh + 16384 + wid * 2560);  // [32][40] fp16

  const unsigned short* qh = q + (size_t)(b * NHEAD + h) * 65536;
  const unsigned short* vh = vT + (size_t)(b * NHEAD + h) * 65536;

  f16x8 qf[2][2][2];                       // [tile][mf][kf]
  #pragma unroll
  for (int t = 0; t < 2; ++t)
    #pragma unroll
    for (int mf = 0; mf < 2; ++mf)
      #pragma unroll
      for (int kf = 0; kf < 2; ++kf)
        qf[t][mf][kf] = *reinterpret_cast<const f16x8*>(
            qh + ((((i0t[t] >> 4) + mf) * 2 + kf) << 9) + lane * 8);
  f32x4 oacc[2][2][4] = {};                // [tile][mf][nf]

  u32x4 sreg;
  auto SLOAD = [&](int ss) {
    sreg = *reinterpret_cast<const u32x4*>(gK + (size_t)ss * 8192 + tid * 16);
  };
  auto SWRITE = [&](int buf) {
    int row = tid >> 3, colb = (tid & 7) * 16;
    *reinterpret_cast<u32x4*>(KB + buf * 8192 + row * 128 + (colb ^ ((row & 7) << 4))) = sreg;
  };

  SLOAD(0); SWRITE(0);
  __syncthreads();

  for (int ss = 0; ss < NSS; ++ss) {
    int cur = ss & 1;
    bool more = (ss + 1 < NSS);
    if (more) SLOAD(ss + 1);               // issue early
    int js = ss * 64 + grp * 32;
    if (js < i0t[1] + 32) {                // wave-uniform
      f16x8 vch[4];
      #pragma unroll
      for (int nf = 0; nf < 4; ++nf)
        vch[nf] = *reinterpret_cast<const f16x8*>(vh + ((nf * 32 + (js >> 5)) << 9) + lane * 8);
      f16x8 kfr[2][2];
      #pragma unroll
      for (int nf2 = 0; nf2 < 2; ++nf2)
        #pragma unroll
        for (int kf = 0; kf < 2; ++kf) {
          int row = grp * 32 + nf2 * 16 + lr;
          int colb = kf * 64 + lg * 16;
          kfr[nf2][kf] = *reinterpret_cast<const f16x8*>(
              KB + cur * 8192 + row * 128 + (colb ^ ((row & 7) << 4)));
        }
      #pragma unroll
      for (int t = 0; t < 2; ++t) {
        if (js < i0t[t] + 32) {            // wave-uniform
          #pragma unroll
          for (int nf2 = 0; nf2 < 2; ++nf2) {
            #pragma unroll
            for (int mf = 0; mf < 2; ++mf) {
              f32x4 sacc = {};
              #pragma unroll
              for (int kf = 0; kf < 2; ++kf)
                sacc = __builtin_amdgcn_mfma_f32_16x16x32_f16(qf[t][mf][kf], kfr[nf2][kf], sacc, 0, 0, 0);
              #pragma unroll
              for (int r = 0; r < 4; ++r) {
                int i = i0t[t] + mf * 16 + lg * 4 + r;
                int j = js + nf2 * 16 + lr;
                float v = (j <= i) ? fmaxf(sacc[r], 0.f) : 0.f;
                sw[(mf * 16 + lg * 4 + r) * 40 + nf2 * 16 + lr] = f2h(v);
              }
            }
          }
          asm volatile("s_waitcnt lgkmcnt(0)" ::: "memory");
          __builtin_amdgcn_sched_barrier(0);
          #pragma unroll
          for (int mf = 0; mf < 2; ++mf) {
            f16x8 sf = *reinterpret_cast<const f16x8*>(&sw[(mf * 16 + lr) * 40 + lg * 8]);
            #pragma unroll
            for (int nf = 0; nf < 4; ++nf)
              oacc[t][mf][nf] = __builtin_amdgcn_mfma_f32_16x16x32_f16(sf, vch[nf], oacc[t][mf][nf], 0, 0, 0);
          }
        }
      }
    }
    if (more) SWRITE(cur ^ 1);             // write late; drained by syncthreads
    __syncthreads();
  }

  // ---- epilogue: tree-sum over 8 waves + 1/(i+1) + residual + LN1 (both tiles) ----
  float hm = head_mask[h];
  float hm3 = hm * hm * hm;
  float* f8 = (float*)sh;                  // [8][32][64] f32, aliases Kbuf+S
  for (int t = 0; t < 2; ++t) {
    #pragma unroll
    for (int mf = 0; mf < 2; ++mf)
      #pragma unroll
      for (int nf = 0; nf < 4; ++nf)
        #pragma unroll
        for (int r = 0; r < 4; ++r)
          f8[wid * 2048 + (mf * 16 + lg * 4 + r) * 64 + nf * 16 + lr] = oacc[t][mf][nf][r] * hm3;
    __syncthreads();
    for (int idx = tid; idx < 8192; idx += 512) f8[idx] += f8[idx + 8192];
    __syncthreads();
    for (int idx = tid; idx < 4096; idx += 512) f8[idx] += f8[idx + 4096];
    __syncthreads();
    for (int idx = tid; idx < 2048; idx += 512) {
      int rr = idx >> 6;
      f8[idx] = (f8[idx] + f8[idx + 2048]) / (float)(i0t[t] + rr + 1);
    }
    __syncthreads();
    for (int rl = 0; rl < 4; ++rl) {
      int rr = wid * 4 + rl;
      size_t row = ((size_t)b * SEQ + i0t[t] + rr) * EMB;
      int c0 = lane, c1 = lane + 64;
      float x0 = Hst[row + c0];
      float x1 = Hst[row + c1] + f8[rr * 64 + lane];
      float s1 = x0 + x1, s2 = x0 * x0 + x1 * x1;
      #pragma unroll
      for (int off = 1; off < 64; off <<= 1) {
        s1 += __shfl_xor(s1, off);
        s2 += __shfl_xor(s2, off);
      }
      float mu = s1 * (1.f / 128.f);
      float var = s2 * (1.f / 128.f) - mu * mu;
      float rs = rsqrt_acc(var + LN_EPS);
      float y0 = (x0 - mu) * rs * g[c0] + bta[c0];
      float y1 = (x1 - mu) * rs * g[c1] + bta[c1];
      Hst[row + c0] = y0; Hst[row + c1] = y1;
      unsigned short h0, l0, h1, l1; split2(y0, h0, l0); split2(y1, h1, l1);
      HbfOut[row + c0] = h0; HbfOut[hbPl + row + c0] = l0;
      HbfOut[row + c1] = h1; HbfOut[hbPl + row + c1] = l1;
    }
    __syncthreads();
  }
}

// ---------------- fused attention (+LN1), last layer (DHEAD=128), fp16 frag-ordered ----------------
__global__ __launch_bounds__(512) void k_attn_fused(
    const unsigned short* __restrict__ q,      // fp16 frag [bh][tb 64][kc 4][512]
    const unsigned short* __restrict__ kbuf,   // fp16 frag [bh][tb 64][kc 4][512]
    const unsigned short* __restrict__ vT,     // fp16 frag [bh][db 8][jc 32][512]
    const float* __restrict__ head_mask,
    float* __restrict__ Hst, unsigned short* __restrict__ HbfOut, size_t hbPl,
    const float* __restrict__ g, const float* __restrict__ bta) {
  constexpr int KF = 4, NFO = 8, DHEAD = 128;
  constexpr int NT = SEQ / 32;
  __shared__ __align__(16) char shraw[8 * 32 * 40 * 2];  // 20KB (S); facc 16KB aliases
  int bid = blockIdx.x;
  int xcd = bid & 7, u = bid >> 3;
  int b = xcd * 2 + (u >> 4);
  int pidx = u & 15;
  int wid = threadIdx.x >> 6, lane = threadIdx.x & 63;
  int h = wid & 3, grp = wid >> 2;
  int lr = lane & 15, lg = lane >> 4;
  unsigned short* sw = (unsigned short*)(shraw + wid * 2560);  // [32][40]
  typedef float FRow[DHEAD];
  FRow* facc = (FRow*)shraw;
  const unsigned short* qh = q + (size_t)(b * NHEAD + h) * 131072;
  const unsigned short* kh = kbuf + (size_t)(b * NHEAD + h) * 131072;
  const unsigned short* vh = vT + (size_t)(b * NHEAD + h) * 131072;
  float hm = head_mask[h];
  float hm3 = hm * hm * hm;

  for (int s = 0; s < 2; ++s) {
    int tile = (s == 0) ? pidx : (NT - 1 - pidx);
    int i0 = tile * 32;
    f16x8 qf[2][KF];
    #pragma unroll
    for (int mf = 0; mf < 2; ++mf)
      #pragma unroll
      for (int kf = 0; kf < KF; ++kf)
        qf[mf][kf] = *reinterpret_cast<const f16x8*>(
            qh + ((((i0 >> 4) + mf) * 4 + kf) << 9) + lane * 8);
    f32x4 oacc[2][NFO] = {};
    int jend = i0 + 32;
    for (int j0 = grp * 32; j0 < jend; j0 += 64) {
      f16x8 vch[NFO];
      #pragma unroll
      for (int nf = 0; nf < NFO; ++nf)
        vch[nf] = *reinterpret_cast<const f16x8*>(vh + ((nf * 32 + (j0 >> 5)) << 9) + lane * 8);
      #pragma unroll
      for (int nf2 = 0; nf2 < 2; ++nf2) {
        f16x8 kfr[KF];
        #pragma unroll
        for (int kf = 0; kf < KF; ++kf)
          kfr[kf] = *reinterpret_cast<const f16x8*>(
              kh + ((((j0 >> 4) + nf2) * 4 + kf) << 9) + lane * 8);
        #pragma unroll
        for (int mf = 0; mf < 2; ++mf) {
          f32x4 sacc = {};
          #pragma unroll
          for (int kf = 0; kf < KF; ++kf)
            sacc = __builtin_amdgcn_mfma_f32_16x16x32_f16(qf[mf][kf], kfr[kf], sacc, 0, 0, 0);
          #pragma unroll
          for (int r = 0; r < 4; ++r) {
            int i = i0 + mf * 16 + lg * 4 + r;
            int j = j0 + nf2 * 16 + lr;
            float v = (j <= i) ? fmaxf(sacc[r], 0.f) : 0.f;
            sw[(mf * 16 + lg * 4 + r) * 40 + nf2 * 16 + lr] = f2h(v);
          }
        }
      }
      asm volatile("s_waitcnt lgkmcnt(0)" ::: "memory");
      __builtin_amdgcn_sched_barrier(0);
      #pragma unroll
      for (int mf = 0; mf < 2; ++mf) {
        f16x8 sf = *reinterpret_cast<const f16x8*>(&sw[(mf * 16 + lr) * 40 + lg * 8]);
        #pragma unroll
        for (int nf = 0; nf < NFO; ++nf)
          oacc[mf][nf] = __builtin_amdgcn_mfma_f32_16x16x32_f16(sf, vch[nf], oacc[mf][nf], 0, 0, 0);
      }
    }
    __syncthreads();
    for (int x = threadIdx.x; x < 32 * DHEAD; x += 512) ((float*)shraw)[x] = 0.f;
    __syncthreads();
    for (int w = 0; w < 8; ++w) {
      if (wid == w) {
        #pragma unroll
        for (int mf = 0; mf < 2; ++mf)
          #pragma unroll
          for (int nf = 0; nf < NFO; ++nf)
            #pragma unroll
            for (int r = 0; r < 4; ++r) {
              int rr = mf * 16 + lg * 4 + r;
              facc[rr][nf * 16 + lr] += oacc[mf][nf][r] * hm3 / (float)(i0 + rr + 1);
            }
      }
      __syncthreads();
    }
    for (int rl = 0; rl < 4; ++rl) {
      int rr = wid * 4 + rl;
      size_t row = ((size_t)b * SEQ + i0 + rr) * EMB;
      int c0 = lane, c1 = lane + 64;
      float x0 = Hst[row + c0] + facc[rr][c0];
      float x1 = Hst[row + c1] + facc[rr][c1];
      float s1 = x0 + x1, s2 = x0 * x0 + x1 * x1;
      #pragma unroll
      for (int off = 1; off < 64; off <<= 1) {
        s1 += __shfl_xor(s1, off);
        s2 += __shfl_xor(s2, off);
      }
      float mu = s1 * (1.f / 128.f);
      float var = s2 * (1.f / 128.f) - mu * mu;
      float rs = rsqrt_acc(var + LN_EPS);
      float y0 = (x0 - mu) * rs * g[c0] + bta[c0];
      float y1 = (x1 - mu) * rs * g[c1] + bta[c1];
      Hst[row + c0] = y0; Hst[row + c1] = y1;
      unsigned short h0, l0, h1, l1; split2(y0, h0, l0); split2(y1, h1, l1);
      HbfOut[row + c0] = h0; HbfOut[hbPl + row + c0] = l0;
      HbfOut[row + c1] = h1; HbfOut[hbPl + row + c1] = l1;
    }
    __syncthreads();
  }
}

// ---------------- fused MLP2 + residual + LN2 (frag-ordered A + B) ----------------
__global__ __launch_bounds__(256) void k_mlp2ln(
    const unsigned short* __restrict__ A,      // frag-ordered packed u32 mid
    const unsigned short* __restrict__ BT, size_t bPl, const float* __restrict__ bias,
    float* __restrict__ Hst, unsigned short* __restrict__ HbfOut, size_t hbPl,
    unsigned short* __restrict__ Hh,
    const float* __restrict__ g, const float* __restrict__ bta) {
  int wid = threadIdx.x >> 6, lane = threadIdx.x & 63;
  int lr = lane & 15, lg = lane >> 4;
  int row0 = blockIdx.x * 64 + wid * 16;
  f32x4 acc[8] = {};
  const unsigned int* aF = (const unsigned int*)A + (size_t)(blockIdx.x * 4 + wid) * 8192 + lane * 8;
  #pragma unroll
  for (int kc = 0; kc < 16; ++kc) {
    u32x4 pa = *reinterpret_cast<const u32x4*>(aF + kc * 512);
    u32x4 pb = *reinterpret_cast<const u32x4*>(aF + kc * 512 + 4);
    bf16x8 ah, al;
    #pragma unroll
    for (int j = 0; j < 4; ++j) {
      ah[j] = (short)(pa[j] & 0xffff);  al[j] = (short)(pa[j] >> 16);
      ah[4 + j] = (short)(pb[j] & 0xffff);  al[4 + j] = (short)(pb[j] >> 16);
    }
    #pragma unroll
    for (int nf = 0; nf < 8; ++nf) {
      size_t bo = ((size_t)kc * 8 + nf) * 512 + lane * 8;
      bf16x8 bh = *reinterpret_cast<const bf16x8*>(BT + bo);
      bf16x8 bl = *reinterpret_cast<const bf16x8*>(BT + bPl + bo);
      acc[nf] = __builtin_amdgcn_mfma_f32_16x16x32_bf16(ah, bh, acc[nf], 0, 0, 0);
      acc[nf] = __builtin_amdgcn_mfma_f32_16x16x32_bf16(al, bh, acc[nf], 0, 0, 0);
      acc[nf] = __builtin_amdgcn_mfma_f32_16x16x32_bf16(ah, bl, acc[nf], 0, 0, 0);
    }
  }
  int rowb = row0 + lg * 4;
  float xv[8][4];
  float s1[4] = {}, s2[4] = {};
  #pragma unroll
  for (int nf = 0; nf < 8; ++nf) {
    int c = nf * 16 + lr;
    float bv = bias[c];
    #pragma unroll
    for (int r = 0; r < 4; ++r) {
      float x = acc[nf][r] + bv + Hst[(size_t)(rowb + r) * EMB + c];
      xv[nf][r] = x; s1[r] += x; s2[r] += x * x;
    }
  }
  #pragma unroll
  for (int off = 1; off < 16; off <<= 1) {
    #pragma unroll
    for (int r = 0; r < 4; ++r) {
      s1[r] += __shfl_xor(s1[r], off);
      s2[r] += __shfl_xor(s2[r], off);
    }
  }
  #pragma unroll
  for (int r = 0; r < 4; ++r) {
    float mu = s1[r] * (1.f / 128.f);
    float var = s2[r] * (1.f / 128.f) - mu * mu;
    float rs = rsqrt_acc(var + LN_EPS);
    #pragma unroll
    for (int nf = 0; nf < 8; ++nf) {
      int c = nf * 16 + lr;
      float y = (xv[nf][r] - mu) * rs * g[c] + bta[c];
      size_t o = (size_t)(rowb + r) * EMB + c;
      Hst[o] = y;
      unsigned short hi, lo; split2(y, hi, lo);
      HbfOut[o] = hi; HbfOut[hbPl + o] = lo;
      if (c < 64) Hh[(size_t)(rowb + r) * 64 + c] = f2h(y);
    }
  }
}

// ---------------- readout ----------------
__global__ __launch_bounds__(64) void k_readout(const float* __restrict__ H,
                                                const float* __restrict__ W, const float* __restrict__ b0,
                                                float* __restrict__ out) {
  int idx = blockIdx.x;           // b*512 + p
  int b = idx >> 9, p = idx & 511;
  size_t row = ((size_t)b * SEQ + 2 * p) * EMB;
  int lane = threadIdx.x;
  float acc = H[row + lane] * W[lane] + H[row + 64 + lane] * W[64 + lane];
  #pragma unroll
  for (int off = 1; off < 64; off <<= 1) acc += __shfl_xor(acc, off);
  if (lane == 0) out[idx] = acc + b0[0];
}

extern "C" void kernel_launch(void* const* d_in, const int* in_sizes, int n_in,
                              void* d_out, int out_size, void* d_ws, size_t ws_size,
                              hipStream_t stream) {
  (void)in_sizes; (void)n_in; (void)out_size; (void)ws_size;
  const float* xs        = (const float*)d_in[0];
  const float* ys        = (const float*)d_in[1];
  const float* head_mask = (const float*)d_in[2];
  const float* read_in_W = (const float*)d_in[3];
  const float* read_in_b = (const float*)d_in[4];
  const float* qW        = (const float*)d_in[5];
  const float* vW        = (const float*)d_in[6];
  const float* qW_last   = (const float*)d_in[7];
  const float* kW_last   = (const float*)d_in[8];
  const float* vW_last   = (const float*)d_in[9];
  const float* ln1_g     = (const float*)d_in[10];
  const float* ln1_b     = (const float*)d_in[11];
  const float* ln2_g     = (const float*)d_in[12];
  const float* ln2_b     = (const float*)d_in[13];
  const float* mlp_W1    = (const float*)d_in[14];
  const float* mlp_b1    = (const float*)d_in[15];
  const float* mlp_W2    = (const float*)d_in[16];
  const float* mlp_b2    = (const float*)d_in[17];
  const float* ro_W      = (const float*)d_in[18];
  const float* ro_b      = (const float*)d_in[19];

  const size_t HPL   = (size_t)BS * SEQ * EMB;          // 2M
  const size_t QVWPL = (size_t)11 * 512 * 128;
  const size_t W1PL  = (size_t)12 * 512 * 128;
  const size_t W2PL  = (size_t)12 * 512 * 128;
  const size_t LASTPL= (size_t)1536 * 128;

  char* ws = (char*)d_ws;
  size_t off = 0;
  auto alloc = [&](size_t bytes) -> void* {
    void* p = ws + off;
    off += (bytes + 255) & ~(size_t)255;
    return p;
  };
  float* H             = (float*)alloc(HPL * 4);                  // 8 MB (in-place state)
  unsigned short* Hbf  = (unsigned short*)alloc(2 * HPL * 2);     // 8 MB bf16 split
  unsigned short* Hbf2 = (unsigned short*)alloc(2 * HPL * 2);     // 8 MB bf16 split
  unsigned short* Hh   = (unsigned short*)alloc((size_t)BS * SEQ * 64 * 2);  // 2 MB fp16 K image
  unsigned short* qbuf = (unsigned short*)alloc((size_t)BS * NHEAD * 131072 * 2); // 16.8 MB q frag
  unsigned short* kmid = (unsigned short*)alloc((size_t)BS * SEQ * 512 * 4);  // 33.5 MB (v7 vfrag / mid / k-last frag)
  unsigned short* vTl  = (unsigned short*)alloc((size_t)BS * NHEAD * 131072 * 2); // 16.8 MB last v frag
  unsigned short* qvWT = (unsigned short*)alloc(2 * QVWPL * 2);
  unsigned short* W1T  = (unsigned short*)alloc(2 * W1PL * 2);
  unsigned short* W2T  = (unsigned short*)alloc(2 * W2PL * 2);
  unsigned short* lastT= (unsigned short*)alloc(2 * LASTPL * 2);

  { int tot = 11 * 512 * 128; k_prep_qvfrag<<<dim3((tot + 255) / 256), 256, 0, stream>>>(qW, vW, qvWT, QVWPL); }
  { int tot = 12 * 512 * 128; k_prep_fragT<<<dim3((tot + 255) / 256), 256, 0, stream>>>(mlp_W1, W1T, W1PL, 12, 128, 512, 512, 128); }
  { int tot = 12 * 512 * 128; k_prep_fragT<<<dim3((tot + 255) / 256), 256, 0, stream>>>(mlp_W2, W2T, W2PL, 12, 512, 128, 128, 512); }
  { int tot = 1536 * 128; k_prep_lastfrag<<<dim3((tot + 255) / 256), 256, 0, stream>>>(qW_last, kW_last, vW_last, lastT, LASTPL); }

  k_combine_readin<<<dim3(BS * SEQ), 128, 0, stream>>>(xs, ys, read_in_W, read_in_b, H, Hbf, HPL, Hh);

  const int GEMM_LDS = 2 * 64 * 136 * 2;   // 34816 B (A planes; tile reuse fits inside)
  for (int l = 0; l < 11; ++l) {
    k_gemm<3, false><<<dim3(256, 8), 256, GEMM_LDS, stream>>>(
        Hbf, HPL, qvWT + (size_t)l * 65536, QVWPL, nullptr, 512,
        qbuf, kmid, nullptr);
    k_attn_v7<<<dim3(256), 512, 65536, stream>>>(
        qbuf, Hh, kmid, head_mask, H, Hbf2, HPL, ln1_g + l * 128, ln1_b + l * 128);
    k_gemm<0, true><<<dim3(256, 8), 256, GEMM_LDS, stream>>>(
        Hbf2, HPL, W1T + (size_t)l * 65536, W1PL, mlp_b1 + l * 512, 512,
        kmid, nullptr, nullptr);
    k_mlp2ln<<<dim3(256), 256, 0, stream>>>(
        kmid, W2T + (size_t)l * 65536, W2PL, mlp_b2 + l * 128,
        H, Hbf, HPL, Hh, ln2_g + l * 128, ln2_b + l * 128);
  }
  // last layer: q,k,v fp16 frag projections in one GEMM (N=1536)
  k_gemm<2, false><<<dim3(256, 24), 256, GEMM_LDS, stream>>>(
      Hbf, HPL, lastT, LASTPL, nullptr, 1536,
      qbuf, kmid, vTl);
  k_attn_fused<<<dim3(256), 512, 0, stream>>>(
      qbuf, kmid, vTl, head_mask, H, Hbf2, HPL, ln1_g + 11 * 128, ln1_b + 11 * 128);
  k_gemm<0, true><<<dim3(256, 8), 256, GEMM_LDS, stream>>>(
      Hbf2, HPL, W1T + (size_t)11 * 65536, W1PL, mlp_b1 + 11 * 512, 512,
      kmid, nullptr, nullptr);
  k_mlp2ln<<<dim3(256), 256, 0, stream>>>(
      kmid, W2T + (size_t)11 * 65536, W2PL, mlp_b2 + 11 * 128,
      H, Hbf, HPL, Hh, ln2_g + 11 * 128, ln2_b + 11 * 128);

  k_readout<<<dim3(8192), 64, 0, stream>>>(H, ro_W, ro_b, (float*)d_out);
}